// Round 5
// baseline (788.531 us; speedup 1.0000x reference)
//
#include <hip/hip_runtime.h>
#include <math.h>

#define NN 50000
#define NE 800000
#define NEP 850000          // NE + NN self loops
#define FI 1284
#define HD 128
#define KP 1312             // FI padded to 41*32 for MFMA K-loop
#define KSPLIT_MID 672      // 21 K-steps | 20 K-steps
#define NH (NN * HD)        // 6,400,000
#define SCAN_B 256
#define NBLK ((NN + SCAN_B - 1) / SCAN_B)   // 196 (<=256)
#define NROWB ((NN + 63) / 64)              // 782 row-blocks of 64

typedef float f32x4 __attribute__((ext_vector_type(4)));
typedef short bfrag __attribute__((ext_vector_type(8)));   // 8 bf16 in 4 VGPRs

// ---------------- helpers ----------------

__device__ __forceinline__ void atomicMaxF(float* addr, float v) {
    if (v >= 0.f) atomicMax((int*)addr, __float_as_int(v));
    else          atomicMin((unsigned int*)addr, __float_as_uint(v));
}

__device__ __forceinline__ float wave_reduce_sum(float v) {
    #pragma unroll
    for (int off = 32; off; off >>= 1) v += __shfl_down(v, off);
    return v;
}

__device__ __forceinline__ ushort f2bf(float f) {   // RNE fp32->bf16 bits
    unsigned u = __float_as_uint(f);
    u += 0x7FFFu + ((u >> 16) & 1u);
    return (ushort)(u >> 16);
}

// ---------------- init ----------------

// grid covers NH: zeroes h1 (gemm now accumulates via atomicAdd K-split halves)
__global__ void k_init(float* h1, float* m1, float* den1, float* m2, float* den2,
                       float* o2a, int* cnt, float* sc) {
    int i = blockIdx.x * blockDim.x + threadIdx.x;
    if (i < NH) h1[i] = 0.f;
    if (i < NN) {
        m1[i]  = -INFINITY; den1[i] = 0.f;
        m2[i]  = -INFINITY; den2[i] = 0.f;
        o2a[i] = 0.f;
        cnt[i] = 0;
    }
    if (i < 8) sc[i] = 0.f;
}

__global__ void k_sum_attr(const float* __restrict__ eattr, float* sc) {
    int i = blockIdx.x * blockDim.x + threadIdx.x;
    float v = (i < NE) ? eattr[i] : 0.f;
    v = wave_reduce_sum(v);
    if ((threadIdx.x & 63) == 0) atomicAdd(&sc[0], v);
}

__global__ void k_consts(const float* We1, const float* ae1,
                         const float* We2, const float* ae2, float* sc) {
    int l = threadIdx.x;  // 64 threads
    float v = We1[l] * ae1[l] + We1[l + 64] * ae1[l + 64];
    v = wave_reduce_sum(v);
    if (l == 0) { sc[1] = v; sc[2] = We2[0] * ae2[0]; }
}

// Wt[c][k] = bf16(W1[k][c]), K-padded with zeros to KP
__global__ void k_wt(const float* __restrict__ W, ushort* __restrict__ Wt) {
    int i = blockIdx.x * 256 + threadIdx.x;
    if (i >= HD * KP) return;
    int c = i / KP, k = i % KP;
    float v = (k < FI) ? W[(size_t)k * HD + c] : 0.f;
    Wt[i] = f2bf(v);
}

// ---------------- GEMM1: h1 = x @ W1  (bf16 MFMA, fp32 acc, K-split x2) ----------------
// blockIdx: bit0 = K-half, rest = 64-row block. 4 waves/block, wave = 16 rows x 128 cols.
// Partial acc atomically added into zero-init h1 (2 commutative adds/elem -> deterministic).

__global__ __launch_bounds__(256, 6) void k_gemm1_mfma(const float* __restrict__ x,
                                                       const ushort* __restrict__ Wt,
                                                       float* __restrict__ h1) {
    const int t = threadIdx.x;
    const int wid = t >> 6, l = t & 63;
    const int lr = l & 15, lg = l >> 4;
    const int ks = blockIdx.x & 1;
    const int rb = blockIdx.x >> 1;
    const int row0 = rb * 64 + wid * 16;

    const int kb = ks ? KSPLIT_MID : 0;
    const int ke = ks ? KP : KSPLIT_MID;

    int rowc = row0 + lr; if (rowc > NN - 1) rowc = NN - 1;   // clamp OOB loads
    const float*  ap = x  + (size_t)rowc * FI + lg * 8;
    const ushort* bp = Wt + (size_t)lr * KP + lg * 8;

    f32x4 acc[8];
    #pragma unroll
    for (int c = 0; c < 8; ++c) acc[c] = (f32x4){0.f, 0.f, 0.f, 0.f};

    const int kmain = (ke < 1280) ? ke : 1280;
    #pragma unroll 2
    for (int k0 = kb; k0 < kmain; k0 += 32) {
        float4 a0 = *(const float4*)(ap + k0);
        float4 a1 = *(const float4*)(ap + k0 + 4);
        bfrag af;
        af[0] = (short)f2bf(a0.x); af[1] = (short)f2bf(a0.y);
        af[2] = (short)f2bf(a0.z); af[3] = (short)f2bf(a0.w);
        af[4] = (short)f2bf(a1.x); af[5] = (short)f2bf(a1.y);
        af[6] = (short)f2bf(a1.z); af[7] = (short)f2bf(a1.w);
        #pragma unroll
        for (int cg = 0; cg < 8; ++cg) {
            bfrag bf = *(const bfrag*)(bp + (size_t)cg * 16 * KP + k0);
            acc[cg] = __builtin_amdgcn_mfma_f32_16x16x32_bf16(af, bf, acc[cg], 0, 0, 0);
        }
    }
    if (ke > 1280) {   // K tail: k0 = 1280, valid k < 1284 (lg==0 low half); Wt zero-padded
        float4 a0 = make_float4(0.f, 0.f, 0.f, 0.f);
        if (lg == 0) a0 = *(const float4*)(ap + 1280);
        bfrag af;
        af[0] = (short)f2bf(a0.x); af[1] = (short)f2bf(a0.y);
        af[2] = (short)f2bf(a0.z); af[3] = (short)f2bf(a0.w);
        af[4] = 0; af[5] = 0; af[6] = 0; af[7] = 0;
        #pragma unroll
        for (int cg = 0; cg < 8; ++cg) {
            bfrag bf = *(const bfrag*)(bp + (size_t)cg * 16 * KP + 1280);
            acc[cg] = __builtin_amdgcn_mfma_f32_16x16x32_bf16(af, bf, acc[cg], 0, 0, 0);
        }
    }

    #pragma unroll
    for (int cg = 0; cg < 8; ++cg) {
        #pragma unroll
        for (int r = 0; r < 4; ++r) {
            int gr = row0 + lg * 4 + r;
            if (gr < NN) atomicAdd(&h1[(size_t)gr * HD + cg * 16 + lr], acc[cg][r]);
        }
    }
}

__global__ __launch_bounds__(256) void k_rowdot(const float* __restrict__ h1,
                                                const float* __restrict__ asrc,
                                                const float* __restrict__ adst,
                                                float* as1, float* ad1) {
    int wid = threadIdx.x >> 6, l = threadIdx.x & 63;
    int i = blockIdx.x * 4 + wid;
    if (i >= NN) return;
    float2 hv = *(const float2*)&h1[(size_t)i * HD + 2 * l];
    float2 av = *(const float2*)&asrc[2 * l];
    float2 dv = *(const float2*)&adst[2 * l];
    float s = hv.x * av.x + hv.y * av.y;
    float d = hv.x * dv.x + hv.y * dv.y;
    #pragma unroll
    for (int off = 32; off; off >>= 1) {
        s += __shfl_down(s, off);
        d += __shfl_down(d, off);
    }
    if (l == 0) { as1[i] = s; ad1[i] = d; }
}

// ---------------- layer-1 edge passes ----------------

__global__ void k_alpha1(const int* __restrict__ ei, const float* __restrict__ eattr,
                         const float* __restrict__ as1, const float* __restrict__ ad1,
                         const float* __restrict__ sc, float* ea1, float* m1, int* cnt) {
    int e = blockIdx.x * blockDim.x + threadIdx.x;
    if (e >= NEP) return;
    int s, d; float av;
    if (e < NE) { s = ei[e]; d = ei[NE + e]; av = eattr[e]; }
    else        { s = d = e - NE; av = sc[0] * (1.0f / NE); }
    float a = as1[s] + ad1[d] + av * sc[1];
    a = (a > 0.f) ? a : 0.2f * a;
    ea1[e] = a;
    atomicMaxF(&m1[d], a);
    atomicAdd(&cnt[d], 1);
}

// ---------------- exclusive scan of cnt -> start ----------------

__global__ void k_scan_blk(const int* __restrict__ cnt, int* incl, int* bsum) {
    __shared__ int sh[SCAN_B];
    int i = blockIdx.x * SCAN_B + threadIdx.x;
    sh[threadIdx.x] = (i < NN) ? cnt[i] : 0;
    __syncthreads();
    for (int off = 1; off < SCAN_B; off <<= 1) {
        int t = (threadIdx.x >= off) ? sh[threadIdx.x - off] : 0;
        __syncthreads();
        sh[threadIdx.x] += t;
        __syncthreads();
    }
    if (i < NN) incl[i] = sh[threadIdx.x];
    if (threadIdx.x == SCAN_B - 1) bsum[blockIdx.x] = sh[threadIdx.x];
}

__global__ void k_scan_top(int* bsum) {
    __shared__ int sh[SCAN_B];
    sh[threadIdx.x] = (threadIdx.x < NBLK) ? bsum[threadIdx.x] : 0;
    __syncthreads();
    for (int off = 1; off < SCAN_B; off <<= 1) {
        int t = (threadIdx.x >= off) ? sh[threadIdx.x - off] : 0;
        __syncthreads();
        sh[threadIdx.x] += t;
        __syncthreads();
    }
    if (threadIdx.x < NBLK) bsum[threadIdx.x] = sh[threadIdx.x];
}

__global__ void k_scan_fix(int* incl_start, const int* __restrict__ cnt,
                           const int* __restrict__ bsum, int* cursor) {
    int i = blockIdx.x * SCAN_B + threadIdx.x;
    if (i >= NN) return;
    int off = (blockIdx.x > 0) ? bsum[blockIdx.x - 1] : 0;
    int st = incl_start[i] - cnt[i] + off;
    incl_start[i] = st;
    cursor[i] = st;
}

__global__ void k_exp1(const int* __restrict__ ei, const float* __restrict__ m1,
                       const float* __restrict__ ea1, float* den1,
                       int* cursor, int* csr_src, float* csr_val) {
    int e = blockIdx.x * blockDim.x + threadIdx.x;
    if (e >= NEP) return;
    int s, d;
    if (e < NE) { s = ei[e]; d = ei[NE + e]; }
    else        { s = d = e - NE; }
    float v = expf(ea1[e] - m1[d]);
    atomicAdd(&den1[d], v);
    int pos = atomicAdd(&cursor[d], 1);
    csr_src[pos] = s;
    csr_val[pos] = v;
}

// gather-accumulate + fused ELU/bias/W2-dot epilogue (out1 never materialized)
__global__ __launch_bounds__(256) void k_accum1_csr(const int* __restrict__ csr_src,
                                                    const float* __restrict__ csr_val,
                                                    const int* __restrict__ start,
                                                    const int* __restrict__ cnt,
                                                    const float* __restrict__ den1,
                                                    const float* __restrict__ h1,
                                                    const float* __restrict__ b1,
                                                    const float* __restrict__ W2,
                                                    float* __restrict__ h2) {
    int wid = threadIdx.x >> 6, l = threadIdx.x & 63;
    int d = blockIdx.x * 4 + wid;
    if (d >= NN) return;
    int s0 = start[d], n = cnt[d];
    float inv = 1.f / (den1[d] + 1e-16f);
    float ax = 0.f, ay = 0.f;
    for (int i = 0; i < n; ++i) {
        int s = csr_src[s0 + i];
        float c = csr_val[s0 + i] * inv;
        float2 hv = *(const float2*)&h1[(size_t)s * HD + 2 * l];
        ax += c * hv.x; ay += c * hv.y;
    }
    float2 bb = *(const float2*)&b1[2 * l];
    float2 w  = *(const float2*)&W2[2 * l];
    float a = ax + bb.x; a = (a > 0.f) ? a : (expf(a) - 1.f);
    float b = ay + bb.y; b = (b > 0.f) ? b : (expf(b) - 1.f);
    float p = a * w.x + b * w.y;
    p = wave_reduce_sum(p);
    if (l == 0) h2[d] = p;
}

// ---------------- layer-2 edge passes ----------------

__global__ void k_alpha2(const int* __restrict__ ei, const float* __restrict__ eattr,
                         const float* __restrict__ h2,
                         const float* __restrict__ as2, const float* __restrict__ ad2,
                         const float* __restrict__ sc, float* ea2, float* m2) {
    int e = blockIdx.x * blockDim.x + threadIdx.x;
    if (e >= NEP) return;
    int s, d; float av;
    if (e < NE) { s = ei[e]; d = ei[NE + e]; av = eattr[e]; }
    else        { s = d = e - NE; av = sc[0] * (1.0f / NE); }
    float a = as2[0] * h2[s] + ad2[0] * h2[d] + av * sc[2];
    a = (a > 0.f) ? a : 0.2f * a;
    ea2[e] = a;
    atomicMaxF(&m2[d], a);
}

__global__ void k_exp2(const int* __restrict__ ei, const float* __restrict__ m2,
                       float* ea2, float* den2) {
    int e = blockIdx.x * blockDim.x + threadIdx.x;
    if (e >= NEP) return;
    int d = (e < NE) ? ei[NE + e] : e - NE;
    float v = expf(ea2[e] - m2[d]);
    ea2[e] = v;
    atomicAdd(&den2[d], v);
}

__global__ void k_accum2(const int* __restrict__ ei, const float* __restrict__ ea2,
                         const float* __restrict__ den2, const float* __restrict__ h2,
                         float* o2a) {
    int e = blockIdx.x * blockDim.x + threadIdx.x;
    if (e >= NEP) return;
    int s, d;
    if (e < NE) { s = ei[e]; d = ei[NE + e]; }
    else        { s = d = e - NE; }
    atomicAdd(&o2a[d], ea2[e] / (den2[d] + 1e-16f) * h2[s]);
}

__global__ void k_final(const float* __restrict__ o2a, const float* __restrict__ b2,
                        float* __restrict__ out) {
    int i = blockIdx.x * blockDim.x + threadIdx.x;
    if (i >= NN) return;
    float v = o2a[i] + b2[0];
    out[i] = (v >= 0.f) ? v : 0.01f * v;
}

// ---------------- launch ----------------

extern "C" void kernel_launch(void* const* d_in, const int* in_sizes, int n_in,
                              void* d_out, int out_size, void* d_ws, size_t ws_size,
                              hipStream_t stream) {
    const float* x     = (const float*)d_in[0];
    const int*   ei    = (const int*)d_in[1];
    const float* eattr = (const float*)d_in[2];
    const float* W1    = (const float*)d_in[3];
    const float* asrc1 = (const float*)d_in[4];
    const float* adst1 = (const float*)d_in[5];
    const float* We1   = (const float*)d_in[6];
    const float* ae1   = (const float*)d_in[7];
    const float* b1    = (const float*)d_in[8];
    const float* W2    = (const float*)d_in[9];
    const float* as2   = (const float*)d_in[10];
    const float* ad2   = (const float*)d_in[11];
    const float* We2   = (const float*)d_in[12];
    const float* ae2   = (const float*)d_in[13];
    const float* b2    = (const float*)d_in[14];
    float* out = (float*)d_out;

    // workspace layout (~38.3 MB)
    float* w    = (float*)d_ws;
    float* h1   = w;                      // NH
    float* as1  = w + (size_t)NH;         // NN
    float* ad1  = as1 + NN;
    float* m1   = ad1 + NN;
    float* den1 = m1 + NN;
    float* h2   = den1 + NN;
    float* m2   = h2 + NN;
    float* den2 = m2 + NN;
    float* o2a  = den2 + NN;
    float* ea1  = o2a + NN;               // NEP
    float* csr_val = ea1 + NEP;           // NEP (reused as ea2 in layer 2)
    float* ea2  = csr_val;
    float* sc   = csr_val + NEP;          // 8 scalars
    int*   cnt    = (int*)(sc + 8);       // NN
    int*   start  = cnt + NN;             // NN
    int*   cursor = start + NN;           // NN
    int*   bsum   = cursor + NN;          // 256
    int*   csr_src = bsum + 256;          // NEP
    ushort* Wt   = (ushort*)(csr_src + NEP);  // HD*KP bf16

    k_init<<<(NH + 255) / 256, 256, 0, stream>>>(h1, m1, den1, m2, den2, o2a, cnt, sc);
    k_sum_attr<<<(NE + 255) / 256, 256, 0, stream>>>(eattr, sc);
    k_consts<<<1, 64, 0, stream>>>(We1, ae1, We2, ae2, sc);
    k_wt<<<(HD * KP + 255) / 256, 256, 0, stream>>>(W1, Wt);

    k_gemm1_mfma<<<NROWB * 2, 256, 0, stream>>>(x, Wt, h1);
    k_rowdot<<<(NN + 3) / 4, 256, 0, stream>>>(h1, asrc1, adst1, as1, ad1);

    k_alpha1<<<(NEP + 255) / 256, 256, 0, stream>>>(ei, eattr, as1, ad1, sc, ea1, m1, cnt);
    k_scan_blk<<<NBLK, SCAN_B, 0, stream>>>(cnt, start, bsum);
    k_scan_top<<<1, SCAN_B, 0, stream>>>(bsum);
    k_scan_fix<<<NBLK, SCAN_B, 0, stream>>>(start, cnt, bsum, cursor);
    k_exp1<<<(NEP + 255) / 256, 256, 0, stream>>>(ei, m1, ea1, den1, cursor, csr_src, csr_val);
    k_accum1_csr<<<(NN + 3) / 4, 256, 0, stream>>>(csr_src, csr_val, start, cnt, den1, h1, b1, W2, h2);

    k_alpha2<<<(NEP + 255) / 256, 256, 0, stream>>>(ei, eattr, h2, as2, ad2, sc, ea2, m2);
    k_exp2<<<(NEP + 255) / 256, 256, 0, stream>>>(ei, m2, ea2, den2);
    k_accum2<<<(NEP + 255) / 256, 256, 0, stream>>>(ei, ea2, den2, h2, o2a);

    k_final<<<(NN + 255) / 256, 256, 0, stream>>>(o2a, b2, out);
}

// Round 6
// 702.427 us; speedup vs baseline: 1.1226x; 1.1226x over previous
//
#include <hip/hip_runtime.h>
#include <math.h>

#define NN 50000
#define NE 800000
#define NEP 850000          // NE + NN self loops
#define FI 1284
#define HD 128
#define KP 1312             // FI padded to 41*32 for MFMA K-loop
#define NSTEP 41            // KP/32
#define SPLIT_STEP 21       // K-split: steps [0,21) | [21,41)
#define NH (NN * HD)        // 6,400,000
#define SCAN_B 256
#define NBLK ((NN + SCAN_B - 1) / SCAN_B)   // 196 (<=256)
#define NROWB ((NN + 63) / 64)              // 782 row-blocks of 64
#define WP_ELEMS (NSTEP * 4096)             // packed B: 41 steps * 8cg * 64lane * 8

typedef float f32x4 __attribute__((ext_vector_type(4)));
typedef short bfrag __attribute__((ext_vector_type(8)));   // 8 bf16 in 4 VGPRs

// ---------------- helpers ----------------

__device__ __forceinline__ void atomicMaxF(float* addr, float v) {
    if (v >= 0.f) atomicMax((int*)addr, __float_as_int(v));
    else          atomicMin((unsigned int*)addr, __float_as_uint(v));
}

__device__ __forceinline__ float wave_reduce_sum(float v) {
    #pragma unroll
    for (int off = 32; off; off >>= 1) v += __shfl_down(v, off);
    return v;
}

__device__ __forceinline__ ushort f2bf(float f) {   // RNE fp32->bf16 bits
    unsigned u = __float_as_uint(f);
    u += 0x7FFFu + ((u >> 16) & 1u);
    return (ushort)(u >> 16);
}

__device__ __forceinline__ bfrag cvt_frag(float4 a0, float4 a1) {
    bfrag af;
    af[0] = (short)f2bf(a0.x); af[1] = (short)f2bf(a0.y);
    af[2] = (short)f2bf(a0.z); af[3] = (short)f2bf(a0.w);
    af[4] = (short)f2bf(a1.x); af[5] = (short)f2bf(a1.y);
    af[6] = (short)f2bf(a1.z); af[7] = (short)f2bf(a1.w);
    return af;
}

// ---------------- init ----------------

__global__ void k_init(float* h1, float* m1, float* den1, float* m2, float* den2,
                       float* o2a, int* cnt, float* sc) {
    int i = blockIdx.x * blockDim.x + threadIdx.x;
    if (i < NH) h1[i] = 0.f;
    if (i < NN) {
        m1[i]  = -INFINITY; den1[i] = 0.f;
        m2[i]  = -INFINITY; den2[i] = 0.f;
        o2a[i] = 0.f;
        cnt[i] = 0;
    }
    if (i < 8) sc[i] = 0.f;
}

__global__ void k_sum_attr(const float* __restrict__ eattr, float* sc) {
    int i = blockIdx.x * blockDim.x + threadIdx.x;
    float v = (i < NE) ? eattr[i] : 0.f;
    v = wave_reduce_sum(v);
    if ((threadIdx.x & 63) == 0) atomicAdd(&sc[0], v);
}

__global__ void k_consts(const float* We1, const float* ae1,
                         const float* We2, const float* ae2, float* sc) {
    int l = threadIdx.x;  // 64 threads
    float v = We1[l] * ae1[l] + We1[l + 64] * ae1[l + 64];
    v = wave_reduce_sum(v);
    if (l == 0) { sc[1] = v; sc[2] = We2[0] * ae2[0]; }
}

// Packed B: Wp[s][cg][lane][j] = bf16(W1[k][c]), k = s*32 + (lane>>4)*8 + j,
// c = cg*16 + (lane&15); zero-padded for k >= FI. Load-order contiguous.
__global__ void k_wt(const float* __restrict__ W, ushort* __restrict__ Wp) {
    int i = blockIdx.x * 256 + threadIdx.x;
    if (i >= WP_ELEMS) return;
    int s = i >> 12;
    int r = i & 4095;
    int cg = r >> 9;
    int q = r & 511;
    int lane = q >> 3, j = q & 7;
    int k = s * 32 + (lane >> 4) * 8 + j;
    int c = cg * 16 + (lane & 15);
    float v = (k < FI) ? W[(size_t)k * HD + c] : 0.f;
    Wp[i] = f2bf(v);
}

// ---------------- GEMM1: h1 = x @ W1  (bf16 MFMA, K-split x2, reg-pipelined) ----------------
// blockIdx: bit0 = K-half, rest = 64-row block. 4 waves/block, wave = 16 rows x 128 cols.
// 1-deep register prefetch of A (HBM) and all 8 B frags (L2, packed layout).
// Partial acc atomically added into zero-init h1 (2 commutative adds/elem -> deterministic).

__global__ __launch_bounds__(256, 4) void k_gemm1_mfma(const float* __restrict__ x,
                                                       const ushort* __restrict__ Wp,
                                                       float* __restrict__ h1) {
    const int t = threadIdx.x;
    const int wid = t >> 6, l = t & 63;
    const int lr = l & 15, lg = l >> 4;
    const int ks = blockIdx.x & 1;
    const int rb = blockIdx.x >> 1;
    const int row0 = rb * 64 + wid * 16;

    const int sb = ks ? SPLIT_STEP : 0;
    const int nmain = ks ? (NSTEP - 1 - SPLIT_STEP) : SPLIT_STEP;  // 19 | 21 (tail step 40 peeled)

    int rowc = row0 + lr; if (rowc > NN - 1) rowc = NN - 1;   // clamp OOB loads
    const float*  ap = x  + (size_t)rowc * FI + sb * 32 + lg * 8;
    const ushort* wq = Wp + (size_t)sb * 4096 + l * 8;        // step stride 4096 ushorts

    f32x4 acc[8];
    #pragma unroll
    for (int c = 0; c < 8; ++c) acc[c] = (f32x4){0.f, 0.f, 0.f, 0.f};

    // prime step sb
    float4 a0 = *(const float4*)ap;
    float4 a1 = *(const float4*)(ap + 4);
    bfrag b[8];
    #pragma unroll
    for (int cg = 0; cg < 4; ++cg) b[cg]     = *(const bfrag*)(wq + cg * 512);
    #pragma unroll
    for (int cg = 0; cg < 4; ++cg) b[4 + cg] = *(const bfrag*)(wq + 2048 + cg * 512);

    #pragma unroll 2
    for (int it = 0; it < nmain - 1; ++it) {
        // issue next step's loads first (independent of current compute)
        ap += 32; wq += 4096;
        float4 a0n = *(const float4*)ap;
        float4 a1n = *(const float4*)(ap + 4);
        bfrag bn[8];
        #pragma unroll
        for (int cg = 0; cg < 4; ++cg) bn[cg]     = *(const bfrag*)(wq + cg * 512);
        #pragma unroll
        for (int cg = 0; cg < 4; ++cg) bn[4 + cg] = *(const bfrag*)(wq + 2048 + cg * 512);
        // compute current step
        bfrag af = cvt_frag(a0, a1);
        #pragma unroll
        for (int cg = 0; cg < 8; ++cg)
            acc[cg] = __builtin_amdgcn_mfma_f32_16x16x32_bf16(af, b[cg], acc[cg], 0, 0, 0);
        // rotate
        a0 = a0n; a1 = a1n;
        #pragma unroll
        for (int cg = 0; cg < 8; ++cg) b[cg] = bn[cg];
    }
    {   // last main step
        bfrag af = cvt_frag(a0, a1);
        #pragma unroll
        for (int cg = 0; cg < 8; ++cg)
            acc[cg] = __builtin_amdgcn_mfma_f32_16x16x32_bf16(af, b[cg], acc[cg], 0, 0, 0);
    }
    if (ks) {   // K tail: step 40 (k0=1280, valid k<1284 in lg==0 low half); Wp zero-padded
        ap += 32; wq += 4096;
        float4 a0t = make_float4(0.f, 0.f, 0.f, 0.f);
        if (lg == 0) a0t = *(const float4*)ap;
        bfrag af;
        af[0] = (short)f2bf(a0t.x); af[1] = (short)f2bf(a0t.y);
        af[2] = (short)f2bf(a0t.z); af[3] = (short)f2bf(a0t.w);
        af[4] = 0; af[5] = 0; af[6] = 0; af[7] = 0;
        #pragma unroll
        for (int cg = 0; cg < 4; ++cg) b[cg]     = *(const bfrag*)(wq + cg * 512);
        #pragma unroll
        for (int cg = 0; cg < 4; ++cg) b[4 + cg] = *(const bfrag*)(wq + 2048 + cg * 512);
        #pragma unroll
        for (int cg = 0; cg < 8; ++cg)
            acc[cg] = __builtin_amdgcn_mfma_f32_16x16x32_bf16(af, b[cg], acc[cg], 0, 0, 0);
    }

    #pragma unroll
    for (int cg = 0; cg < 8; ++cg) {
        #pragma unroll
        for (int r = 0; r < 4; ++r) {
            int gr = row0 + lg * 4 + r;
            if (gr < NN) atomicAdd(&h1[(size_t)gr * HD + cg * 16 + lr], acc[cg][r]);
        }
    }
}

__global__ __launch_bounds__(256) void k_rowdot(const float* __restrict__ h1,
                                                const float* __restrict__ asrc,
                                                const float* __restrict__ adst,
                                                float* as1, float* ad1) {
    int wid = threadIdx.x >> 6, l = threadIdx.x & 63;
    int i = blockIdx.x * 4 + wid;
    if (i >= NN) return;
    float2 hv = *(const float2*)&h1[(size_t)i * HD + 2 * l];
    float2 av = *(const float2*)&asrc[2 * l];
    float2 dv = *(const float2*)&adst[2 * l];
    float s = hv.x * av.x + hv.y * av.y;
    float d = hv.x * dv.x + hv.y * dv.y;
    #pragma unroll
    for (int off = 32; off; off >>= 1) {
        s += __shfl_down(s, off);
        d += __shfl_down(d, off);
    }
    if (l == 0) { as1[i] = s; ad1[i] = d; }
}

// ---------------- layer-1 edge passes ----------------

__global__ void k_alpha1(const int* __restrict__ ei, const float* __restrict__ eattr,
                         const float* __restrict__ as1, const float* __restrict__ ad1,
                         const float* __restrict__ sc, float* ea1, float* m1, int* cnt) {
    int e = blockIdx.x * blockDim.x + threadIdx.x;
    if (e >= NEP) return;
    int s, d; float av;
    if (e < NE) { s = ei[e]; d = ei[NE + e]; av = eattr[e]; }
    else        { s = d = e - NE; av = sc[0] * (1.0f / NE); }
    float a = as1[s] + ad1[d] + av * sc[1];
    a = (a > 0.f) ? a : 0.2f * a;
    ea1[e] = a;
    atomicMaxF(&m1[d], a);
    atomicAdd(&cnt[d], 1);
}

// ---------------- exclusive scan of cnt -> start ----------------

__global__ void k_scan_blk(const int* __restrict__ cnt, int* incl, int* bsum) {
    __shared__ int sh[SCAN_B];
    int i = blockIdx.x * SCAN_B + threadIdx.x;
    sh[threadIdx.x] = (i < NN) ? cnt[i] : 0;
    __syncthreads();
    for (int off = 1; off < SCAN_B; off <<= 1) {
        int t = (threadIdx.x >= off) ? sh[threadIdx.x - off] : 0;
        __syncthreads();
        sh[threadIdx.x] += t;
        __syncthreads();
    }
    if (i < NN) incl[i] = sh[threadIdx.x];
    if (threadIdx.x == SCAN_B - 1) bsum[blockIdx.x] = sh[threadIdx.x];
}

__global__ void k_scan_top(int* bsum) {
    __shared__ int sh[SCAN_B];
    sh[threadIdx.x] = (threadIdx.x < NBLK) ? bsum[threadIdx.x] : 0;
    __syncthreads();
    for (int off = 1; off < SCAN_B; off <<= 1) {
        int t = (threadIdx.x >= off) ? sh[threadIdx.x - off] : 0;
        __syncthreads();
        sh[threadIdx.x] += t;
        __syncthreads();
    }
    if (threadIdx.x < NBLK) bsum[threadIdx.x] = sh[threadIdx.x];
}

__global__ void k_scan_fix(int* incl_start, const int* __restrict__ cnt,
                           const int* __restrict__ bsum, int* cursor) {
    int i = blockIdx.x * SCAN_B + threadIdx.x;
    if (i >= NN) return;
    int off = (blockIdx.x > 0) ? bsum[blockIdx.x - 1] : 0;
    int st = incl_start[i] - cnt[i] + off;
    incl_start[i] = st;
    cursor[i] = st;
}

__global__ void k_exp1(const int* __restrict__ ei, const float* __restrict__ m1,
                       const float* __restrict__ ea1, float* den1,
                       int* cursor, int* csr_src, float* csr_val) {
    int e = blockIdx.x * blockDim.x + threadIdx.x;
    if (e >= NEP) return;
    int s, d;
    if (e < NE) { s = ei[e]; d = ei[NE + e]; }
    else        { s = d = e - NE; }
    float v = expf(ea1[e] - m1[d]);
    atomicAdd(&den1[d], v);
    int pos = atomicAdd(&cursor[d], 1);
    csr_src[pos] = s;
    csr_val[pos] = v;
}

// gather-accumulate + fused ELU/bias/W2-dot epilogue (out1 never materialized)
__global__ __launch_bounds__(256) void k_accum1_csr(const int* __restrict__ csr_src,
                                                    const float* __restrict__ csr_val,
                                                    const int* __restrict__ start,
                                                    const int* __restrict__ cnt,
                                                    const float* __restrict__ den1,
                                                    const float* __restrict__ h1,
                                                    const float* __restrict__ b1,
                                                    const float* __restrict__ W2,
                                                    float* __restrict__ h2) {
    int wid = threadIdx.x >> 6, l = threadIdx.x & 63;
    int d = blockIdx.x * 4 + wid;
    if (d >= NN) return;
    int s0 = start[d], n = cnt[d];
    float inv = 1.f / (den1[d] + 1e-16f);
    float ax = 0.f, ay = 0.f;
    for (int i = 0; i < n; ++i) {
        int s = csr_src[s0 + i];
        float c = csr_val[s0 + i] * inv;
        float2 hv = *(const float2*)&h1[(size_t)s * HD + 2 * l];
        ax += c * hv.x; ay += c * hv.y;
    }
    float2 bb = *(const float2*)&b1[2 * l];
    float2 w  = *(const float2*)&W2[2 * l];
    float a = ax + bb.x; a = (a > 0.f) ? a : (expf(a) - 1.f);
    float b = ay + bb.y; b = (b > 0.f) ? b : (expf(b) - 1.f);
    float p = a * w.x + b * w.y;
    p = wave_reduce_sum(p);
    if (l == 0) h2[d] = p;
}

// ---------------- layer-2 edge passes ----------------

__global__ void k_alpha2(const int* __restrict__ ei, const float* __restrict__ eattr,
                         const float* __restrict__ h2,
                         const float* __restrict__ as2, const float* __restrict__ ad2,
                         const float* __restrict__ sc, float* ea2, float* m2) {
    int e = blockIdx.x * blockDim.x + threadIdx.x;
    if (e >= NEP) return;
    int s, d; float av;
    if (e < NE) { s = ei[e]; d = ei[NE + e]; av = eattr[e]; }
    else        { s = d = e - NE; av = sc[0] * (1.0f / NE); }
    float a = as2[0] * h2[s] + ad2[0] * h2[d] + av * sc[2];
    a = (a > 0.f) ? a : 0.2f * a;
    ea2[e] = a;
    atomicMaxF(&m2[d], a);
}

__global__ void k_exp2(const int* __restrict__ ei, const float* __restrict__ m2,
                       float* ea2, float* den2) {
    int e = blockIdx.x * blockDim.x + threadIdx.x;
    if (e >= NEP) return;
    int d = (e < NE) ? ei[NE + e] : e - NE;
    float v = expf(ea2[e] - m2[d]);
    ea2[e] = v;
    atomicAdd(&den2[d], v);
}

__global__ void k_accum2(const int* __restrict__ ei, const float* __restrict__ ea2,
                         const float* __restrict__ den2, const float* __restrict__ h2,
                         float* o2a) {
    int e = blockIdx.x * blockDim.x + threadIdx.x;
    if (e >= NEP) return;
    int s, d;
    if (e < NE) { s = ei[e]; d = ei[NE + e]; }
    else        { s = d = e - NE; }
    atomicAdd(&o2a[d], ea2[e] / (den2[d] + 1e-16f) * h2[s]);
}

__global__ void k_final(const float* __restrict__ o2a, const float* __restrict__ b2,
                        float* __restrict__ out) {
    int i = blockIdx.x * blockDim.x + threadIdx.x;
    if (i >= NN) return;
    float v = o2a[i] + b2[0];
    out[i] = (v >= 0.f) ? v : 0.01f * v;
}

// ---------------- launch ----------------

extern "C" void kernel_launch(void* const* d_in, const int* in_sizes, int n_in,
                              void* d_out, int out_size, void* d_ws, size_t ws_size,
                              hipStream_t stream) {
    const float* x     = (const float*)d_in[0];
    const int*   ei    = (const int*)d_in[1];
    const float* eattr = (const float*)d_in[2];
    const float* W1    = (const float*)d_in[3];
    const float* asrc1 = (const float*)d_in[4];
    const float* adst1 = (const float*)d_in[5];
    const float* We1   = (const float*)d_in[6];
    const float* ae1   = (const float*)d_in[7];
    const float* b1    = (const float*)d_in[8];
    const float* W2    = (const float*)d_in[9];
    const float* as2   = (const float*)d_in[10];
    const float* ad2   = (const float*)d_in[11];
    const float* We2   = (const float*)d_in[12];
    const float* ae2   = (const float*)d_in[13];
    const float* b2    = (const float*)d_in[14];
    float* out = (float*)d_out;

    // workspace layout (~38.3 MB)
    float* w    = (float*)d_ws;
    float* h1   = w;                      // NH
    float* as1  = w + (size_t)NH;         // NN
    float* ad1  = as1 + NN;
    float* m1   = ad1 + NN;
    float* den1 = m1 + NN;
    float* h2   = den1 + NN;
    float* m2   = h2 + NN;
    float* den2 = m2 + NN;
    float* o2a  = den2 + NN;
    float* ea1  = o2a + NN;               // NEP
    float* csr_val = ea1 + NEP;           // NEP (reused as ea2 in layer 2)
    float* ea2  = csr_val;
    float* sc   = csr_val + NEP;          // 8 scalars
    int*   cnt    = (int*)(sc + 8);       // NN
    int*   start  = cnt + NN;             // NN
    int*   cursor = start + NN;           // NN
    int*   bsum   = cursor + NN;          // 256
    int*   csr_src = bsum + 256;          // NEP
    ushort* Wp   = (ushort*)(csr_src + NEP);  // WP_ELEMS bf16 (packed)

    k_init<<<(NH + 255) / 256, 256, 0, stream>>>(h1, m1, den1, m2, den2, o2a, cnt, sc);
    k_sum_attr<<<(NE + 255) / 256, 256, 0, stream>>>(eattr, sc);
    k_consts<<<1, 64, 0, stream>>>(We1, ae1, We2, ae2, sc);
    k_wt<<<(WP_ELEMS + 255) / 256, 256, 0, stream>>>(W1, Wp);

    k_gemm1_mfma<<<NROWB * 2, 256, 0, stream>>>(x, Wp, h1);
    k_rowdot<<<(NN + 3) / 4, 256, 0, stream>>>(h1, asrc1, adst1, as1, ad1);

    k_alpha1<<<(NEP + 255) / 256, 256, 0, stream>>>(ei, eattr, as1, ad1, sc, ea1, m1, cnt);
    k_scan_blk<<<NBLK, SCAN_B, 0, stream>>>(cnt, start, bsum);
    k_scan_top<<<1, SCAN_B, 0, stream>>>(bsum);
    k_scan_fix<<<NBLK, SCAN_B, 0, stream>>>(start, cnt, bsum, cursor);
    k_exp1<<<(NEP + 255) / 256, 256, 0, stream>>>(ei, m1, ea1, den1, cursor, csr_src, csr_val);
    k_accum1_csr<<<(NN + 3) / 4, 256, 0, stream>>>(csr_src, csr_val, start, cnt, den1, h1, b1, W2, h2);

    k_alpha2<<<(NEP + 255) / 256, 256, 0, stream>>>(ei, eattr, h2, as2, ad2, sc, ea2, m2);
    k_exp2<<<(NEP + 255) / 256, 256, 0, stream>>>(ei, m2, ea2, den2);
    k_accum2<<<(NEP + 255) / 256, 256, 0, stream>>>(ei, ea2, den2, h2, o2a);

    k_final<<<(NN + 255) / 256, 256, 0, stream>>>(o2a, b2, out);
}

// Round 7
// 677.597 us; speedup vs baseline: 1.1637x; 1.0366x over previous
//
#include <hip/hip_runtime.h>
#include <math.h>

#define NN 50000
#define NE 800000
#define NEP 850000          // NE + NN self loops
#define FI 1284
#define HD 128
#define KP 1312             // FI padded to 41*32 for MFMA K-loop
#define NSTEP 41            // KP/32
#define NH (NN * HD)        // 6,400,000
#define SCAN_B 256
#define NBLK ((NN + SCAN_B - 1) / SCAN_B)   // 196 (<=256)
#define NROWB ((NN + 63) / 64)              // 782 row-blocks of 64
#define WP_ELEMS (NSTEP * 4096)             // packed B: 41 steps * 8cg * 64lane * 8

typedef float f32x4 __attribute__((ext_vector_type(4)));
typedef short bfrag __attribute__((ext_vector_type(8)));   // 8 bf16 in 4 VGPRs

// ---------------- helpers ----------------

__device__ __forceinline__ void atomicMaxF(float* addr, float v) {
    if (v >= 0.f) atomicMax((int*)addr, __float_as_int(v));
    else          atomicMin((unsigned int*)addr, __float_as_uint(v));
}

__device__ __forceinline__ float wave_reduce_sum(float v) {
    #pragma unroll
    for (int off = 32; off; off >>= 1) v += __shfl_down(v, off);
    return v;
}

__device__ __forceinline__ ushort f2bf(float f) {   // RNE fp32->bf16 bits
    unsigned u = __float_as_uint(f);
    u += 0x7FFFu + ((u >> 16) & 1u);
    return (ushort)(u >> 16);
}

__device__ __forceinline__ bfrag cvt_frag(float4 a0, float4 a1) {
    bfrag af;
    af[0] = (short)f2bf(a0.x); af[1] = (short)f2bf(a0.y);
    af[2] = (short)f2bf(a0.z); af[3] = (short)f2bf(a0.w);
    af[4] = (short)f2bf(a1.x); af[5] = (short)f2bf(a1.y);
    af[6] = (short)f2bf(a1.z); af[7] = (short)f2bf(a1.w);
    return af;
}

// ---------------- init ----------------

__global__ void k_init(float* m1, float* den1, float* m2, float* den2,
                       float* o2a, int* cnt, float* sc) {
    int i = blockIdx.x * blockDim.x + threadIdx.x;
    if (i < NN) {
        m1[i]  = -INFINITY; den1[i] = 0.f;
        m2[i]  = -INFINITY; den2[i] = 0.f;
        o2a[i] = 0.f;
        cnt[i] = 0;
    }
    if (i < 8) sc[i] = 0.f;
}

__global__ void k_sum_attr(const float* __restrict__ eattr, float* sc) {
    int i = blockIdx.x * blockDim.x + threadIdx.x;
    float v = (i < NE) ? eattr[i] : 0.f;
    v = wave_reduce_sum(v);
    if ((threadIdx.x & 63) == 0) atomicAdd(&sc[0], v);
}

__global__ void k_consts(const float* We1, const float* ae1,
                         const float* We2, const float* ae2, float* sc) {
    int l = threadIdx.x;  // 64 threads
    float v = We1[l] * ae1[l] + We1[l + 64] * ae1[l + 64];
    v = wave_reduce_sum(v);
    if (l == 0) { sc[1] = v; sc[2] = We2[0] * ae2[0]; }
}

// Packed B: Wp[s][cg][lane][j] = bf16(W1[k][c]), k = s*32 + (lane>>4)*8 + j,
// c = cg*16 + (lane&15); zero-padded for k >= FI. Load-order contiguous.
__global__ void k_wt(const float* __restrict__ W, ushort* __restrict__ Wp) {
    int i = blockIdx.x * 256 + threadIdx.x;
    if (i >= WP_ELEMS) return;
    int s = i >> 12;
    int r = i & 4095;
    int cg = r >> 9;
    int q = r & 511;
    int lane = q >> 3, j = q & 7;
    int k = s * 32 + (lane >> 4) * 8 + j;
    int c = cg * 16 + (lane & 15);
    float v = (k < FI) ? W[(size_t)k * HD + c] : 0.f;
    Wp[i] = f2bf(v);
}

// ---------------- GEMM1: h1 = x @ W1  (bf16 MFMA, LDS-staged A via global_load_lds) ----------------
// 4 waves/block, BM=64 (wave slab = 16 rows), BN=128, BK=32 floats, double-buffered LDS.
// A staged fp32 with XOR chunk-swizzle: LDS slot p of row r holds global chunk p^(r&7)
// (pre-swizzled global source, linear LDS dest; reads apply same XOR) -> no bank conflicts.
// B from packed Wp (L2-resident) to registers. Tail step 40 peeled (direct global A).

__global__ __launch_bounds__(256) void k_gemm1_mfma(const float* __restrict__ x,
                                                    const ushort* __restrict__ Wp,
                                                    float* __restrict__ h1) {
    __shared__ float As[2][64][32];   // 16 KB
    const int t = threadIdx.x;
    const int wid = t >> 6, l = t & 63;
    const int lr = l & 15, lg = l >> 4;
    const int wrow0 = blockIdx.x * 64 + wid * 16;

    // staging: inst i covers slab rows i*8..i*8+7; lane l -> row i*8 + l/8, slot l%8.
    // slot p of row r must hold global chunk p^(r&7); here r&7 == l/8.
    const int srow = l >> 3;
    const int schunk = (l & 7) ^ srow;
    int g0 = wrow0 + srow;      if (g0 > NN - 1) g0 = NN - 1;
    int g1 = wrow0 + 8 + srow;  if (g1 > NN - 1) g1 = NN - 1;
    const float* sp0 = x + (size_t)g0 * FI + schunk * 4;
    const float* sp1 = x + (size_t)g1 * FI + schunk * 4;

    // swizzled read slots for this lane (chunk c of row lr lives at slot c^(lr&7))
    const int rs0 = (lg * 2)     ^ (lr & 7);
    const int rs1 = (lg * 2 + 1) ^ (lr & 7);

    const ushort* wq = Wp + l * 8;

    f32x4 acc[8];
    #pragma unroll
    for (int c = 0; c < 8; ++c) acc[c] = (f32x4){0.f, 0.f, 0.f, 0.f};

#define STAGE(B, K0) do { \
    __builtin_amdgcn_global_load_lds( \
        (const __attribute__((address_space(1))) unsigned int*)(sp0 + (K0)), \
        (__attribute__((address_space(3))) unsigned int*)&As[B][wid * 16][0], 16, 0, 0); \
    __builtin_amdgcn_global_load_lds( \
        (const __attribute__((address_space(1))) unsigned int*)(sp1 + (K0)), \
        (__attribute__((address_space(3))) unsigned int*)&As[B][wid * 16 + 8][0], 16, 0, 0); \
} while (0)

    STAGE(0, 0);
    __syncthreads();

    for (int it = 0; it < 40; ++it) {
        const int bsel = it & 1;
        if (it < 39) STAGE((it + 1) & 1, (it + 1) * 32);   // async, flies during compute

        const ushort* wqs = wq + (size_t)it * 4096;
        bfrag bfr[8];
        #pragma unroll
        for (int cg = 0; cg < 4; ++cg) bfr[cg]     = *(const bfrag*)(wqs + cg * 512);
        #pragma unroll
        for (int cg = 0; cg < 4; ++cg) bfr[4 + cg] = *(const bfrag*)(wqs + 2048 + cg * 512);

        float4 a0 = *(const float4*)&As[bsel][wid * 16 + lr][rs0 * 4];
        float4 a1 = *(const float4*)&As[bsel][wid * 16 + lr][rs1 * 4];
        bfrag af = cvt_frag(a0, a1);
        #pragma unroll
        for (int cg = 0; cg < 8; ++cg)
            acc[cg] = __builtin_amdgcn_mfma_f32_16x16x32_bf16(af, bfr[cg], acc[cg], 0, 0, 0);

        __syncthreads();   // drains stage(it+1), guards buffer reuse
    }
#undef STAGE

    {   // K tail: step 40 (k0=1280, valid k<1284 in lg==0 low half); Wp zero-padded
        int rowc = wrow0 + lr; if (rowc > NN - 1) rowc = NN - 1;
        float4 a0t = make_float4(0.f, 0.f, 0.f, 0.f);
        if (lg == 0) a0t = *(const float4*)(x + (size_t)rowc * FI + 1280);
        bfrag af;
        af[0] = (short)f2bf(a0t.x); af[1] = (short)f2bf(a0t.y);
        af[2] = (short)f2bf(a0t.z); af[3] = (short)f2bf(a0t.w);
        af[4] = 0; af[5] = 0; af[6] = 0; af[7] = 0;
        const ushort* wqs = wq + (size_t)40 * 4096;
        bfrag bfr[8];
        #pragma unroll
        for (int cg = 0; cg < 4; ++cg) bfr[cg]     = *(const bfrag*)(wqs + cg * 512);
        #pragma unroll
        for (int cg = 0; cg < 4; ++cg) bfr[4 + cg] = *(const bfrag*)(wqs + 2048 + cg * 512);
        #pragma unroll
        for (int cg = 0; cg < 8; ++cg)
            acc[cg] = __builtin_amdgcn_mfma_f32_16x16x32_bf16(af, bfr[cg], acc[cg], 0, 0, 0);
    }

    #pragma unroll
    for (int cg = 0; cg < 8; ++cg) {
        #pragma unroll
        for (int r = 0; r < 4; ++r) {
            int gr = wrow0 + lg * 4 + r;
            if (gr < NN) h1[(size_t)gr * HD + cg * 16 + lr] = acc[cg][r];
        }
    }
}

__global__ __launch_bounds__(256) void k_rowdot(const float* __restrict__ h1,
                                                const float* __restrict__ asrc,
                                                const float* __restrict__ adst,
                                                float* as1, float* ad1) {
    int wid = threadIdx.x >> 6, l = threadIdx.x & 63;
    int i = blockIdx.x * 4 + wid;
    if (i >= NN) return;
    float2 hv = *(const float2*)&h1[(size_t)i * HD + 2 * l];
    float2 av = *(const float2*)&asrc[2 * l];
    float2 dv = *(const float2*)&adst[2 * l];
    float s = hv.x * av.x + hv.y * av.y;
    float d = hv.x * dv.x + hv.y * dv.y;
    #pragma unroll
    for (int off = 32; off; off >>= 1) {
        s += __shfl_down(s, off);
        d += __shfl_down(d, off);
    }
    if (l == 0) { as1[i] = s; ad1[i] = d; }
}

// ---------------- layer-1 edge passes ----------------

__global__ void k_alpha1(const int* __restrict__ ei, const float* __restrict__ eattr,
                         const float* __restrict__ as1, const float* __restrict__ ad1,
                         const float* __restrict__ sc, float* ea1, float* m1, int* cnt) {
    int e = blockIdx.x * blockDim.x + threadIdx.x;
    if (e >= NEP) return;
    int s, d; float av;
    if (e < NE) { s = ei[e]; d = ei[NE + e]; av = eattr[e]; }
    else        { s = d = e - NE; av = sc[0] * (1.0f / NE); }
    float a = as1[s] + ad1[d] + av * sc[1];
    a = (a > 0.f) ? a : 0.2f * a;
    ea1[e] = a;
    atomicMaxF(&m1[d], a);
    atomicAdd(&cnt[d], 1);
}

// ---------------- exclusive scan of cnt -> start ----------------

__global__ void k_scan_blk(const int* __restrict__ cnt, int* incl, int* bsum) {
    __shared__ int sh[SCAN_B];
    int i = blockIdx.x * SCAN_B + threadIdx.x;
    sh[threadIdx.x] = (i < NN) ? cnt[i] : 0;
    __syncthreads();
    for (int off = 1; off < SCAN_B; off <<= 1) {
        int t = (threadIdx.x >= off) ? sh[threadIdx.x - off] : 0;
        __syncthreads();
        sh[threadIdx.x] += t;
        __syncthreads();
    }
    if (i < NN) incl[i] = sh[threadIdx.x];
    if (threadIdx.x == SCAN_B - 1) bsum[blockIdx.x] = sh[threadIdx.x];
}

__global__ void k_scan_top(int* bsum) {
    __shared__ int sh[SCAN_B];
    sh[threadIdx.x] = (threadIdx.x < NBLK) ? bsum[threadIdx.x] : 0;
    __syncthreads();
    for (int off = 1; off < SCAN_B; off <<= 1) {
        int t = (threadIdx.x >= off) ? sh[threadIdx.x - off] : 0;
        __syncthreads();
        sh[threadIdx.x] += t;
        __syncthreads();
    }
    if (threadIdx.x < NBLK) bsum[threadIdx.x] = sh[threadIdx.x];
}

__global__ void k_scan_fix(int* incl_start, const int* __restrict__ cnt,
                           const int* __restrict__ bsum, int* cursor) {
    int i = blockIdx.x * SCAN_B + threadIdx.x;
    if (i >= NN) return;
    int off = (blockIdx.x > 0) ? bsum[blockIdx.x - 1] : 0;
    int st = incl_start[i] - cnt[i] + off;
    incl_start[i] = st;
    cursor[i] = st;
}

__global__ void k_exp1(const int* __restrict__ ei, const float* __restrict__ m1,
                       const float* __restrict__ ea1, float* den1,
                       int* cursor, int* csr_src, float* csr_val) {
    int e = blockIdx.x * blockDim.x + threadIdx.x;
    if (e >= NEP) return;
    int s, d;
    if (e < NE) { s = ei[e]; d = ei[NE + e]; }
    else        { s = d = e - NE; }
    float v = expf(ea1[e] - m1[d]);
    atomicAdd(&den1[d], v);
    int pos = atomicAdd(&cursor[d], 1);
    csr_src[pos] = s;
    csr_val[pos] = v;
}

// gather-accumulate + fused ELU/bias/W2-dot epilogue (out1 never materialized)
__global__ __launch_bounds__(256) void k_accum1_csr(const int* __restrict__ csr_src,
                                                    const float* __restrict__ csr_val,
                                                    const int* __restrict__ start,
                                                    const int* __restrict__ cnt,
                                                    const float* __restrict__ den1,
                                                    const float* __restrict__ h1,
                                                    const float* __restrict__ b1,
                                                    const float* __restrict__ W2,
                                                    float* __restrict__ h2) {
    int wid = threadIdx.x >> 6, l = threadIdx.x & 63;
    int d = blockIdx.x * 4 + wid;
    if (d >= NN) return;
    int s0 = start[d], n = cnt[d];
    float inv = 1.f / (den1[d] + 1e-16f);
    float ax = 0.f, ay = 0.f;
    for (int i = 0; i < n; ++i) {
        int s = csr_src[s0 + i];
        float c = csr_val[s0 + i] * inv;
        float2 hv = *(const float2*)&h1[(size_t)s * HD + 2 * l];
        ax += c * hv.x; ay += c * hv.y;
    }
    float2 bb = *(const float2*)&b1[2 * l];
    float2 w  = *(const float2*)&W2[2 * l];
    float a = ax + bb.x; a = (a > 0.f) ? a : (expf(a) - 1.f);
    float b = ay + bb.y; b = (b > 0.f) ? b : (expf(b) - 1.f);
    float p = a * w.x + b * w.y;
    p = wave_reduce_sum(p);
    if (l == 0) h2[d] = p;
}

// ---------------- layer-2 edge passes ----------------

__global__ void k_alpha2(const int* __restrict__ ei, const float* __restrict__ eattr,
                         const float* __restrict__ h2,
                         const float* __restrict__ as2, const float* __restrict__ ad2,
                         const float* __restrict__ sc, float* ea2, float* m2) {
    int e = blockIdx.x * blockDim.x + threadIdx.x;
    if (e >= NEP) return;
    int s, d; float av;
    if (e < NE) { s = ei[e]; d = ei[NE + e]; av = eattr[e]; }
    else        { s = d = e - NE; av = sc[0] * (1.0f / NE); }
    float a = as2[0] * h2[s] + ad2[0] * h2[d] + av * sc[2];
    a = (a > 0.f) ? a : 0.2f * a;
    ea2[e] = a;
    atomicMaxF(&m2[d], a);
}

__global__ void k_exp2(const int* __restrict__ ei, const float* __restrict__ m2,
                       float* ea2, float* den2) {
    int e = blockIdx.x * blockDim.x + threadIdx.x;
    if (e >= NEP) return;
    int d = (e < NE) ? ei[NE + e] : e - NE;
    float v = expf(ea2[e] - m2[d]);
    ea2[e] = v;
    atomicAdd(&den2[d], v);
}

__global__ void k_accum2(const int* __restrict__ ei, const float* __restrict__ ea2,
                         const float* __restrict__ den2, const float* __restrict__ h2,
                         float* o2a) {
    int e = blockIdx.x * blockDim.x + threadIdx.x;
    if (e >= NEP) return;
    int s, d;
    if (e < NE) { s = ei[e]; d = ei[NE + e]; }
    else        { s = d = e - NE; }
    atomicAdd(&o2a[d], ea2[e] / (den2[d] + 1e-16f) * h2[s]);
}

__global__ void k_final(const float* __restrict__ o2a, const float* __restrict__ b2,
                        float* __restrict__ out) {
    int i = blockIdx.x * blockDim.x + threadIdx.x;
    if (i >= NN) return;
    float v = o2a[i] + b2[0];
    out[i] = (v >= 0.f) ? v : 0.01f * v;
}

// ---------------- launch ----------------

extern "C" void kernel_launch(void* const* d_in, const int* in_sizes, int n_in,
                              void* d_out, int out_size, void* d_ws, size_t ws_size,
                              hipStream_t stream) {
    const float* x     = (const float*)d_in[0];
    const int*   ei    = (const int*)d_in[1];
    const float* eattr = (const float*)d_in[2];
    const float* W1    = (const float*)d_in[3];
    const float* asrc1 = (const float*)d_in[4];
    const float* adst1 = (const float*)d_in[5];
    const float* We1   = (const float*)d_in[6];
    const float* ae1   = (const float*)d_in[7];
    const float* b1    = (const float*)d_in[8];
    const float* W2    = (const float*)d_in[9];
    const float* as2   = (const float*)d_in[10];
    const float* ad2   = (const float*)d_in[11];
    const float* We2   = (const float*)d_in[12];
    const float* ae2   = (const float*)d_in[13];
    const float* b2    = (const float*)d_in[14];
    float* out = (float*)d_out;

    // workspace layout (~38.3 MB)
    float* w    = (float*)d_ws;
    float* h1   = w;                      // NH
    float* as1  = w + (size_t)NH;         // NN
    float* ad1  = as1 + NN;
    float* m1   = ad1 + NN;
    float* den1 = m1 + NN;
    float* h2   = den1 + NN;
    float* m2   = h2 + NN;
    float* den2 = m2 + NN;
    float* o2a  = den2 + NN;
    float* ea1  = o2a + NN;               // NEP
    float* csr_val = ea1 + NEP;           // NEP (reused as ea2 in layer 2)
    float* ea2  = csr_val;
    float* sc   = csr_val + NEP;          // 8 scalars
    int*   cnt    = (int*)(sc + 8);       // NN
    int*   start  = cnt + NN;             // NN
    int*   cursor = start + NN;           // NN
    int*   bsum   = cursor + NN;          // 256
    int*   csr_src = bsum + 256;          // NEP
    ushort* Wp   = (ushort*)(csr_src + NEP);  // WP_ELEMS bf16 (packed)

    k_init<<<(NN + 255) / 256, 256, 0, stream>>>(m1, den1, m2, den2, o2a, cnt, sc);
    k_sum_attr<<<(NE + 255) / 256, 256, 0, stream>>>(eattr, sc);
    k_consts<<<1, 64, 0, stream>>>(We1, ae1, We2, ae2, sc);
    k_wt<<<(WP_ELEMS + 255) / 256, 256, 0, stream>>>(W1, Wp);

    k_gemm1_mfma<<<NROWB, 256, 0, stream>>>(x, Wp, h1);
    k_rowdot<<<(NN + 3) / 4, 256, 0, stream>>>(h1, asrc1, adst1, as1, ad1);

    k_alpha1<<<(NEP + 255) / 256, 256, 0, stream>>>(ei, eattr, as1, ad1, sc, ea1, m1, cnt);
    k_scan_blk<<<NBLK, SCAN_B, 0, stream>>>(cnt, start, bsum);
    k_scan_top<<<1, SCAN_B, 0, stream>>>(bsum);
    k_scan_fix<<<NBLK, SCAN_B, 0, stream>>>(start, cnt, bsum, cursor);
    k_exp1<<<(NEP + 255) / 256, 256, 0, stream>>>(ei, m1, ea1, den1, cursor, csr_src, csr_val);
    k_accum1_csr<<<(NN + 3) / 4, 256, 0, stream>>>(csr_src, csr_val, start, cnt, den1, h1, b1, W2, h2);

    k_alpha2<<<(NEP + 255) / 256, 256, 0, stream>>>(ei, eattr, h2, as2, ad2, sc, ea2, m2);
    k_exp2<<<(NEP + 255) / 256, 256, 0, stream>>>(ei, m2, ea2, den2);
    k_accum2<<<(NEP + 255) / 256, 256, 0, stream>>>(ei, ea2, den2, h2, o2a);

    k_final<<<(NN + 255) / 256, 256, 0, stream>>>(o2a, b2, out);
}

// Round 8
// 526.140 us; speedup vs baseline: 1.4987x; 1.2879x over previous
//
#include <hip/hip_runtime.h>
#include <math.h>

#define NN 50000
#define NE 800000
#define NEP 850000          // NE + NN self loops
#define FI 1284
#define HD 128
#define KP 1312             // FI padded to 41*32 for MFMA K-loop
#define NSTEP 41            // KP/32
#define NH (NN * HD)        // 6,400,000
#define SCAN_B 256
#define NBLK ((NN + SCAN_B - 1) / SCAN_B)   // 196 (<=256)
#define NROWB ((NN + 63) / 64)              // 782 row-blocks of 64
#define WP_ELEMS (NSTEP * 4096)             // packed B: 41 steps * 8cg * 64lane * 8

typedef float f32x4 __attribute__((ext_vector_type(4)));
typedef short bfrag __attribute__((ext_vector_type(8)));   // 8 bf16 in 4 VGPRs

// ---------------- helpers ----------------

__device__ __forceinline__ void atomicMaxF(float* addr, float v) {
    if (v >= 0.f) atomicMax((int*)addr, __float_as_int(v));
    else          atomicMin((unsigned int*)addr, __float_as_uint(v));
}

__device__ __forceinline__ float wave_reduce_sum(float v) {
    #pragma unroll
    for (int off = 32; off; off >>= 1) v += __shfl_down(v, off);
    return v;
}

__device__ __forceinline__ ushort f2bf(float f) {   // RNE fp32->bf16 bits
    unsigned u = __float_as_uint(f);
    u += 0x7FFFu + ((u >> 16) & 1u);
    return (ushort)(u >> 16);
}

__device__ __forceinline__ bfrag cvt_frag(float4 a0, float4 a1) {
    bfrag af;
    af[0] = (short)f2bf(a0.x); af[1] = (short)f2bf(a0.y);
    af[2] = (short)f2bf(a0.z); af[3] = (short)f2bf(a0.w);
    af[4] = (short)f2bf(a1.x); af[5] = (short)f2bf(a1.y);
    af[6] = (short)f2bf(a1.z); af[7] = (short)f2bf(a1.w);
    return af;
}

// ---------------- init ----------------

__global__ void k_init(float* m1, float* den1, float* m2, float* den2,
                       float* o2a, int* cnt, float* sc) {
    int i = blockIdx.x * blockDim.x + threadIdx.x;
    if (i < NN) {
        m1[i]  = -INFINITY; den1[i] = 0.f;
        m2[i]  = -INFINITY; den2[i] = 0.f;
        o2a[i] = 0.f;
        cnt[i] = 0;
    }
    if (i < 8) sc[i] = 0.f;
}

// grid-stride block reduction: 256 blocks -> 256 same-address atomics (was 12500)
__global__ __launch_bounds__(256) void k_sum_attr(const float* __restrict__ eattr, float* sc) {
    __shared__ float wsum[4];
    float v = 0.f;
    for (int i = blockIdx.x * 256 + threadIdx.x; i < NE; i += 256 * 256)
        v += eattr[i];
    v = wave_reduce_sum(v);
    int wid = threadIdx.x >> 6, l = threadIdx.x & 63;
    if (l == 0) wsum[wid] = v;
    __syncthreads();
    if (threadIdx.x == 0)
        atomicAdd(&sc[0], wsum[0] + wsum[1] + wsum[2] + wsum[3]);
}

__global__ void k_consts(const float* We1, const float* ae1,
                         const float* We2, const float* ae2, float* sc) {
    int l = threadIdx.x;  // 64 threads
    float v = We1[l] * ae1[l] + We1[l + 64] * ae1[l + 64];
    v = wave_reduce_sum(v);
    if (l == 0) { sc[1] = v; sc[2] = We2[0] * ae2[0]; }
}

// Packed B: Wp[s][cg][lane][j] = bf16(W1[k][c]), k = s*32 + (lane>>4)*8 + j,
// c = cg*16 + (lane&15); zero-padded for k >= FI. Load-order contiguous.
__global__ void k_wt(const float* __restrict__ W, ushort* __restrict__ Wp) {
    int i = blockIdx.x * 256 + threadIdx.x;
    if (i >= WP_ELEMS) return;
    int s = i >> 12;
    int r = i & 4095;
    int cg = r >> 9;
    int q = r & 511;
    int lane = q >> 3, j = q & 7;
    int k = s * 32 + (lane >> 4) * 8 + j;
    int c = cg * 16 + (lane & 15);
    float v = (k < FI) ? W[(size_t)k * HD + c] : 0.f;
    Wp[i] = f2bf(v);
}

// ---------------- GEMM1: h1 = x @ W1  (bf16 MFMA, LDS-staged A via global_load_lds) ----------------
// 4 waves/block, BM=64 (wave slab = 16 rows), BN=128, BK=32 floats, double-buffered LDS.
// A staged fp32 with XOR chunk-swizzle: LDS slot p of row r holds global chunk p^(r&7)
// (pre-swizzled global source, linear LDS dest; reads apply same XOR) -> no bank conflicts.
// B from packed Wp (L2-resident) to registers. Tail step 40 peeled (direct global A).

__global__ __launch_bounds__(256) void k_gemm1_mfma(const float* __restrict__ x,
                                                    const ushort* __restrict__ Wp,
                                                    float* __restrict__ h1) {
    __shared__ float As[2][64][32];   // 16 KB
    const int t = threadIdx.x;
    const int wid = t >> 6, l = t & 63;
    const int lr = l & 15, lg = l >> 4;
    const int wrow0 = blockIdx.x * 64 + wid * 16;

    // staging: inst i covers slab rows i*8..i*8+7; lane l -> row i*8 + l/8, slot l%8.
    // slot p of row r must hold global chunk p^(r&7); here r&7 == l/8.
    const int srow = l >> 3;
    const int schunk = (l & 7) ^ srow;
    int g0 = wrow0 + srow;      if (g0 > NN - 1) g0 = NN - 1;
    int g1 = wrow0 + 8 + srow;  if (g1 > NN - 1) g1 = NN - 1;
    const float* sp0 = x + (size_t)g0 * FI + schunk * 4;
    const float* sp1 = x + (size_t)g1 * FI + schunk * 4;

    // swizzled read slots for this lane (chunk c of row lr lives at slot c^(lr&7))
    const int rs0 = (lg * 2)     ^ (lr & 7);
    const int rs1 = (lg * 2 + 1) ^ (lr & 7);

    const ushort* wq = Wp + l * 8;

    f32x4 acc[8];
    #pragma unroll
    for (int c = 0; c < 8; ++c) acc[c] = (f32x4){0.f, 0.f, 0.f, 0.f};

#define STAGE(B, K0) do { \
    __builtin_amdgcn_global_load_lds( \
        (const __attribute__((address_space(1))) unsigned int*)(sp0 + (K0)), \
        (__attribute__((address_space(3))) unsigned int*)&As[B][wid * 16][0], 16, 0, 0); \
    __builtin_amdgcn_global_load_lds( \
        (const __attribute__((address_space(1))) unsigned int*)(sp1 + (K0)), \
        (__attribute__((address_space(3))) unsigned int*)&As[B][wid * 16 + 8][0], 16, 0, 0); \
} while (0)

    STAGE(0, 0);
    __syncthreads();

    for (int it = 0; it < 40; ++it) {
        const int bsel = it & 1;
        if (it < 39) STAGE((it + 1) & 1, (it + 1) * 32);   // async, flies during compute

        const ushort* wqs = wq + (size_t)it * 4096;
        bfrag bfr[8];
        #pragma unroll
        for (int cg = 0; cg < 4; ++cg) bfr[cg]     = *(const bfrag*)(wqs + cg * 512);
        #pragma unroll
        for (int cg = 0; cg < 4; ++cg) bfr[4 + cg] = *(const bfrag*)(wqs + 2048 + cg * 512);

        float4 a0 = *(const float4*)&As[bsel][wid * 16 + lr][rs0 * 4];
        float4 a1 = *(const float4*)&As[bsel][wid * 16 + lr][rs1 * 4];
        bfrag af = cvt_frag(a0, a1);
        #pragma unroll
        for (int cg = 0; cg < 8; ++cg)
            acc[cg] = __builtin_amdgcn_mfma_f32_16x16x32_bf16(af, bfr[cg], acc[cg], 0, 0, 0);

        __syncthreads();   // drains stage(it+1), guards buffer reuse
    }
#undef STAGE

    {   // K tail: step 40 (k0=1280, valid k<1284 in lg==0 low half); Wp zero-padded
        int rowc = wrow0 + lr; if (rowc > NN - 1) rowc = NN - 1;
        float4 a0t = make_float4(0.f, 0.f, 0.f, 0.f);
        if (lg == 0) a0t = *(const float4*)(x + (size_t)rowc * FI + 1280);
        bfrag af;
        af[0] = (short)f2bf(a0t.x); af[1] = (short)f2bf(a0t.y);
        af[2] = (short)f2bf(a0t.z); af[3] = (short)f2bf(a0t.w);
        af[4] = 0; af[5] = 0; af[6] = 0; af[7] = 0;
        const ushort* wqs = wq + (size_t)40 * 4096;
        bfrag bfr[8];
        #pragma unroll
        for (int cg = 0; cg < 4; ++cg) bfr[cg]     = *(const bfrag*)(wqs + cg * 512);
        #pragma unroll
        for (int cg = 0; cg < 4; ++cg) bfr[4 + cg] = *(const bfrag*)(wqs + 2048 + cg * 512);
        #pragma unroll
        for (int cg = 0; cg < 8; ++cg)
            acc[cg] = __builtin_amdgcn_mfma_f32_16x16x32_bf16(af, bfr[cg], acc[cg], 0, 0, 0);
    }

    #pragma unroll
    for (int cg = 0; cg < 8; ++cg) {
        #pragma unroll
        for (int r = 0; r < 4; ++r) {
            int gr = wrow0 + lg * 4 + r;
            if (gr < NN) h1[(size_t)gr * HD + cg * 16 + lr] = acc[cg][r];
        }
    }
}

__global__ __launch_bounds__(256) void k_rowdot(const float* __restrict__ h1,
                                                const float* __restrict__ asrc,
                                                const float* __restrict__ adst,
                                                float* as1, float* ad1) {
    int wid = threadIdx.x >> 6, l = threadIdx.x & 63;
    int i = blockIdx.x * 4 + wid;
    if (i >= NN) return;
    float2 hv = *(const float2*)&h1[(size_t)i * HD + 2 * l];
    float2 av = *(const float2*)&asrc[2 * l];
    float2 dv = *(const float2*)&adst[2 * l];
    float s = hv.x * av.x + hv.y * av.y;
    float d = hv.x * dv.x + hv.y * dv.y;
    #pragma unroll
    for (int off = 32; off; off >>= 1) {
        s += __shfl_down(s, off);
        d += __shfl_down(d, off);
    }
    if (l == 0) { as1[i] = s; ad1[i] = d; }
}

// ---------------- layer-1 edge passes ----------------

__global__ void k_alpha1(const int* __restrict__ ei, const float* __restrict__ eattr,
                         const float* __restrict__ as1, const float* __restrict__ ad1,
                         const float* __restrict__ sc, float* ea1, float* m1, int* cnt) {
    int e = blockIdx.x * blockDim.x + threadIdx.x;
    if (e >= NEP) return;
    int s, d; float av;
    if (e < NE) { s = ei[e]; d = ei[NE + e]; av = eattr[e]; }
    else        { s = d = e - NE; av = sc[0] * (1.0f / NE); }
    float a = as1[s] + ad1[d] + av * sc[1];
    a = (a > 0.f) ? a : 0.2f * a;
    ea1[e] = a;
    atomicMaxF(&m1[d], a);
    atomicAdd(&cnt[d], 1);
}

// ---------------- exclusive scan of cnt -> start ----------------

__global__ void k_scan_blk(const int* __restrict__ cnt, int* incl, int* bsum) {
    __shared__ int sh[SCAN_B];
    int i = blockIdx.x * SCAN_B + threadIdx.x;
    sh[threadIdx.x] = (i < NN) ? cnt[i] : 0;
    __syncthreads();
    for (int off = 1; off < SCAN_B; off <<= 1) {
        int t = (threadIdx.x >= off) ? sh[threadIdx.x - off] : 0;
        __syncthreads();
        sh[threadIdx.x] += t;
        __syncthreads();
    }
    if (i < NN) incl[i] = sh[threadIdx.x];
    if (threadIdx.x == SCAN_B - 1) bsum[blockIdx.x] = sh[threadIdx.x];
}

__global__ void k_scan_top(int* bsum) {
    __shared__ int sh[SCAN_B];
    sh[threadIdx.x] = (threadIdx.x < NBLK) ? bsum[threadIdx.x] : 0;
    __syncthreads();
    for (int off = 1; off < SCAN_B; off <<= 1) {
        int t = (threadIdx.x >= off) ? sh[threadIdx.x - off] : 0;
        __syncthreads();
        sh[threadIdx.x] += t;
        __syncthreads();
    }
    if (threadIdx.x < NBLK) bsum[threadIdx.x] = sh[threadIdx.x];
}

__global__ void k_scan_fix(int* incl_start, const int* __restrict__ cnt,
                           const int* __restrict__ bsum, int* cursor) {
    int i = blockIdx.x * SCAN_B + threadIdx.x;
    if (i >= NN) return;
    int off = (blockIdx.x > 0) ? bsum[blockIdx.x - 1] : 0;
    int st = incl_start[i] - cnt[i] + off;
    incl_start[i] = st;
    cursor[i] = st;
}

__global__ void k_exp1(const int* __restrict__ ei, const float* __restrict__ m1,
                       const float* __restrict__ ea1, float* den1,
                       int* cursor, int* csr_src, float* csr_val) {
    int e = blockIdx.x * blockDim.x + threadIdx.x;
    if (e >= NEP) return;
    int s, d;
    if (e < NE) { s = ei[e]; d = ei[NE + e]; }
    else        { s = d = e - NE; }
    float v = expf(ea1[e] - m1[d]);
    atomicAdd(&den1[d], v);
    int pos = atomicAdd(&cursor[d], 1);
    csr_src[pos] = s;
    csr_val[pos] = v;
}

// gather-accumulate + fused ELU/bias/W2-dot epilogue (out1 never materialized)
__global__ __launch_bounds__(256) void k_accum1_csr(const int* __restrict__ csr_src,
                                                    const float* __restrict__ csr_val,
                                                    const int* __restrict__ start,
                                                    const int* __restrict__ cnt,
                                                    const float* __restrict__ den1,
                                                    const float* __restrict__ h1,
                                                    const float* __restrict__ b1,
                                                    const float* __restrict__ W2,
                                                    float* __restrict__ h2) {
    int wid = threadIdx.x >> 6, l = threadIdx.x & 63;
    int d = blockIdx.x * 4 + wid;
    if (d >= NN) return;
    int s0 = start[d], n = cnt[d];
    float inv = 1.f / (den1[d] + 1e-16f);
    float ax = 0.f, ay = 0.f;
    for (int i = 0; i < n; ++i) {
        int s = csr_src[s0 + i];
        float c = csr_val[s0 + i] * inv;
        float2 hv = *(const float2*)&h1[(size_t)s * HD + 2 * l];
        ax += c * hv.x; ay += c * hv.y;
    }
    float2 bb = *(const float2*)&b1[2 * l];
    float2 w  = *(const float2*)&W2[2 * l];
    float a = ax + bb.x; a = (a > 0.f) ? a : (expf(a) - 1.f);
    float b = ay + bb.y; b = (b > 0.f) ? b : (expf(b) - 1.f);
    float p = a * w.x + b * w.y;
    p = wave_reduce_sum(p);
    if (l == 0) h2[d] = p;
}

// ---------------- layer-2 edge passes ----------------

__global__ void k_alpha2(const int* __restrict__ ei, const float* __restrict__ eattr,
                         const float* __restrict__ h2,
                         const float* __restrict__ as2, const float* __restrict__ ad2,
                         const float* __restrict__ sc, float* ea2, float* m2) {
    int e = blockIdx.x * blockDim.x + threadIdx.x;
    if (e >= NEP) return;
    int s, d; float av;
    if (e < NE) { s = ei[e]; d = ei[NE + e]; av = eattr[e]; }
    else        { s = d = e - NE; av = sc[0] * (1.0f / NE); }
    float a = as2[0] * h2[s] + ad2[0] * h2[d] + av * sc[2];
    a = (a > 0.f) ? a : 0.2f * a;
    ea2[e] = a;
    atomicMaxF(&m2[d], a);
}

__global__ void k_exp2(const int* __restrict__ ei, const float* __restrict__ m2,
                       float* ea2, float* den2) {
    int e = blockIdx.x * blockDim.x + threadIdx.x;
    if (e >= NEP) return;
    int d = (e < NE) ? ei[NE + e] : e - NE;
    float v = expf(ea2[e] - m2[d]);
    ea2[e] = v;
    atomicAdd(&den2[d], v);
}

__global__ void k_accum2(const int* __restrict__ ei, const float* __restrict__ ea2,
                         const float* __restrict__ den2, const float* __restrict__ h2,
                         float* o2a) {
    int e = blockIdx.x * blockDim.x + threadIdx.x;
    if (e >= NEP) return;
    int s, d;
    if (e < NE) { s = ei[e]; d = ei[NE + e]; }
    else        { s = d = e - NE; }
    atomicAdd(&o2a[d], ea2[e] / (den2[d] + 1e-16f) * h2[s]);
}

__global__ void k_final(const float* __restrict__ o2a, const float* __restrict__ b2,
                        float* __restrict__ out) {
    int i = blockIdx.x * blockDim.x + threadIdx.x;
    if (i >= NN) return;
    float v = o2a[i] + b2[0];
    out[i] = (v >= 0.f) ? v : 0.01f * v;
}

// ---------------- launch ----------------

extern "C" void kernel_launch(void* const* d_in, const int* in_sizes, int n_in,
                              void* d_out, int out_size, void* d_ws, size_t ws_size,
                              hipStream_t stream) {
    const float* x     = (const float*)d_in[0];
    const int*   ei    = (const int*)d_in[1];
    const float* eattr = (const float*)d_in[2];
    const float* W1    = (const float*)d_in[3];
    const float* asrc1 = (const float*)d_in[4];
    const float* adst1 = (const float*)d_in[5];
    const float* We1   = (const float*)d_in[6];
    const float* ae1   = (const float*)d_in[7];
    const float* b1    = (const float*)d_in[8];
    const float* W2    = (const float*)d_in[9];
    const float* as2   = (const float*)d_in[10];
    const float* ad2   = (const float*)d_in[11];
    const float* We2   = (const float*)d_in[12];
    const float* ae2   = (const float*)d_in[13];
    const float* b2    = (const float*)d_in[14];
    float* out = (float*)d_out;

    // workspace layout (~38.3 MB)
    float* w    = (float*)d_ws;
    float* h1   = w;                      // NH
    float* as1  = w + (size_t)NH;         // NN
    float* ad1  = as1 + NN;
    float* m1   = ad1 + NN;
    float* den1 = m1 + NN;
    float* h2   = den1 + NN;
    float* m2   = h2 + NN;
    float* den2 = m2 + NN;
    float* o2a  = den2 + NN;
    float* ea1  = o2a + NN;               // NEP
    float* csr_val = ea1 + NEP;           // NEP (reused as ea2 in layer 2)
    float* ea2  = csr_val;
    float* sc   = csr_val + NEP;          // 8 scalars
    int*   cnt    = (int*)(sc + 8);       // NN
    int*   start  = cnt + NN;             // NN
    int*   cursor = start + NN;           // NN
    int*   bsum   = cursor + NN;          // 256
    int*   csr_src = bsum + 256;          // NEP
    ushort* Wp   = (ushort*)(csr_src + NEP);  // WP_ELEMS bf16 (packed)

    k_init<<<(NN + 255) / 256, 256, 0, stream>>>(m1, den1, m2, den2, o2a, cnt, sc);
    k_sum_attr<<<256, 256, 0, stream>>>(eattr, sc);
    k_consts<<<1, 64, 0, stream>>>(We1, ae1, We2, ae2, sc);
    k_wt<<<(WP_ELEMS + 255) / 256, 256, 0, stream>>>(W1, Wp);

    k_gemm1_mfma<<<NROWB, 256, 0, stream>>>(x, Wp, h1);
    k_rowdot<<<(NN + 3) / 4, 256, 0, stream>>>(h1, asrc1, adst1, as1, ad1);

    k_alpha1<<<(NEP + 255) / 256, 256, 0, stream>>>(ei, eattr, as1, ad1, sc, ea1, m1, cnt);
    k_scan_blk<<<NBLK, SCAN_B, 0, stream>>>(cnt, start, bsum);
    k_scan_top<<<1, SCAN_B, 0, stream>>>(bsum);
    k_scan_fix<<<NBLK, SCAN_B, 0, stream>>>(start, cnt, bsum, cursor);
    k_exp1<<<(NEP + 255) / 256, 256, 0, stream>>>(ei, m1, ea1, den1, cursor, csr_src, csr_val);
    k_accum1_csr<<<(NN + 3) / 4, 256, 0, stream>>>(csr_src, csr_val, start, cnt, den1, h1, b1, W2, h2);

    k_alpha2<<<(NEP + 255) / 256, 256, 0, stream>>>(ei, eattr, h2, as2, ad2, sc, ea2, m2);
    k_exp2<<<(NEP + 255) / 256, 256, 0, stream>>>(ei, m2, ea2, den2);
    k_accum2<<<(NEP + 255) / 256, 256, 0, stream>>>(ei, ea2, den2, h2, o2a);

    k_final<<<(NN + 255) / 256, 256, 0, stream>>>(o2a, b2, out);
}

// Round 9
// 489.705 us; speedup vs baseline: 1.6102x; 1.0744x over previous
//
#include <hip/hip_runtime.h>
#include <math.h>

#define NN 50000
#define NE 800000
#define NEP 850000          // NE + NN self loops
#define FI 1284
#define HD 128
#define KP 1312             // FI padded to 41*32 for MFMA K-loop
#define NSTEP 41            // KP/32
#define NH (NN * HD)        // 6,400,000
#define SCAN_B 256
#define NBLK ((NN + SCAN_B - 1) / SCAN_B)   // 196 (<=256)
#define NROWB ((NN + 63) / 64)              // 782 row-blocks of 64
#define WP_ELEMS (NSTEP * 4096)             // packed B: 41 steps * 8cg * 64lane * 8

typedef float f32x4 __attribute__((ext_vector_type(4)));
typedef short bfrag __attribute__((ext_vector_type(8)));   // 8 bf16 in 4 VGPRs

// ---------------- helpers ----------------

__device__ __forceinline__ void atomicMaxF(float* addr, float v) {
    if (v >= 0.f) atomicMax((int*)addr, __float_as_int(v));
    else          atomicMin((unsigned int*)addr, __float_as_uint(v));
}

__device__ __forceinline__ float wave_reduce_sum(float v) {
    #pragma unroll
    for (int off = 32; off; off >>= 1) v += __shfl_down(v, off);
    return v;
}

__device__ __forceinline__ ushort f2bf(float f) {   // RNE fp32->bf16 bits
    unsigned u = __float_as_uint(f);
    u += 0x7FFFu + ((u >> 16) & 1u);
    return (ushort)(u >> 16);
}

__device__ __forceinline__ float bf2f(ushort u) {
    return __uint_as_float(((unsigned)u) << 16);
}

__device__ __forceinline__ bfrag cvt_frag(float4 a0, float4 a1) {
    bfrag af;
    af[0] = (short)f2bf(a0.x); af[1] = (short)f2bf(a0.y);
    af[2] = (short)f2bf(a0.z); af[3] = (short)f2bf(a0.w);
    af[4] = (short)f2bf(a1.x); af[5] = (short)f2bf(a1.y);
    af[6] = (short)f2bf(a1.z); af[7] = (short)f2bf(a1.w);
    return af;
}

// ---------------- init ----------------

__global__ void k_init(float* m1, float* den1, float* m2, float* den2,
                       float* o2a, int* cnt, float* sc) {
    int i = blockIdx.x * blockDim.x + threadIdx.x;
    if (i < NN) {
        m1[i]  = -INFINITY; den1[i] = 0.f;
        m2[i]  = -INFINITY; den2[i] = 0.f;
        o2a[i] = 0.f;
        cnt[i] = 0;
    }
    if (i < 8) sc[i] = 0.f;
}

// grid-stride block reduction: 256 blocks -> 256 same-address atomics
__global__ __launch_bounds__(256) void k_sum_attr(const float* __restrict__ eattr, float* sc) {
    __shared__ float wsum[4];
    float v = 0.f;
    for (int i = blockIdx.x * 256 + threadIdx.x; i < NE; i += 256 * 256)
        v += eattr[i];
    v = wave_reduce_sum(v);
    int wid = threadIdx.x >> 6, l = threadIdx.x & 63;
    if (l == 0) wsum[wid] = v;
    __syncthreads();
    if (threadIdx.x == 0)
        atomicAdd(&sc[0], wsum[0] + wsum[1] + wsum[2] + wsum[3]);
}

__global__ void k_consts(const float* We1, const float* ae1,
                         const float* We2, const float* ae2, float* sc) {
    int l = threadIdx.x;  // 64 threads
    float v = We1[l] * ae1[l] + We1[l + 64] * ae1[l + 64];
    v = wave_reduce_sum(v);
    if (l == 0) { sc[1] = v; sc[2] = We2[0] * ae2[0]; }
}

// Packed B: Wp[s][cg][lane][j] = bf16(W1[k][c]), k = s*32 + (lane>>4)*8 + j,
// c = cg*16 + (lane&15); zero-padded for k >= FI. Load-order contiguous.
__global__ void k_wt(const float* __restrict__ W, ushort* __restrict__ Wp) {
    int i = blockIdx.x * 256 + threadIdx.x;
    if (i >= WP_ELEMS) return;
    int s = i >> 12;
    int r = i & 4095;
    int cg = r >> 9;
    int q = r & 511;
    int lane = q >> 3, j = q & 7;
    int k = s * 32 + (lane >> 4) * 8 + j;
    int c = cg * 16 + (lane & 15);
    float v = (k < FI) ? W[(size_t)k * HD + c] : 0.f;
    Wp[i] = f2bf(v);
}

// ---------------- GEMM1: h1 = x @ W1  (bf16 MFMA, A+B both LDS-staged async) ----------------
// 4 waves/block, BM=64, BN=128, BK=32, double-buffered LDS (A 16KB + B 16KB).
// A fp32 with XOR chunk-swizzle (pre-swizzled global source, linear LDS dest).
// B (packed Wp) staged linearly: whole 8KB step shared by all 4 waves, 2 glds insts/wave.
// h1 stored bf16. Tail step 40 peeled (direct global A and B).

__global__ __launch_bounds__(256) void k_gemm1_mfma(const float* __restrict__ x,
                                                    const ushort* __restrict__ Wp,
                                                    ushort* __restrict__ h1) {
    __shared__ float  As[2][64][32];    // 16 KB
    __shared__ ushort Bs[2][4096];      // 16 KB
    const int t = threadIdx.x;
    const int wid = t >> 6, l = t & 63;
    const int lr = l & 15, lg = l >> 4;
    const int wrow0 = blockIdx.x * 64 + wid * 16;

    // A staging: inst i covers slab rows i*8..i*8+7; lane l -> row i*8 + l/8, slot l%8.
    // slot p of row r must hold global chunk p^(r&7); here r&7 == l/8.
    const int srow = l >> 3;
    const int schunk = (l & 7) ^ srow;
    int g0 = wrow0 + srow;      if (g0 > NN - 1) g0 = NN - 1;
    int g1 = wrow0 + 8 + srow;  if (g1 > NN - 1) g1 = NN - 1;
    const float* sp0 = x + (size_t)g0 * FI + schunk * 4;
    const float* sp1 = x + (size_t)g1 * FI + schunk * 4;

    // B staging: wave wid stages chunks (wid*2) and (wid*2+1), 1KB each, linear.
    const ushort* bq0 = Wp + (wid * 2    ) * 512 + l * 8;
    const ushort* bq1 = Wp + (wid * 2 + 1) * 512 + l * 8;

    // swizzled A read slots (chunk c of row lr lives at slot c^(lr&7))
    const int rs0 = (lg * 2)     ^ (lr & 7);
    const int rs1 = (lg * 2 + 1) ^ (lr & 7);

    f32x4 acc[8];
    #pragma unroll
    for (int c = 0; c < 8; ++c) acc[c] = (f32x4){0.f, 0.f, 0.f, 0.f};

#define STAGE(B, IT) do { \
    __builtin_amdgcn_global_load_lds( \
        (const __attribute__((address_space(1))) unsigned int*)(sp0 + (size_t)(IT) * 32), \
        (__attribute__((address_space(3))) unsigned int*)&As[B][wid * 16][0], 16, 0, 0); \
    __builtin_amdgcn_global_load_lds( \
        (const __attribute__((address_space(1))) unsigned int*)(sp1 + (size_t)(IT) * 32), \
        (__attribute__((address_space(3))) unsigned int*)&As[B][wid * 16 + 8][0], 16, 0, 0); \
    __builtin_amdgcn_global_load_lds( \
        (const __attribute__((address_space(1))) unsigned int*)(bq0 + (size_t)(IT) * 4096), \
        (__attribute__((address_space(3))) unsigned int*)&Bs[B][(wid * 2) * 512], 16, 0, 0); \
    __builtin_amdgcn_global_load_lds( \
        (const __attribute__((address_space(1))) unsigned int*)(bq1 + (size_t)(IT) * 4096), \
        (__attribute__((address_space(3))) unsigned int*)&Bs[B][(wid * 2 + 1) * 512], 16, 0, 0); \
} while (0)

    STAGE(0, 0);
    __syncthreads();

    for (int it = 0; it < 40; ++it) {
        const int bsel = it & 1;
        if (it < 39) STAGE((it + 1) & 1, it + 1);   // async, flies during compute

        bfrag bfr[8];
        #pragma unroll
        for (int cg = 0; cg < 8; ++cg)
            bfr[cg] = *(const bfrag*)&Bs[bsel][cg * 512 + l * 8];

        float4 a0 = *(const float4*)&As[bsel][wid * 16 + lr][rs0 * 4];
        float4 a1 = *(const float4*)&As[bsel][wid * 16 + lr][rs1 * 4];
        bfrag af = cvt_frag(a0, a1);
        #pragma unroll
        for (int cg = 0; cg < 8; ++cg)
            acc[cg] = __builtin_amdgcn_mfma_f32_16x16x32_bf16(af, bfr[cg], acc[cg], 0, 0, 0);

        __syncthreads();   // drains stage(it+1), guards buffer reuse
    }
#undef STAGE

    {   // K tail: step 40 (k0=1280, valid k<1284 in lg==0 low half); Wp zero-padded
        int rowc = wrow0 + lr; if (rowc > NN - 1) rowc = NN - 1;
        float4 a0t = make_float4(0.f, 0.f, 0.f, 0.f);
        if (lg == 0) a0t = *(const float4*)(x + (size_t)rowc * FI + 1280);
        bfrag af;
        af[0] = (short)f2bf(a0t.x); af[1] = (short)f2bf(a0t.y);
        af[2] = (short)f2bf(a0t.z); af[3] = (short)f2bf(a0t.w);
        af[4] = 0; af[5] = 0; af[6] = 0; af[7] = 0;
        const ushort* wqs = Wp + (size_t)40 * 4096 + l * 8;
        #pragma unroll
        for (int cg = 0; cg < 8; ++cg) {
            bfrag bf = *(const bfrag*)(wqs + cg * 512);
            acc[cg] = __builtin_amdgcn_mfma_f32_16x16x32_bf16(af, bf, acc[cg], 0, 0, 0);
        }
    }

    #pragma unroll
    for (int cg = 0; cg < 8; ++cg) {
        #pragma unroll
        for (int r = 0; r < 4; ++r) {
            int gr = wrow0 + lg * 4 + r;
            if (gr < NN) h1[(size_t)gr * HD + cg * 16 + lr] = f2bf(acc[cg][r]);
        }
    }
}

__global__ __launch_bounds__(256) void k_rowdot(const ushort* __restrict__ h1,
                                                const float* __restrict__ asrc,
                                                const float* __restrict__ adst,
                                                float* as1, float* ad1) {
    int wid = threadIdx.x >> 6, l = threadIdx.x & 63;
    int i = blockIdx.x * 4 + wid;
    if (i >= NN) return;
    ushort2 hv = *(const ushort2*)&h1[(size_t)i * HD + 2 * l];
    float hx = bf2f(hv.x), hy = bf2f(hv.y);
    float2 av = *(const float2*)&asrc[2 * l];
    float2 dv = *(const float2*)&adst[2 * l];
    float s = hx * av.x + hy * av.y;
    float d = hx * dv.x + hy * dv.y;
    #pragma unroll
    for (int off = 32; off; off >>= 1) {
        s += __shfl_down(s, off);
        d += __shfl_down(d, off);
    }
    if (l == 0) { as1[i] = s; ad1[i] = d; }
}

// ---------------- layer-1 edge passes ----------------

__global__ void k_alpha1(const int* __restrict__ ei, const float* __restrict__ eattr,
                         const float* __restrict__ as1, const float* __restrict__ ad1,
                         const float* __restrict__ sc, float* ea1, float* m1, int* cnt) {
    int e = blockIdx.x * blockDim.x + threadIdx.x;
    if (e >= NEP) return;
    int s, d; float av;
    if (e < NE) { s = ei[e]; d = ei[NE + e]; av = eattr[e]; }
    else        { s = d = e - NE; av = sc[0] * (1.0f / NE); }
    float a = as1[s] + ad1[d] + av * sc[1];
    a = (a > 0.f) ? a : 0.2f * a;
    ea1[e] = a;
    atomicMaxF(&m1[d], a);
    atomicAdd(&cnt[d], 1);
}

// ---------------- exclusive scan of cnt -> start ----------------

__global__ void k_scan_blk(const int* __restrict__ cnt, int* incl, int* bsum) {
    __shared__ int sh[SCAN_B];
    int i = blockIdx.x * SCAN_B + threadIdx.x;
    sh[threadIdx.x] = (i < NN) ? cnt[i] : 0;
    __syncthreads();
    for (int off = 1; off < SCAN_B; off <<= 1) {
        int t = (threadIdx.x >= off) ? sh[threadIdx.x - off] : 0;
        __syncthreads();
        sh[threadIdx.x] += t;
        __syncthreads();
    }
    if (i < NN) incl[i] = sh[threadIdx.x];
    if (threadIdx.x == SCAN_B - 1) bsum[blockIdx.x] = sh[threadIdx.x];
}

__global__ void k_scan_top(int* bsum) {
    __shared__ int sh[SCAN_B];
    sh[threadIdx.x] = (threadIdx.x < NBLK) ? bsum[threadIdx.x] : 0;
    __syncthreads();
    for (int off = 1; off < SCAN_B; off <<= 1) {
        int t = (threadIdx.x >= off) ? sh[threadIdx.x - off] : 0;
        __syncthreads();
        sh[threadIdx.x] += t;
        __syncthreads();
    }
    if (threadIdx.x < NBLK) bsum[threadIdx.x] = sh[threadIdx.x];
}

__global__ void k_scan_fix(int* incl_start, const int* __restrict__ cnt,
                           const int* __restrict__ bsum, int* cursor) {
    int i = blockIdx.x * SCAN_B + threadIdx.x;
    if (i >= NN) return;
    int off = (blockIdx.x > 0) ? bsum[blockIdx.x - 1] : 0;
    int st = incl_start[i] - cnt[i] + off;
    incl_start[i] = st;
    cursor[i] = st;
}

__global__ void k_exp1(const int* __restrict__ ei, const float* __restrict__ m1,
                       const float* __restrict__ ea1, float* den1,
                       int* cursor, int* csr_src, float* csr_val) {
    int e = blockIdx.x * blockDim.x + threadIdx.x;
    if (e >= NEP) return;
    int s, d;
    if (e < NE) { s = ei[e]; d = ei[NE + e]; }
    else        { s = d = e - NE; }
    float v = expf(ea1[e] - m1[d]);
    atomicAdd(&den1[d], v);
    int pos = atomicAdd(&cursor[d], 1);
    csr_src[pos] = s;
    csr_val[pos] = v;
}

// gather-accumulate + fused ELU/bias/W2-dot epilogue (out1 never materialized)
__global__ __launch_bounds__(256) void k_accum1_csr(const int* __restrict__ csr_src,
                                                    const float* __restrict__ csr_val,
                                                    const int* __restrict__ start,
                                                    const int* __restrict__ cnt,
                                                    const float* __restrict__ den1,
                                                    const ushort* __restrict__ h1,
                                                    const float* __restrict__ b1,
                                                    const float* __restrict__ W2,
                                                    float* __restrict__ h2) {
    int wid = threadIdx.x >> 6, l = threadIdx.x & 63;
    int d = blockIdx.x * 4 + wid;
    if (d >= NN) return;
    int s0 = start[d], n = cnt[d];
    float inv = 1.f / (den1[d] + 1e-16f);
    float ax = 0.f, ay = 0.f;
    for (int i = 0; i < n; ++i) {
        int s = csr_src[s0 + i];
        float c = csr_val[s0 + i] * inv;
        ushort2 hv = *(const ushort2*)&h1[(size_t)s * HD + 2 * l];
        ax += c * bf2f(hv.x); ay += c * bf2f(hv.y);
    }
    float2 bb = *(const float2*)&b1[2 * l];
    float2 w  = *(const float2*)&W2[2 * l];
    float a = ax + bb.x; a = (a > 0.f) ? a : (expf(a) - 1.f);
    float b = ay + bb.y; b = (b > 0.f) ? b : (expf(b) - 1.f);
    float p = a * w.x + b * w.y;
    p = wave_reduce_sum(p);
    if (l == 0) h2[d] = p;
}

// ---------------- layer-2 edge passes ----------------

__global__ void k_alpha2(const int* __restrict__ ei, const float* __restrict__ eattr,
                         const float* __restrict__ h2,
                         const float* __restrict__ as2, const float* __restrict__ ad2,
                         const float* __restrict__ sc, float* ea2, float* m2) {
    int e = blockIdx.x * blockDim.x + threadIdx.x;
    if (e >= NEP) return;
    int s, d; float av;
    if (e < NE) { s = ei[e]; d = ei[NE + e]; av = eattr[e]; }
    else        { s = d = e - NE; av = sc[0] * (1.0f / NE); }
    float a = as2[0] * h2[s] + ad2[0] * h2[d] + av * sc[2];
    a = (a > 0.f) ? a : 0.2f * a;
    ea2[e] = a;
    atomicMaxF(&m2[d], a);
}

__global__ void k_exp2(const int* __restrict__ ei, const float* __restrict__ m2,
                       float* ea2, float* den2) {
    int e = blockIdx.x * blockDim.x + threadIdx.x;
    if (e >= NEP) return;
    int d = (e < NE) ? ei[NE + e] : e - NE;
    float v = expf(ea2[e] - m2[d]);
    ea2[e] = v;
    atomicAdd(&den2[d], v);
}

__global__ void k_accum2(const int* __restrict__ ei, const float* __restrict__ ea2,
                         const float* __restrict__ den2, const float* __restrict__ h2,
                         float* o2a) {
    int e = blockIdx.x * blockDim.x + threadIdx.x;
    if (e >= NEP) return;
    int s, d;
    if (e < NE) { s = ei[e]; d = ei[NE + e]; }
    else        { s = d = e - NE; }
    atomicAdd(&o2a[d], ea2[e] / (den2[d] + 1e-16f) * h2[s]);
}

__global__ void k_final(const float* __restrict__ o2a, const float* __restrict__ b2,
                        float* __restrict__ out) {
    int i = blockIdx.x * blockDim.x + threadIdx.x;
    if (i >= NN) return;
    float v = o2a[i] + b2[0];
    out[i] = (v >= 0.f) ? v : 0.01f * v;
}

// ---------------- launch ----------------

extern "C" void kernel_launch(void* const* d_in, const int* in_sizes, int n_in,
                              void* d_out, int out_size, void* d_ws, size_t ws_size,
                              hipStream_t stream) {
    const float* x     = (const float*)d_in[0];
    const int*   ei    = (const int*)d_in[1];
    const float* eattr = (const float*)d_in[2];
    const float* W1    = (const float*)d_in[3];
    const float* asrc1 = (const float*)d_in[4];
    const float* adst1 = (const float*)d_in[5];
    const float* We1   = (const float*)d_in[6];
    const float* ae1   = (const float*)d_in[7];
    const float* b1    = (const float*)d_in[8];
    const float* W2    = (const float*)d_in[9];
    const float* as2   = (const float*)d_in[10];
    const float* ad2   = (const float*)d_in[11];
    const float* We2   = (const float*)d_in[12];
    const float* ae2   = (const float*)d_in[13];
    const float* b2    = (const float*)d_in[14];
    float* out = (float*)d_out;

    // workspace layout (~25.5 MB; h1 now bf16)
    ushort* h1  = (ushort*)d_ws;          // NH ushorts (12.8 MB)
    float* as1  = (float*)(h1 + (size_t)NH);  // NN
    float* ad1  = as1 + NN;
    float* m1   = ad1 + NN;
    float* den1 = m1 + NN;
    float* h2   = den1 + NN;
    float* m2   = h2 + NN;
    float* den2 = m2 + NN;
    float* o2a  = den2 + NN;
    float* ea1  = o2a + NN;               // NEP
    float* csr_val = ea1 + NEP;           // NEP (reused as ea2 in layer 2)
    float* ea2  = csr_val;
    float* sc   = csr_val + NEP;          // 8 scalars
    int*   cnt    = (int*)(sc + 8);       // NN
    int*   start  = cnt + NN;             // NN
    int*   cursor = start + NN;           // NN
    int*   bsum   = cursor + NN;          // 256
    int*   csr_src = bsum + 256;          // NEP
    ushort* Wp   = (ushort*)(csr_src + NEP);  // WP_ELEMS bf16 (packed)

    k_init<<<(NN + 255) / 256, 256, 0, stream>>>(m1, den1, m2, den2, o2a, cnt, sc);
    k_sum_attr<<<256, 256, 0, stream>>>(eattr, sc);
    k_consts<<<1, 64, 0, stream>>>(We1, ae1, We2, ae2, sc);
    k_wt<<<(WP_ELEMS + 255) / 256, 256, 0, stream>>>(W1, Wp);

    k_gemm1_mfma<<<NROWB, 256, 0, stream>>>(x, Wp, h1);
    k_rowdot<<<(NN + 3) / 4, 256, 0, stream>>>(h1, asrc1, adst1, as1, ad1);

    k_alpha1<<<(NEP + 255) / 256, 256, 0, stream>>>(ei, eattr, as1, ad1, sc, ea1, m1, cnt);
    k_scan_blk<<<NBLK, SCAN_B, 0, stream>>>(cnt, start, bsum);
    k_scan_top<<<1, SCAN_B, 0, stream>>>(bsum);
    k_scan_fix<<<NBLK, SCAN_B, 0, stream>>>(start, cnt, bsum, cursor);
    k_exp1<<<(NEP + 255) / 256, 256, 0, stream>>>(ei, m1, ea1, den1, cursor, csr_src, csr_val);
    k_accum1_csr<<<(NN + 3) / 4, 256, 0, stream>>>(csr_src, csr_val, start, cnt, den1, h1, b1, W2, h2);

    k_alpha2<<<(NEP + 255) / 256, 256, 0, stream>>>(ei, eattr, h2, as2, ad2, sc, ea2, m2);
    k_exp2<<<(NEP + 255) / 256, 256, 0, stream>>>(ei, m2, ea2, den2);
    k_accum2<<<(NEP + 255) / 256, 256, 0, stream>>>(ei, ea2, den2, h2, o2a);

    k_final<<<(NN + 255) / 256, 256, 0, stream>>>(o2a, b2, out);
}

// Round 10
// 369.340 us; speedup vs baseline: 2.1350x; 1.3259x over previous
//
#include <hip/hip_runtime.h>
#include <math.h>

#define NN 50000
#define NE 800000
#define NEP 850000          // NE + NN self loops
#define FI 1284
#define HD 128
#define KP 1312             // FI padded to 41*32 for MFMA K-loop
#define NSTEP 41            // KP/32
#define NH (NN * HD)        // 6,400,000
#define SCAN_B 256
#define NBLK ((NN + SCAN_B - 1) / SCAN_B)   // 196 (<=256)
#define NROWB ((NN + 63) / 64)              // 782 row-blocks of 64
#define WP_ELEMS (NSTEP * 4096)             // packed B: 41 steps * 8cg * 64lane * 8

typedef float f32x4 __attribute__((ext_vector_type(4)));
typedef short bfrag __attribute__((ext_vector_type(8)));   // 8 bf16 in 4 VGPRs

// ---------------- helpers ----------------

__device__ __forceinline__ float wave_reduce_sum(float v) {
    #pragma unroll
    for (int off = 32; off; off >>= 1) v += __shfl_down(v, off);
    return v;
}

__device__ __forceinline__ ushort f2bf(float f) {   // RNE fp32->bf16 bits
    unsigned u = __float_as_uint(f);
    u += 0x7FFFu + ((u >> 16) & 1u);
    return (ushort)(u >> 16);
}

__device__ __forceinline__ float bf2f(ushort u) {
    return __uint_as_float(((unsigned)u) << 16);
}

__device__ __forceinline__ bfrag cvt_frag(float4 a0, float4 a1) {
    bfrag af;
    af[0] = (short)f2bf(a0.x); af[1] = (short)f2bf(a0.y);
    af[2] = (short)f2bf(a0.z); af[3] = (short)f2bf(a0.w);
    af[4] = (short)f2bf(a1.x); af[5] = (short)f2bf(a1.y);
    af[6] = (short)f2bf(a1.z); af[7] = (short)f2bf(a1.w);
    return af;
}

// ---------------- init ----------------

__global__ void k_init(int* cnt, float* sc) {
    int i = blockIdx.x * blockDim.x + threadIdx.x;
    if (i < NN) cnt[i] = 0;
    if (i < 8) sc[i] = 0.f;
}

// grid-stride block reduction: 256 blocks -> 256 same-address atomics
__global__ __launch_bounds__(256) void k_sum_attr(const float* __restrict__ eattr, float* sc) {
    __shared__ float wsum[4];
    float v = 0.f;
    for (int i = blockIdx.x * 256 + threadIdx.x; i < NE; i += 256 * 256)
        v += eattr[i];
    v = wave_reduce_sum(v);
    int wid = threadIdx.x >> 6, l = threadIdx.x & 63;
    if (l == 0) wsum[wid] = v;
    __syncthreads();
    if (threadIdx.x == 0)
        atomicAdd(&sc[0], wsum[0] + wsum[1] + wsum[2] + wsum[3]);
}

__global__ void k_consts(const float* We1, const float* ae1,
                         const float* We2, const float* ae2, float* sc) {
    int l = threadIdx.x;  // 64 threads
    float v = We1[l] * ae1[l] + We1[l + 64] * ae1[l + 64];
    v = wave_reduce_sum(v);
    if (l == 0) { sc[1] = v; sc[2] = We2[0] * ae2[0]; }
}

// Packed B: Wp[s][cg][lane][j] = bf16(W1[k][c]), k = s*32 + (lane>>4)*8 + j,
// c = cg*16 + (lane&15); zero-padded for k >= FI. Load-order contiguous.
__global__ void k_wt(const float* __restrict__ W, ushort* __restrict__ Wp) {
    int i = blockIdx.x * 256 + threadIdx.x;
    if (i >= WP_ELEMS) return;
    int s = i >> 12;
    int r = i & 4095;
    int cg = r >> 9;
    int q = r & 511;
    int lane = q >> 3, j = q & 7;
    int k = s * 32 + (lane >> 4) * 8 + j;
    int c = cg * 16 + (lane & 15);
    float v = (k < FI) ? W[(size_t)k * HD + c] : 0.f;
    Wp[i] = f2bf(v);
}

// ---------------- GEMM1: h1 = x @ W1  (bf16 MFMA, A+B both LDS-staged async) ----------------

__global__ __launch_bounds__(256) void k_gemm1_mfma(const float* __restrict__ x,
                                                    const ushort* __restrict__ Wp,
                                                    ushort* __restrict__ h1) {
    __shared__ float  As[2][64][32];    // 16 KB
    __shared__ ushort Bs[2][4096];      // 16 KB
    const int t = threadIdx.x;
    const int wid = t >> 6, l = t & 63;
    const int lr = l & 15, lg = l >> 4;
    const int wrow0 = blockIdx.x * 64 + wid * 16;

    const int srow = l >> 3;
    const int schunk = (l & 7) ^ srow;
    int g0 = wrow0 + srow;      if (g0 > NN - 1) g0 = NN - 1;
    int g1 = wrow0 + 8 + srow;  if (g1 > NN - 1) g1 = NN - 1;
    const float* sp0 = x + (size_t)g0 * FI + schunk * 4;
    const float* sp1 = x + (size_t)g1 * FI + schunk * 4;

    const ushort* bq0 = Wp + (wid * 2    ) * 512 + l * 8;
    const ushort* bq1 = Wp + (wid * 2 + 1) * 512 + l * 8;

    const int rs0 = (lg * 2)     ^ (lr & 7);
    const int rs1 = (lg * 2 + 1) ^ (lr & 7);

    f32x4 acc[8];
    #pragma unroll
    for (int c = 0; c < 8; ++c) acc[c] = (f32x4){0.f, 0.f, 0.f, 0.f};

#define STAGE(B, IT) do { \
    __builtin_amdgcn_global_load_lds( \
        (const __attribute__((address_space(1))) unsigned int*)(sp0 + (size_t)(IT) * 32), \
        (__attribute__((address_space(3))) unsigned int*)&As[B][wid * 16][0], 16, 0, 0); \
    __builtin_amdgcn_global_load_lds( \
        (const __attribute__((address_space(1))) unsigned int*)(sp1 + (size_t)(IT) * 32), \
        (__attribute__((address_space(3))) unsigned int*)&As[B][wid * 16 + 8][0], 16, 0, 0); \
    __builtin_amdgcn_global_load_lds( \
        (const __attribute__((address_space(1))) unsigned int*)(bq0 + (size_t)(IT) * 4096), \
        (__attribute__((address_space(3))) unsigned int*)&Bs[B][(wid * 2) * 512], 16, 0, 0); \
    __builtin_amdgcn_global_load_lds( \
        (const __attribute__((address_space(1))) unsigned int*)(bq1 + (size_t)(IT) * 4096), \
        (__attribute__((address_space(3))) unsigned int*)&Bs[B][(wid * 2 + 1) * 512], 16, 0, 0); \
} while (0)

    STAGE(0, 0);
    __syncthreads();

    for (int it = 0; it < 40; ++it) {
        const int bsel = it & 1;
        if (it < 39) STAGE((it + 1) & 1, it + 1);   // async, flies during compute

        bfrag bfr[8];
        #pragma unroll
        for (int cg = 0; cg < 8; ++cg)
            bfr[cg] = *(const bfrag*)&Bs[bsel][cg * 512 + l * 8];

        float4 a0 = *(const float4*)&As[bsel][wid * 16 + lr][rs0 * 4];
        float4 a1 = *(const float4*)&As[bsel][wid * 16 + lr][rs1 * 4];
        bfrag af = cvt_frag(a0, a1);
        #pragma unroll
        for (int cg = 0; cg < 8; ++cg)
            acc[cg] = __builtin_amdgcn_mfma_f32_16x16x32_bf16(af, bfr[cg], acc[cg], 0, 0, 0);

        __syncthreads();
    }
#undef STAGE

    {   // K tail: step 40 (k0=1280, valid k<1284 in lg==0 low half); Wp zero-padded
        int rowc = wrow0 + lr; if (rowc > NN - 1) rowc = NN - 1;
        float4 a0t = make_float4(0.f, 0.f, 0.f, 0.f);
        if (lg == 0) a0t = *(const float4*)(x + (size_t)rowc * FI + 1280);
        bfrag af;
        af[0] = (short)f2bf(a0t.x); af[1] = (short)f2bf(a0t.y);
        af[2] = (short)f2bf(a0t.z); af[3] = (short)f2bf(a0t.w);
        af[4] = 0; af[5] = 0; af[6] = 0; af[7] = 0;
        const ushort* wqs = Wp + (size_t)40 * 4096 + l * 8;
        #pragma unroll
        for (int cg = 0; cg < 8; ++cg) {
            bfrag bf = *(const bfrag*)(wqs + cg * 512);
            acc[cg] = __builtin_amdgcn_mfma_f32_16x16x32_bf16(af, bf, acc[cg], 0, 0, 0);
        }
    }

    #pragma unroll
    for (int cg = 0; cg < 8; ++cg) {
        #pragma unroll
        for (int r = 0; r < 4; ++r) {
            int gr = wrow0 + lg * 4 + r;
            if (gr < NN) h1[(size_t)gr * HD + cg * 16 + lr] = f2bf(acc[cg][r]);
        }
    }
}

__global__ __launch_bounds__(256) void k_rowdot(const ushort* __restrict__ h1,
                                                const float* __restrict__ asrc,
                                                const float* __restrict__ adst,
                                                float* as1, float* ad1) {
    int wid = threadIdx.x >> 6, l = threadIdx.x & 63;
    int i = blockIdx.x * 4 + wid;
    if (i >= NN) return;
    ushort2 hv = *(const ushort2*)&h1[(size_t)i * HD + 2 * l];
    float hx = bf2f(hv.x), hy = bf2f(hv.y);
    float2 av = *(const float2*)&asrc[2 * l];
    float2 dv = *(const float2*)&adst[2 * l];
    float s = hx * av.x + hy * av.y;
    float d = hx * dv.x + hy * dv.y;
    #pragma unroll
    for (int off = 32; off; off >>= 1) {
        s += __shfl_down(s, off);
        d += __shfl_down(d, off);
    }
    if (l == 0) { as1[i] = s; ad1[i] = d; }
}

// ---------------- CSR build: hist -> scan -> place ----------------

__global__ void k_hist(const int* __restrict__ ei, int* cnt) {
    int e = blockIdx.x * blockDim.x + threadIdx.x;
    if (e >= NEP) return;
    int d = (e < NE) ? ei[NE + e] : e - NE;
    atomicAdd(&cnt[d], 1);
}

__global__ void k_scan_blk(const int* __restrict__ cnt, int* incl, int* bsum) {
    __shared__ int sh[SCAN_B];
    int i = blockIdx.x * SCAN_B + threadIdx.x;
    sh[threadIdx.x] = (i < NN) ? cnt[i] : 0;
    __syncthreads();
    for (int off = 1; off < SCAN_B; off <<= 1) {
        int t = (threadIdx.x >= off) ? sh[threadIdx.x - off] : 0;
        __syncthreads();
        sh[threadIdx.x] += t;
        __syncthreads();
    }
    if (i < NN) incl[i] = sh[threadIdx.x];
    if (threadIdx.x == SCAN_B - 1) bsum[blockIdx.x] = sh[threadIdx.x];
}

__global__ void k_scan_top(int* bsum) {
    __shared__ int sh[SCAN_B];
    sh[threadIdx.x] = (threadIdx.x < NBLK) ? bsum[threadIdx.x] : 0;
    __syncthreads();
    for (int off = 1; off < SCAN_B; off <<= 1) {
        int t = (threadIdx.x >= off) ? sh[threadIdx.x - off] : 0;
        __syncthreads();
        sh[threadIdx.x] += t;
        __syncthreads();
    }
    if (threadIdx.x < NBLK) bsum[threadIdx.x] = sh[threadIdx.x];
}

__global__ void k_scan_fix(int* incl_start, const int* __restrict__ cnt,
                           const int* __restrict__ bsum, int* cursor) {
    int i = blockIdx.x * SCAN_B + threadIdx.x;
    if (i >= NN) return;
    int off = (blockIdx.x > 0) ? bsum[blockIdx.x - 1] : 0;
    int st = incl_start[i] - cnt[i] + off;
    incl_start[i] = st;
    cursor[i] = st;
}

// place edges into dst-grouped CSR: one 8B record {src, eattr_bits}
__global__ void k_place(const int* __restrict__ ei, const float* __restrict__ eattr,
                        const float* __restrict__ sc, int* cursor, int2* __restrict__ csr) {
    int e = blockIdx.x * blockDim.x + threadIdx.x;
    if (e >= NEP) return;
    int s, d; float av;
    if (e < NE) { s = ei[e]; d = ei[NE + e]; av = eattr[e]; }
    else        { s = d = e - NE; av = sc[0] * (1.0f / NE); }
    int pos = atomicAdd(&cursor[d], 1);
    csr[pos] = make_int2(s, __float_as_int(av));
}

// ---------------- layer 1 (fused): softmax over neighborhood + PV + ELU + W2-dot ----------------
// one wave per dst. Scalar alpha math is wave-uniform (lane-redundant = free).
// loop1: sequential max (no atomics). loop2: exp, den, weighted h1 row accumulate.
__global__ __launch_bounds__(256) void k_layer1(const int2* __restrict__ csr,
                                                const int* __restrict__ start,
                                                const int* __restrict__ cnt,
                                                const float* __restrict__ as1,
                                                const float* __restrict__ ad1,
                                                const float* __restrict__ sc,
                                                const ushort* __restrict__ h1,
                                                const float* __restrict__ b1,
                                                const float* __restrict__ W2,
                                                float* __restrict__ h2) {
    int wid = threadIdx.x >> 6, l = threadIdx.x & 63;
    int d = blockIdx.x * 4 + wid;
    if (d >= NN) return;
    int s0 = start[d], n = cnt[d];
    float adv = ad1[d], c1 = sc[1];

    float m = -INFINITY;
    for (int i = 0; i < n; ++i) {
        int2 sa = csr[s0 + i];
        float a = as1[sa.x] + adv + c1 * __int_as_float(sa.y);
        a = (a > 0.f) ? a : 0.2f * a;
        m = fmaxf(m, a);
    }
    float den = 0.f, ax = 0.f, ay = 0.f;
    for (int i = 0; i < n; ++i) {
        int2 sa = csr[s0 + i];
        float a = as1[sa.x] + adv + c1 * __int_as_float(sa.y);
        a = (a > 0.f) ? a : 0.2f * a;
        float wgt = expf(a - m);
        den += wgt;
        ushort2 hv = *(const ushort2*)&h1[(size_t)sa.x * HD + 2 * l];
        ax += wgt * bf2f(hv.x); ay += wgt * bf2f(hv.y);
    }
    float inv = 1.f / (den + 1e-16f);
    ax *= inv; ay *= inv;
    float2 bb = *(const float2*)&b1[2 * l];
    float2 w  = *(const float2*)&W2[2 * l];
    float a = ax + bb.x; a = (a > 0.f) ? a : (expf(a) - 1.f);
    float b = ay + bb.y; b = (b > 0.f) ? b : (expf(b) - 1.f);
    float p = a * w.x + b * w.y;
    p = wave_reduce_sum(p);
    if (l == 0) h2[d] = p;
}

// ---------------- layer 2 (fused, scalar): softmax + weighted sum + bias + leaky ----------------
// one thread per dst; h2 (200KB) is L2-resident.
__global__ __launch_bounds__(256) void k_layer2(const int2* __restrict__ csr,
                                                const int* __restrict__ start,
                                                const int* __restrict__ cnt,
                                                const float* __restrict__ h2,
                                                const float* __restrict__ as2,
                                                const float* __restrict__ ad2,
                                                const float* __restrict__ sc,
                                                const float* __restrict__ b2,
                                                float* __restrict__ out) {
    int d = blockIdx.x * blockDim.x + threadIdx.x;
    if (d >= NN) return;
    int s0 = start[d], n = cnt[d];
    float A = as2[0], D = ad2[0], c2 = sc[2];
    float hd = D * h2[d];

    float m = -INFINITY;
    for (int i = 0; i < n; ++i) {
        int2 sa = csr[s0 + i];
        float a = A * h2[sa.x] + hd + c2 * __int_as_float(sa.y);
        a = (a > 0.f) ? a : 0.2f * a;
        m = fmaxf(m, a);
    }
    float den = 0.f, num = 0.f;
    for (int i = 0; i < n; ++i) {
        int2 sa = csr[s0 + i];
        float hs = h2[sa.x];
        float a = A * hs + hd + c2 * __int_as_float(sa.y);
        a = (a > 0.f) ? a : 0.2f * a;
        float wgt = expf(a - m);
        den += wgt;
        num += wgt * hs;
    }
    float v = num / (den + 1e-16f) + b2[0];
    out[d] = (v >= 0.f) ? v : 0.01f * v;
}

// ---------------- launch ----------------

extern "C" void kernel_launch(void* const* d_in, const int* in_sizes, int n_in,
                              void* d_out, int out_size, void* d_ws, size_t ws_size,
                              hipStream_t stream) {
    const float* x     = (const float*)d_in[0];
    const int*   ei    = (const int*)d_in[1];
    const float* eattr = (const float*)d_in[2];
    const float* W1    = (const float*)d_in[3];
    const float* asrc1 = (const float*)d_in[4];
    const float* adst1 = (const float*)d_in[5];
    const float* We1   = (const float*)d_in[6];
    const float* ae1   = (const float*)d_in[7];
    const float* b1    = (const float*)d_in[8];
    const float* W2    = (const float*)d_in[9];
    const float* as2   = (const float*)d_in[10];
    const float* ad2   = (const float*)d_in[11];
    const float* We2   = (const float*)d_in[12];
    const float* ae2   = (const float*)d_in[13];
    const float* b2    = (const float*)d_in[14];
    float* out = (float*)d_out;

    // workspace layout (~21.3 MB)
    ushort* h1  = (ushort*)d_ws;              // NH ushorts (12.8 MB)
    float* as1  = (float*)(h1 + (size_t)NH);  // NN
    float* ad1  = as1 + NN;
    float* h2   = ad1 + NN;
    float* sc   = h2 + NN;                    // 8 scalars
    int*   cnt    = (int*)(sc + 8);           // NN
    int*   start  = cnt + NN;                 // NN
    int*   cursor = start + NN;               // NN
    int*   bsum   = cursor + NN;              // 256
    int2*  csr    = (int2*)(bsum + 256);      // NEP int2 (6.8 MB)
    ushort* Wp  = (ushort*)(csr + NEP);       // WP_ELEMS bf16 (packed)

    k_init<<<(NN + 255) / 256, 256, 0, stream>>>(cnt, sc);
    k_sum_attr<<<256, 256, 0, stream>>>(eattr, sc);
    k_consts<<<1, 64, 0, stream>>>(We1, ae1, We2, ae2, sc);
    k_wt<<<(WP_ELEMS + 255) / 256, 256, 0, stream>>>(W1, Wp);

    k_gemm1_mfma<<<NROWB, 256, 0, stream>>>(x, Wp, h1);
    k_rowdot<<<(NN + 3) / 4, 256, 0, stream>>>(h1, asrc1, adst1, as1, ad1);

    k_hist<<<(NEP + 255) / 256, 256, 0, stream>>>(ei, cnt);
    k_scan_blk<<<NBLK, SCAN_B, 0, stream>>>(cnt, start, bsum);
    k_scan_top<<<1, SCAN_B, 0, stream>>>(bsum);
    k_scan_fix<<<NBLK, SCAN_B, 0, stream>>>(start, cnt, bsum, cursor);
    k_place<<<(NEP + 255) / 256, 256, 0, stream>>>(ei, eattr, sc, cursor, csr);

    k_layer1<<<(NN + 3) / 4, 256, 0, stream>>>(csr, start, cnt, as1, ad1, sc, h1, b1, W2, h2);
    k_layer2<<<(NN + 255) / 256, 256, 0, stream>>>(csr, start, cnt, h2, as2, ad2, sc, b2, out);
}

// Round 11
// 368.512 us; speedup vs baseline: 2.1398x; 1.0022x over previous
//
#include <hip/hip_runtime.h>
#include <math.h>

#define NN 50000
#define NE 800000
#define NEP 850000          // NE + NN self loops
#define FI 1284
#define HD 128
#define KP 1312             // FI padded to 41*32 for MFMA K-loop
#define NSTEP 41            // KP/32
#define NH (NN * HD)        // 6,400,000
#define SCAN_B 256
#define NBLK ((NN + SCAN_B - 1) / SCAN_B)   // 196 (<=256)
#define NROWB ((NN + 63) / 64)              // 782 row-blocks of 64
#define WP_ELEMS (NSTEP * 4096)             // packed B: 41 steps * 8cg * 64lane * 8

typedef float f32x4 __attribute__((ext_vector_type(4)));
typedef short bfrag __attribute__((ext_vector_type(8)));   // 8 bf16 in 4 VGPRs

// ---------------- helpers ----------------

__device__ __forceinline__ float wave_reduce_sum(float v) {
    #pragma unroll
    for (int off = 32; off; off >>= 1) v += __shfl_down(v, off);
    return v;
}

__device__ __forceinline__ ushort f2bf(float f) {   // RNE fp32->bf16 bits
    unsigned u = __float_as_uint(f);
    u += 0x7FFFu + ((u >> 16) & 1u);
    return (ushort)(u >> 16);
}

__device__ __forceinline__ float bf2f(ushort u) {
    return __uint_as_float(((unsigned)u) << 16);
}

__device__ __forceinline__ bfrag cvt_frag(float4 a0, float4 a1) {
    bfrag af;
    af[0] = (short)f2bf(a0.x); af[1] = (short)f2bf(a0.y);
    af[2] = (short)f2bf(a0.z); af[3] = (short)f2bf(a0.w);
    af[4] = (short)f2bf(a1.x); af[5] = (short)f2bf(a1.y);
    af[6] = (short)f2bf(a1.z); af[7] = (short)f2bf(a1.w);
    return af;
}

// ---------------- init ----------------

__global__ void k_init(int* cnt, float* sc) {
    int i = blockIdx.x * blockDim.x + threadIdx.x;
    if (i < NN) cnt[i] = 0;
    if (i < 8) sc[i] = 0.f;
}

// grid-stride block reduction: 256 blocks -> 256 same-address atomics
__global__ __launch_bounds__(256) void k_sum_attr(const float* __restrict__ eattr, float* sc) {
    __shared__ float wsum[4];
    float v = 0.f;
    for (int i = blockIdx.x * 256 + threadIdx.x; i < NE; i += 256 * 256)
        v += eattr[i];
    v = wave_reduce_sum(v);
    int wid = threadIdx.x >> 6, l = threadIdx.x & 63;
    if (l == 0) wsum[wid] = v;
    __syncthreads();
    if (threadIdx.x == 0)
        atomicAdd(&sc[0], wsum[0] + wsum[1] + wsum[2] + wsum[3]);
}

__global__ void k_consts(const float* We1, const float* ae1,
                         const float* We2, const float* ae2, float* sc) {
    int l = threadIdx.x;  // 64 threads
    float v = We1[l] * ae1[l] + We1[l + 64] * ae1[l + 64];
    v = wave_reduce_sum(v);
    if (l == 0) { sc[1] = v; sc[2] = We2[0] * ae2[0]; }
}

// Packed B: Wp[s][cg][lane][j] = bf16(W1[k][c]), k = s*32 + (lane>>4)*8 + j,
// c = cg*16 + (lane&15); zero-padded for k >= FI. Load-order contiguous.
__global__ void k_wt(const float* __restrict__ W, ushort* __restrict__ Wp) {
    int i = blockIdx.x * 256 + threadIdx.x;
    if (i >= WP_ELEMS) return;
    int s = i >> 12;
    int r = i & 4095;
    int cg = r >> 9;
    int q = r & 511;
    int lane = q >> 3, j = q & 7;
    int k = s * 32 + (lane >> 4) * 8 + j;
    int c = cg * 16 + (lane & 15);
    float v = (k < FI) ? W[(size_t)k * HD + c] : 0.f;
    Wp[i] = f2bf(v);
}

// ---------------- GEMM1: h1 = x @ W1  (bf16 MFMA, A+B LDS-staged, counted-vmcnt pipeline) ----------------
// 4 waves/block, BM=64, BN=128, BK=32, double-buffered LDS (A 16KB + B 16KB).
// T4 pattern: raw s_barrier (no auto vmcnt drain) + inline-asm s_waitcnt vmcnt(4):
// stage(t+2) stays in flight across compute(t+1); only stage(t+1)'s 4 loads are waited.
// Per-wave loads/stage = 4 -> vmcnt(4) == "oldest stage complete".

__global__ __launch_bounds__(256) void k_gemm1_mfma(const float* __restrict__ x,
                                                    const ushort* __restrict__ Wp,
                                                    ushort* __restrict__ h1) {
    __shared__ float  As[2][64][32];    // 16 KB
    __shared__ ushort Bs[2][4096];      // 16 KB
    const int t = threadIdx.x;
    const int wid = t >> 6, l = t & 63;
    const int lr = l & 15, lg = l >> 4;
    const int wrow0 = blockIdx.x * 64 + wid * 16;

    const int srow = l >> 3;
    const int schunk = (l & 7) ^ srow;
    int g0 = wrow0 + srow;      if (g0 > NN - 1) g0 = NN - 1;
    int g1 = wrow0 + 8 + srow;  if (g1 > NN - 1) g1 = NN - 1;
    const float* sp0 = x + (size_t)g0 * FI + schunk * 4;
    const float* sp1 = x + (size_t)g1 * FI + schunk * 4;

    const ushort* bq0 = Wp + (wid * 2    ) * 512 + l * 8;
    const ushort* bq1 = Wp + (wid * 2 + 1) * 512 + l * 8;

    const int rs0 = (lg * 2)     ^ (lr & 7);
    const int rs1 = (lg * 2 + 1) ^ (lr & 7);

    f32x4 acc[8];
    #pragma unroll
    for (int c = 0; c < 8; ++c) acc[c] = (f32x4){0.f, 0.f, 0.f, 0.f};

#define STAGE(B, IT) do { \
    __builtin_amdgcn_global_load_lds( \
        (const __attribute__((address_space(1))) unsigned int*)(sp0 + (size_t)(IT) * 32), \
        (__attribute__((address_space(3))) unsigned int*)&As[B][wid * 16][0], 16, 0, 0); \
    __builtin_amdgcn_global_load_lds( \
        (const __attribute__((address_space(1))) unsigned int*)(sp1 + (size_t)(IT) * 32), \
        (__attribute__((address_space(3))) unsigned int*)&As[B][wid * 16 + 8][0], 16, 0, 0); \
    __builtin_amdgcn_global_load_lds( \
        (const __attribute__((address_space(1))) unsigned int*)(bq0 + (size_t)(IT) * 4096), \
        (__attribute__((address_space(3))) unsigned int*)&Bs[B][(wid * 2) * 512], 16, 0, 0); \
    __builtin_amdgcn_global_load_lds( \
        (const __attribute__((address_space(1))) unsigned int*)(bq1 + (size_t)(IT) * 4096), \
        (__attribute__((address_space(3))) unsigned int*)&Bs[B][(wid * 2 + 1) * 512], 16, 0, 0); \
} while (0)

    STAGE(0, 0);                                        // buf0 <- step 0
    STAGE(1, 1);                                        // buf1 <- step 1 (stays in flight)
    asm volatile("s_waitcnt vmcnt(4)" ::: "memory");    // step 0 landed (own 4 oldest)
    __builtin_amdgcn_s_barrier();                       // all waves' step-0 writes visible

    for (int it = 0; it < 40; ++it) {
        const int bsel = it & 1;

        bfrag bfr[8];
        #pragma unroll
        for (int cg = 0; cg < 8; ++cg)
            bfr[cg] = *(const bfrag*)&Bs[bsel][cg * 512 + l * 8];

        float4 a0 = *(const float4*)&As[bsel][wid * 16 + lr][rs0 * 4];
        float4 a1 = *(const float4*)&As[bsel][wid * 16 + lr][rs1 * 4];
        bfrag af = cvt_frag(a0, a1);
        #pragma unroll
        for (int cg = 0; cg < 8; ++cg)
            acc[cg] = __builtin_amdgcn_mfma_f32_16x16x32_bf16(af, bfr[cg], acc[cg], 0, 0, 0);

        __builtin_amdgcn_s_barrier();                   // all waves done READING buf[bsel]
        if (it + 2 < 40) {
            STAGE(bsel, it + 2);                        // refill freed buffer (async)
            asm volatile("s_waitcnt vmcnt(4)" ::: "memory");  // stage(it+1) landed
        } else {
            asm volatile("s_waitcnt vmcnt(0)" ::: "memory");  // drain remaining
        }
        __builtin_amdgcn_s_barrier();                   // stage(it+1) visible to all waves
    }
#undef STAGE

    {   // K tail: step 40 (k0=1280, valid k<1284 in lg==0 low half); Wp zero-padded
        int rowc = wrow0 + lr; if (rowc > NN - 1) rowc = NN - 1;
        float4 a0t = make_float4(0.f, 0.f, 0.f, 0.f);
        if (lg == 0) a0t = *(const float4*)(x + (size_t)rowc * FI + 1280);
        bfrag af;
        af[0] = (short)f2bf(a0t.x); af[1] = (short)f2bf(a0t.y);
        af[2] = (short)f2bf(a0t.z); af[3] = (short)f2bf(a0t.w);
        af[4] = 0; af[5] = 0; af[6] = 0; af[7] = 0;
        const ushort* wqs = Wp + (size_t)40 * 4096 + l * 8;
        #pragma unroll
        for (int cg = 0; cg < 8; ++cg) {
            bfrag bf = *(const bfrag*)(wqs + cg * 512);
            acc[cg] = __builtin_amdgcn_mfma_f32_16x16x32_bf16(af, bf, acc[cg], 0, 0, 0);
        }
    }

    #pragma unroll
    for (int cg = 0; cg < 8; ++cg) {
        #pragma unroll
        for (int r = 0; r < 4; ++r) {
            int gr = wrow0 + lg * 4 + r;
            if (gr < NN) h1[(size_t)gr * HD + cg * 16 + lr] = f2bf(acc[cg][r]);
        }
    }
}

__global__ __launch_bounds__(256) void k_rowdot(const ushort* __restrict__ h1,
                                                const float* __restrict__ asrc,
                                                const float* __restrict__ adst,
                                                float* as1, float* ad1) {
    int wid = threadIdx.x >> 6, l = threadIdx.x & 63;
    int i = blockIdx.x * 4 + wid;
    if (i >= NN) return;
    ushort2 hv = *(const ushort2*)&h1[(size_t)i * HD + 2 * l];
    float hx = bf2f(hv.x), hy = bf2f(hv.y);
    float2 av = *(const float2*)&asrc[2 * l];
    float2 dv = *(const float2*)&adst[2 * l];
    float s = hx * av.x + hy * av.y;
    float d = hx * dv.x + hy * dv.y;
    #pragma unroll
    for (int off = 32; off; off >>= 1) {
        s += __shfl_down(s, off);
        d += __shfl_down(d, off);
    }
    if (l == 0) { as1[i] = s; ad1[i] = d; }
}

// ---------------- CSR build: hist -> scan -> place ----------------

__global__ void k_hist(const int* __restrict__ ei, int* cnt) {
    int e = blockIdx.x * blockDim.x + threadIdx.x;
    if (e >= NEP) return;
    int d = (e < NE) ? ei[NE + e] : e - NE;
    atomicAdd(&cnt[d], 1);
}

__global__ void k_scan_blk(const int* __restrict__ cnt, int* incl, int* bsum) {
    __shared__ int sh[SCAN_B];
    int i = blockIdx.x * SCAN_B + threadIdx.x;
    sh[threadIdx.x] = (i < NN) ? cnt[i] : 0;
    __syncthreads();
    for (int off = 1; off < SCAN_B; off <<= 1) {
        int t = (threadIdx.x >= off) ? sh[threadIdx.x - off] : 0;
        __syncthreads();
        sh[threadIdx.x] += t;
        __syncthreads();
    }
    if (i < NN) incl[i] = sh[threadIdx.x];
    if (threadIdx.x == SCAN_B - 1) bsum[blockIdx.x] = sh[threadIdx.x];
}

__global__ void k_scan_top(int* bsum) {
    __shared__ int sh[SCAN_B];
    sh[threadIdx.x] = (threadIdx.x < NBLK) ? bsum[threadIdx.x] : 0;
    __syncthreads();
    for (int off = 1; off < SCAN_B; off <<= 1) {
        int t = (threadIdx.x >= off) ? sh[threadIdx.x - off] : 0;
        __syncthreads();
        sh[threadIdx.x] += t;
        __syncthreads();
    }
    if (threadIdx.x < NBLK) bsum[threadIdx.x] = sh[threadIdx.x];
}

__global__ void k_scan_fix(int* incl_start, const int* __restrict__ cnt,
                           const int* __restrict__ bsum, int* cursor) {
    int i = blockIdx.x * SCAN_B + threadIdx.x;
    if (i >= NN) return;
    int off = (blockIdx.x > 0) ? bsum[blockIdx.x - 1] : 0;
    int st = incl_start[i] - cnt[i] + off;
    incl_start[i] = st;
    cursor[i] = st;
}

// place edges into dst-grouped CSR: one 8B record {src, eattr_bits}
__global__ void k_place(const int* __restrict__ ei, const float* __restrict__ eattr,
                        const float* __restrict__ sc, int* cursor, int2* __restrict__ csr) {
    int e = blockIdx.x * blockDim.x + threadIdx.x;
    if (e >= NEP) return;
    int s, d; float av;
    if (e < NE) { s = ei[e]; d = ei[NE + e]; av = eattr[e]; }
    else        { s = d = e - NE; av = sc[0] * (1.0f / NE); }
    int pos = atomicAdd(&cursor[d], 1);
    csr[pos] = make_int2(s, __float_as_int(av));
}

// ---------------- layer 1 (fused): softmax over neighborhood + PV + ELU + W2-dot ----------------
__global__ __launch_bounds__(256) void k_layer1(const int2* __restrict__ csr,
                                                const int* __restrict__ start,
                                                const int* __restrict__ cnt,
                                                const float* __restrict__ as1,
                                                const float* __restrict__ ad1,
                                                const float* __restrict__ sc,
                                                const ushort* __restrict__ h1,
                                                const float* __restrict__ b1,
                                                const float* __restrict__ W2,
                                                float* __restrict__ h2) {
    int wid = threadIdx.x >> 6, l = threadIdx.x & 63;
    int d = blockIdx.x * 4 + wid;
    if (d >= NN) return;
    int s0 = start[d], n = cnt[d];
    float adv = ad1[d], c1 = sc[1];

    float m = -INFINITY;
    for (int i = 0; i < n; ++i) {
        int2 sa = csr[s0 + i];
        float a = as1[sa.x] + adv + c1 * __int_as_float(sa.y);
        a = (a > 0.f) ? a : 0.2f * a;
        m = fmaxf(m, a);
    }
    float den = 0.f, ax = 0.f, ay = 0.f;
    for (int i = 0; i < n; ++i) {
        int2 sa = csr[s0 + i];
        float a = as1[sa.x] + adv + c1 * __int_as_float(sa.y);
        a = (a > 0.f) ? a : 0.2f * a;
        float wgt = expf(a - m);
        den += wgt;
        ushort2 hv = *(const ushort2*)&h1[(size_t)sa.x * HD + 2 * l];
        ax += wgt * bf2f(hv.x); ay += wgt * bf2f(hv.y);
    }
    float inv = 1.f / (den + 1e-16f);
    ax *= inv; ay *= inv;
    float2 bb = *(const float2*)&b1[2 * l];
    float2 w  = *(const float2*)&W2[2 * l];
    float a = ax + bb.x; a = (a > 0.f) ? a : (expf(a) - 1.f);
    float b = ay + bb.y; b = (b > 0.f) ? b : (expf(b) - 1.f);
    float p = a * w.x + b * w.y;
    p = wave_reduce_sum(p);
    if (l == 0) h2[d] = p;
}

// ---------------- layer 2 (fused, scalar): softmax + weighted sum + bias + leaky ----------------
__global__ __launch_bounds__(256) void k_layer2(const int2* __restrict__ csr,
                                                const int* __restrict__ start,
                                                const int* __restrict__ cnt,
                                                const float* __restrict__ h2,
                                                const float* __restrict__ as2,
                                                const float* __restrict__ ad2,
                                                const float* __restrict__ sc,
                                                const float* __restrict__ b2,
                                                float* __restrict__ out) {
    int d = blockIdx.x * blockDim.x + threadIdx.x;
    if (d >= NN) return;
    int s0 = start[d], n = cnt[d];
    float A = as2[0], D = ad2[0], c2 = sc[2];
    float hd = D * h2[d];

    float m = -INFINITY;
    for (int i = 0; i < n; ++i) {
        int2 sa = csr[s0 + i];
        float a = A * h2[sa.x] + hd + c2 * __int_as_float(sa.y);
        a = (a > 0.f) ? a : 0.2f * a;
        m = fmaxf(m, a);
    }
    float den = 0.f, num = 0.f;
    for (int i = 0; i < n; ++i) {
        int2 sa = csr[s0 + i];
        float hs = h2[sa.x];
        float a = A * hs + hd + c2 * __int_as_float(sa.y);
        a = (a > 0.f) ? a : 0.2f * a;
        float wgt = expf(a - m);
        den += wgt;
        num += wgt * hs;
    }
    float v = num / (den + 1e-16f) + b2[0];
    out[d] = (v >= 0.f) ? v : 0.01f * v;
}

// ---------------- launch ----------------

extern "C" void kernel_launch(void* const* d_in, const int* in_sizes, int n_in,
                              void* d_out, int out_size, void* d_ws, size_t ws_size,
                              hipStream_t stream) {
    const float* x     = (const float*)d_in[0];
    const int*   ei    = (const int*)d_in[1];
    const float* eattr = (const float*)d_in[2];
    const float* W1    = (const float*)d_in[3];
    const float* asrc1 = (const float*)d_in[4];
    const float* adst1 = (const float*)d_in[5];
    const float* We1   = (const float*)d_in[6];
    const float* ae1   = (const float*)d_in[7];
    const float* b1    = (const float*)d_in[8];
    const float* W2    = (const float*)d_in[9];
    const float* as2   = (const float*)d_in[10];
    const float* ad2   = (const float*)d_in[11];
    const float* We2   = (const float*)d_in[12];
    const float* ae2   = (const float*)d_in[13];
    const float* b2    = (const float*)d_in[14];
    float* out = (float*)d_out;

    // workspace layout (~21.3 MB)
    ushort* h1  = (ushort*)d_ws;              // NH ushorts (12.8 MB)
    float* as1  = (float*)(h1 + (size_t)NH);  // NN
    float* ad1  = as1 + NN;
    float* h2   = ad1 + NN;
    float* sc   = h2 + NN;                    // 8 scalars
    int*   cnt    = (int*)(sc + 8);           // NN
    int*   start  = cnt + NN;                 // NN
    int*   cursor = start + NN;               // NN
    int*   bsum   = cursor + NN;              // 256
    int2*  csr    = (int2*)(bsum + 256);      // NEP int2 (6.8 MB)
    ushort* Wp  = (ushort*)(csr + NEP);       // WP_ELEMS bf16 (packed)

    k_init<<<(NN + 255) / 256, 256, 0, stream>>>(cnt, sc);
    k_sum_attr<<<256, 256, 0, stream>>>(eattr, sc);
    k_consts<<<1, 64, 0, stream>>>(We1, ae1, We2, ae2, sc);
    k_wt<<<(WP_ELEMS + 255) / 256, 256, 0, stream>>>(W1, Wp);

    k_gemm1_mfma<<<NROWB, 256, 0, stream>>>(x, Wp, h1);
    k_rowdot<<<(NN + 3) / 4, 256, 0, stream>>>(h1, asrc1, adst1, as1, ad1);

    k_hist<<<(NEP + 255) / 256, 256, 0, stream>>>(ei, cnt);
    k_scan_blk<<<NBLK, SCAN_B, 0, stream>>>(cnt, start, bsum);
    k_scan_top<<<1, SCAN_B, 0, stream>>>(bsum);
    k_scan_fix<<<NBLK, SCAN_B, 0, stream>>>(start, cnt, bsum, cursor);
    k_place<<<(NEP + 255) / 256, 256, 0, stream>>>(ei, eattr, sc, cursor, csr);

    k_layer1<<<(NN + 3) / 4, 256, 0, stream>>>(csr, start, cnt, as1, ad1, sc, h1, b1, W2, h2);
    k_layer2<<<(NN + 255) / 256, 256, 0, stream>>>(csr, start, cnt, h2, as2, ad2, sc, b2, out);
}

// Round 12
// 320.248 us; speedup vs baseline: 2.4622x; 1.1507x over previous
//
#include <hip/hip_runtime.h>
#include <math.h>

#define NN 50000
#define NE 800000
#define NEP 850000          // NE + NN self loops
#define FI 1284
#define HD 128
#define KP 1312             // FI padded to 41*32 for MFMA K-loop
#define NSTEP 41            // KP/32
#define NH (NN * HD)        // 6,400,000
#define SCAN_B 256
#define NBLK ((NN + SCAN_B - 1) / SCAN_B)   // 196 (<=256)
#define NROWB ((NN + 63) / 64)              // 782 row-blocks of 64
#define WP_ELEMS (NSTEP * 4096)             // packed B: 41 steps * 8cg * 64lane * 8

typedef float f32x4 __attribute__((ext_vector_type(4)));
typedef short bfrag __attribute__((ext_vector_type(8)));   // 8 bf16 in 4 VGPRs

// ---------------- helpers ----------------

__device__ __forceinline__ float wave_reduce_sum(float v) {
    #pragma unroll
    for (int off = 32; off; off >>= 1) v += __shfl_down(v, off);
    return v;
}

__device__ __forceinline__ ushort f2bf(float f) {   // RNE fp32->bf16 bits
    unsigned u = __float_as_uint(f);
    u += 0x7FFFu + ((u >> 16) & 1u);
    return (ushort)(u >> 16);
}

__device__ __forceinline__ float bf2f(ushort u) {
    return __uint_as_float(((unsigned)u) << 16);
}

__device__ __forceinline__ bfrag cvt_frag(float4 a0, float4 a1) {
    bfrag af;
    af[0] = (short)f2bf(a0.x); af[1] = (short)f2bf(a0.y);
    af[2] = (short)f2bf(a0.z); af[3] = (short)f2bf(a0.w);
    af[4] = (short)f2bf(a1.x); af[5] = (short)f2bf(a1.y);
    af[6] = (short)f2bf(a1.z); af[7] = (short)f2bf(a1.w);
    return af;
}

// ---------------- init ----------------

__global__ void k_init(int* cnt, float* sc) {
    int i = blockIdx.x * blockDim.x + threadIdx.x;
    if (i < NN) cnt[i] = 0;
    if (i < 8) sc[i] = 0.f;
}

__global__ __launch_bounds__(256) void k_sum_attr(const float* __restrict__ eattr, float* sc) {
    __shared__ float wsum[4];
    float v = 0.f;
    for (int i = blockIdx.x * 256 + threadIdx.x; i < NE; i += 256 * 256)
        v += eattr[i];
    v = wave_reduce_sum(v);
    int wid = threadIdx.x >> 6, l = threadIdx.x & 63;
    if (l == 0) wsum[wid] = v;
    __syncthreads();
    if (threadIdx.x == 0)
        atomicAdd(&sc[0], wsum[0] + wsum[1] + wsum[2] + wsum[3]);
}

__global__ void k_consts(const float* We1, const float* ae1,
                         const float* We2, const float* ae2, float* sc) {
    int l = threadIdx.x;  // 64 threads
    float v = We1[l] * ae1[l] + We1[l + 64] * ae1[l + 64];
    v = wave_reduce_sum(v);
    if (l == 0) { sc[1] = v; sc[2] = We2[0] * ae2[0]; }
}

// Packed B: Wp[s][cg][lane][j] = bf16(W1[k][c]); zero-padded for k >= FI.
__global__ void k_wt(const float* __restrict__ W, ushort* __restrict__ Wp) {
    int i = blockIdx.x * 256 + threadIdx.x;
    if (i >= WP_ELEMS) return;
    int s = i >> 12;
    int r = i & 4095;
    int cg = r >> 9;
    int q = r & 511;
    int lane = q >> 3, j = q & 7;
    int k = s * 32 + (lane >> 4) * 8 + j;
    int c = cg * 16 + (lane & 15);
    float v = (k < FI) ? W[(size_t)k * HD + c] : 0.f;
    Wp[i] = f2bf(v);
}

// ---------------- GEMM1: h1 = x @ W1  (bf16 MFMA, 3-buffer depth-2 async pipeline) ----------------
// 4 waves/block, BM=64, BN=128, BK=32. LDS = 3 x (A 8KB + B 8KB) = 48 KB.
// Stages for t+1 AND t+2 in flight: wait for stage(t+1) sits 2 compute windows
// after its issue. vmcnt(8) steady (2 stages x 4 loads/wave), 4 -> 0 in tail.

__global__ __launch_bounds__(256) void k_gemm1_mfma(const float* __restrict__ x,
                                                    const ushort* __restrict__ Wp,
                                                    ushort* __restrict__ h1) {
    __shared__ float  As[3][64][32];    // 24 KB
    __shared__ ushort Bs[3][4096];      // 24 KB
    const int t = threadIdx.x;
    const int wid = t >> 6, l = t & 63;
    const int lr = l & 15, lg = l >> 4;
    const int wrow0 = blockIdx.x * 64 + wid * 16;

    const int srow = l >> 3;
    const int schunk = (l & 7) ^ srow;
    int g0 = wrow0 + srow;      if (g0 > NN - 1) g0 = NN - 1;
    int g1 = wrow0 + 8 + srow;  if (g1 > NN - 1) g1 = NN - 1;
    const float* sp0 = x + (size_t)g0 * FI + schunk * 4;
    const float* sp1 = x + (size_t)g1 * FI + schunk * 4;

    const ushort* bq0 = Wp + (wid * 2    ) * 512 + l * 8;
    const ushort* bq1 = Wp + (wid * 2 + 1) * 512 + l * 8;

    const int rs0 = (lg * 2)     ^ (lr & 7);
    const int rs1 = (lg * 2 + 1) ^ (lr & 7);

    f32x4 acc[8];
    #pragma unroll
    for (int c = 0; c < 8; ++c) acc[c] = (f32x4){0.f, 0.f, 0.f, 0.f};

#define STAGE(B, IT) do { \
    __builtin_amdgcn_global_load_lds( \
        (const __attribute__((address_space(1))) unsigned int*)(sp0 + (size_t)(IT) * 32), \
        (__attribute__((address_space(3))) unsigned int*)&As[B][wid * 16][0], 16, 0, 0); \
    __builtin_amdgcn_global_load_lds( \
        (const __attribute__((address_space(1))) unsigned int*)(sp1 + (size_t)(IT) * 32), \
        (__attribute__((address_space(3))) unsigned int*)&As[B][wid * 16 + 8][0], 16, 0, 0); \
    __builtin_amdgcn_global_load_lds( \
        (const __attribute__((address_space(1))) unsigned int*)(bq0 + (size_t)(IT) * 4096), \
        (__attribute__((address_space(3))) unsigned int*)&Bs[B][(wid * 2) * 512], 16, 0, 0); \
    __builtin_amdgcn_global_load_lds( \
        (const __attribute__((address_space(1))) unsigned int*)(bq1 + (size_t)(IT) * 4096), \
        (__attribute__((address_space(3))) unsigned int*)&Bs[B][(wid * 2 + 1) * 512], 16, 0, 0); \
} while (0)

    // prologue: fill 3 buffers (steps 0,1,2); wait only for step 0 (8 newest stay in flight)
    STAGE(0, 0);
    STAGE(1, 1);
    STAGE(2, 2);
    asm volatile("s_waitcnt vmcnt(8)" ::: "memory");
    __builtin_amdgcn_s_barrier();

    int bsel = 0;
    for (int it = 0; it < 40; ++it) {
        bfrag bfr[8];
        #pragma unroll
        for (int cg = 0; cg < 8; ++cg)
            bfr[cg] = *(const bfrag*)&Bs[bsel][cg * 512 + l * 8];

        float4 a0 = *(const float4*)&As[bsel][wid * 16 + lr][rs0 * 4];
        float4 a1 = *(const float4*)&As[bsel][wid * 16 + lr][rs1 * 4];
        bfrag af = cvt_frag(a0, a1);
        #pragma unroll
        for (int cg = 0; cg < 8; ++cg)
            acc[cg] = __builtin_amdgcn_mfma_f32_16x16x32_bf16(af, bfr[cg], acc[cg], 0, 0, 0);

        __builtin_amdgcn_s_barrier();                   // all waves done READING buf[bsel]
        if (it + 3 < 40) {
            STAGE(bsel, it + 3);                        // refill freed buffer (async)
            asm volatile("s_waitcnt vmcnt(8)" ::: "memory");  // stage(it+1) landed
        } else if (it == 37) {
            asm volatile("s_waitcnt vmcnt(4)" ::: "memory");  // stage(38) landed
        } else if (it == 38) {
            asm volatile("s_waitcnt vmcnt(0)" ::: "memory");  // stage(39) landed
        }
        __builtin_amdgcn_s_barrier();                   // staged writes visible to all waves
        bsel = (bsel == 2) ? 0 : bsel + 1;
    }
#undef STAGE

    {   // K tail: step 40 (k0=1280, valid k<1284 in lg==0 low half); Wp zero-padded
        int rowc = wrow0 + lr; if (rowc > NN - 1) rowc = NN - 1;
        float4 a0t = make_float4(0.f, 0.f, 0.f, 0.f);
        if (lg == 0) a0t = *(const float4*)(x + (size_t)rowc * FI + 1280);
        bfrag af;
        af[0] = (short)f2bf(a0t.x); af[1] = (short)f2bf(a0t.y);
        af[2] = (short)f2bf(a0t.z); af[3] = (short)f2bf(a0t.w);
        af[4] = 0; af[5] = 0; af[6] = 0; af[7] = 0;
        const ushort* wqs = Wp + (size_t)40 * 4096 + l * 8;
        #pragma unroll
        for (int cg = 0; cg < 8; ++cg) {
            bfrag bf = *(const bfrag*)(wqs + cg * 512);
            acc[cg] = __builtin_amdgcn_mfma_f32_16x16x32_bf16(af, bf, acc[cg], 0, 0, 0);
        }
    }

    #pragma unroll
    for (int cg = 0; cg < 8; ++cg) {
        #pragma unroll
        for (int r = 0; r < 4; ++r) {
            int gr = wrow0 + lg * 4 + r;
            if (gr < NN) h1[(size_t)gr * HD + cg * 16 + lr] = f2bf(acc[cg][r]);
        }
    }
}

__global__ __launch_bounds__(256) void k_rowdot(const ushort* __restrict__ h1,
                                                const float* __restrict__ asrc,
                                                const float* __restrict__ adst,
                                                float* as1, float* ad1) {
    int wid = threadIdx.x >> 6, l = threadIdx.x & 63;
    int i = blockIdx.x * 4 + wid;
    if (i >= NN) return;
    ushort2 hv = *(const ushort2*)&h1[(size_t)i * HD + 2 * l];
    float hx = bf2f(hv.x), hy = bf2f(hv.y);
    float2 av = *(const float2*)&asrc[2 * l];
    float2 dv = *(const float2*)&adst[2 * l];
    float s = hx * av.x + hy * av.y;
    float d = hx * dv.x + hy * dv.y;
    #pragma unroll
    for (int off = 32; off; off >>= 1) {
        s += __shfl_down(s, off);
        d += __shfl_down(d, off);
    }
    if (l == 0) { as1[i] = s; ad1[i] = d; }
}

// ---------------- CSR build: hist -> scan -> place(+alpha) ----------------

__global__ void k_hist(const int* __restrict__ ei, int* cnt) {
    int e = blockIdx.x * blockDim.x + threadIdx.x;
    if (e >= NEP) return;
    int d = (e < NE) ? ei[NE + e] : e - NE;
    atomicAdd(&cnt[d], 1);
}

__global__ void k_scan_blk(const int* __restrict__ cnt, int* incl, int* bsum) {
    __shared__ int sh[SCAN_B];
    int i = blockIdx.x * SCAN_B + threadIdx.x;
    sh[threadIdx.x] = (i < NN) ? cnt[i] : 0;
    __syncthreads();
    for (int off = 1; off < SCAN_B; off <<= 1) {
        int t = (threadIdx.x >= off) ? sh[threadIdx.x - off] : 0;
        __syncthreads();
        sh[threadIdx.x] += t;
        __syncthreads();
    }
    if (i < NN) incl[i] = sh[threadIdx.x];
    if (threadIdx.x == SCAN_B - 1) bsum[blockIdx.x] = sh[threadIdx.x];
}

__global__ void k_scan_top(int* bsum) {
    __shared__ int sh[SCAN_B];
    sh[threadIdx.x] = (threadIdx.x < NBLK) ? bsum[threadIdx.x] : 0;
    __syncthreads();
    for (int off = 1; off < SCAN_B; off <<= 1) {
        int t = (threadIdx.x >= off) ? sh[threadIdx.x - off] : 0;
        __syncthreads();
        sh[threadIdx.x] += t;
        __syncthreads();
    }
    if (threadIdx.x < NBLK) bsum[threadIdx.x] = sh[threadIdx.x];
}

__global__ void k_scan_fix(int* incl_start, const int* __restrict__ cnt,
                           const int* __restrict__ bsum, int* cursor) {
    int i = blockIdx.x * SCAN_B + threadIdx.x;
    if (i >= NN) return;
    int off = (blockIdx.x > 0) ? bsum[blockIdx.x - 1] : 0;
    int st = incl_start[i] - cnt[i] + off;
    incl_start[i] = st;
    cursor[i] = st;
}

// place edges into dst-grouped CSR + precompute layer-1 post-leaky alpha.
// runs after k_rowdot; the as1/ad1 gathers hide under this pass's full TLP.
__global__ void k_place(const int* __restrict__ ei, const float* __restrict__ eattr,
                        const float* __restrict__ sc,
                        const float* __restrict__ as1, const float* __restrict__ ad1,
                        int* cursor, int2* __restrict__ csr, float* __restrict__ csr_al) {
    int e = blockIdx.x * blockDim.x + threadIdx.x;
    if (e >= NEP) return;
    int s, d; float av;
    if (e < NE) { s = ei[e]; d = ei[NE + e]; av = eattr[e]; }
    else        { s = d = e - NE; av = sc[0] * (1.0f / NE); }
    float a = as1[s] + ad1[d] + sc[1] * av;
    a = (a > 0.f) ? a : 0.2f * a;
    int pos = atomicAdd(&cursor[d], 1);
    csr[pos] = make_int2(s, __float_as_int(av));
    csr_al[pos] = a;
}

// ---------------- layer 1 (fused): streamed-alpha softmax + PV + ELU + W2-dot ----------------
// one wave per dst. max-loop streams csr_al (no gathers); exp-loop unrolled x2 for MLP.
__global__ __launch_bounds__(256) void k_layer1(const int2* __restrict__ csr,
                                                const float* __restrict__ csr_al,
                                                const int* __restrict__ start,
                                                const int* __restrict__ cnt,
                                                const ushort* __restrict__ h1,
                                                const float* __restrict__ b1,
                                                const float* __restrict__ W2,
                                                float* __restrict__ h2) {
    int wid = threadIdx.x >> 6, l = threadIdx.x & 63;
    int d = blockIdx.x * 4 + wid;
    if (d >= NN) return;
    int s0 = start[d], n = cnt[d];

    float m = -INFINITY;
    for (int i = 0; i < n; ++i) m = fmaxf(m, csr_al[s0 + i]);

    float den = 0.f, ax = 0.f, ay = 0.f;
    int i = 0;
    for (; i + 2 <= n; i += 2) {
        int2 e0 = csr[s0 + i], e1 = csr[s0 + i + 1];
        float w0 = expf(csr_al[s0 + i] - m);
        float w1 = expf(csr_al[s0 + i + 1] - m);
        ushort2 hv0 = *(const ushort2*)&h1[(size_t)e0.x * HD + 2 * l];
        ushort2 hv1 = *(const ushort2*)&h1[(size_t)e1.x * HD + 2 * l];
        den += w0 + w1;
        ax += w0 * bf2f(hv0.x) + w1 * bf2f(hv1.x);
        ay += w0 * bf2f(hv0.y) + w1 * bf2f(hv1.y);
    }
    if (i < n) {
        int2 e0 = csr[s0 + i];
        float w0 = expf(csr_al[s0 + i] - m);
        ushort2 hv0 = *(const ushort2*)&h1[(size_t)e0.x * HD + 2 * l];
        den += w0;
        ax += w0 * bf2f(hv0.x);
        ay += w0 * bf2f(hv0.y);
    }
    float inv = 1.f / (den + 1e-16f);
    ax *= inv; ay *= inv;
    float2 bb = *(const float2*)&b1[2 * l];
    float2 w  = *(const float2*)&W2[2 * l];
    float a = ax + bb.x; a = (a > 0.f) ? a : (expf(a) - 1.f);
    float b = ay + bb.y; b = (b > 0.f) ? b : (expf(b) - 1.f);
    float p = a * w.x + b * w.y;
    p = wave_reduce_sum(p);
    if (l == 0) h2[d] = p;
}

// ---------------- layer 2 (fused, scalar): softmax + weighted sum + bias + leaky ----------------
__global__ __launch_bounds__(256) void k_layer2(const int2* __restrict__ csr,
                                                const int* __restrict__ start,
                                                const int* __restrict__ cnt,
                                                const float* __restrict__ h2,
                                                const float* __restrict__ as2,
                                                const float* __restrict__ ad2,
                                                const float* __restrict__ sc,
                                                const float* __restrict__ b2,
                                                float* __restrict__ out) {
    int d = blockIdx.x * blockDim.x + threadIdx.x;
    if (d >= NN) return;
    int s0 = start[d], n = cnt[d];
    float A = as2[0], D = ad2[0], c2 = sc[2];
    float hd = D * h2[d];

    float m = -INFINITY;
    for (int i = 0; i < n; ++i) {
        int2 sa = csr[s0 + i];
        float a = A * h2[sa.x] + hd + c2 * __int_as_float(sa.y);
        a = (a > 0.f) ? a : 0.2f * a;
        m = fmaxf(m, a);
    }
    float den = 0.f, num = 0.f;
    for (int i = 0; i < n; ++i) {
        int2 sa = csr[s0 + i];
        float hs = h2[sa.x];
        float a = A * hs + hd + c2 * __int_as_float(sa.y);
        a = (a > 0.f) ? a : 0.2f * a;
        float wgt = expf(a - m);
        den += wgt;
        num += wgt * hs;
    }
    float v = num / (den + 1e-16f) + b2[0];
    out[d] = (v >= 0.f) ? v : 0.01f * v;
}

// ---------------- launch ----------------

extern "C" void kernel_launch(void* const* d_in, const int* in_sizes, int n_in,
                              void* d_out, int out_size, void* d_ws, size_t ws_size,
                              hipStream_t stream) {
    const float* x     = (const float*)d_in[0];
    const int*   ei    = (const int*)d_in[1];
    const float* eattr = (const float*)d_in[2];
    const float* W1    = (const float*)d_in[3];
    const float* asrc1 = (const float*)d_in[4];
    const float* adst1 = (const float*)d_in[5];
    const float* We1   = (const float*)d_in[6];
    const float* ae1   = (const float*)d_in[7];
    const float* b1    = (const float*)d_in[8];
    const float* W2    = (const float*)d_in[9];
    const float* as2   = (const float*)d_in[10];
    const float* ad2   = (const float*)d_in[11];
    const float* We2   = (const float*)d_in[12];
    const float* ae2   = (const float*)d_in[13];
    const float* b2    = (const float*)d_in[14];
    float* out = (float*)d_out;

    // workspace layout (~24.8 MB)
    ushort* h1  = (ushort*)d_ws;              // NH ushorts (12.8 MB)
    float* as1  = (float*)(h1 + (size_t)NH);  // NN
    float* ad1  = as1 + NN;
    float* h2   = ad1 + NN;
    float* sc   = h2 + NN;                    // 8 scalars
    int*   cnt    = (int*)(sc + 8);           // NN
    int*   start  = cnt + NN;                 // NN
    int*   cursor = start + NN;               // NN
    int*   bsum   = cursor + NN;              // 256
    int2*  csr    = (int2*)(bsum + 256);      // NEP int2 (6.8 MB)
    float* csr_al = (float*)(csr + NEP);      // NEP floats (3.4 MB)
    ushort* Wp  = (ushort*)(csr_al + NEP);    // WP_ELEMS bf16 (packed)

    k_init<<<(NN + 255) / 256, 256, 0, stream>>>(cnt, sc);
    k_sum_attr<<<256, 256, 0, stream>>>(eattr, sc);
    k_consts<<<1, 64, 0, stream>>>(We1, ae1, We2, ae2, sc);
    k_wt<<<(WP_ELEMS + 255) / 256, 256, 0, stream>>>(W1, Wp);

    k_gemm1_mfma<<<NROWB, 256, 0, stream>>>(x, Wp, h1);
    k_rowdot<<<(NN + 3) / 4, 256, 0, stream>>>(h1, asrc1, adst1, as1, ad1);

    k_hist<<<(NEP + 255) / 256, 256, 0, stream>>>(ei, cnt);
    k_scan_blk<<<NBLK, SCAN_B, 0, stream>>>(cnt, start, bsum);
    k_scan_top<<<1, SCAN_B, 0, stream>>>(bsum);
    k_scan_fix<<<NBLK, SCAN_B, 0, stream>>>(start, cnt, bsum, cursor);
    k_place<<<(NEP + 255) / 256, 256, 0, stream>>>(ei, eattr, sc, as1, ad1, cursor, csr, csr_al);

    k_layer1<<<(NN + 3) / 4, 256, 0, stream>>>(csr, csr_al, start, cnt, h1, b1, W2, h2);
    k_layer2<<<(NN + 255) / 256, 256, 0, stream>>>(csr, start, cnt, h2, as2, ad2, sc, b2, out);
}

// Round 13
// 280.775 us; speedup vs baseline: 2.8084x; 1.1406x over previous
//
#include <hip/hip_runtime.h>
#include <math.h>

#define NN 50000
#define NE 800000
#define NEP 850000          // NE + NN self loops
#define FI 1284
#define HD 128
#define KP 1312             // FI padded to 41*32 for MFMA K-loop
#define NSTEP 41            // KP/32
#define NH (NN * HD)        // 6,400,000
#define SCAN_B 256
#define NBLK ((NN + SCAN_B - 1) / SCAN_B)   // 196 (<=256)
#define NROWB ((NN + 63) / 64)              // 782 row-blocks of 64
#define WP_ELEMS (NSTEP * 4096)             // packed B: 41 steps * 8cg * 64lane * 8
#define WT_BLKS ((WP_ELEMS + 255) / 256)    // 657
#define HIST_BLKS ((NEP + 255) / 256)       // 3321

typedef float f32x4 __attribute__((ext_vector_type(4)));
typedef short bfrag __attribute__((ext_vector_type(8)));   // 8 bf16 in 4 VGPRs

// ---------------- helpers ----------------

__device__ __forceinline__ float wave_reduce_sum(float v) {
    #pragma unroll
    for (int off = 32; off; off >>= 1) v += __shfl_down(v, off);
    return v;
}

__device__ __forceinline__ ushort f2bf(float f) {   // RNE fp32->bf16 bits
    unsigned u = __float_as_uint(f);
    u += 0x7FFFu + ((u >> 16) & 1u);
    return (ushort)(u >> 16);
}

__device__ __forceinline__ float bf2f(ushort u) {
    return __uint_as_float(((unsigned)u) << 16);
}

__device__ __forceinline__ ushort f2h(float f) {    // fp32 -> fp16 bits (RNE)
    _Float16 h = (_Float16)f;
    return *(ushort*)&h;
}

__device__ __forceinline__ float h2f(ushort u) {
    _Float16 h = *(_Float16*)&u;
    return (float)h;
}

__device__ __forceinline__ bfrag cvt_frag(float4 a0, float4 a1) {
    bfrag af;
    af[0] = (short)f2bf(a0.x); af[1] = (short)f2bf(a0.y);
    af[2] = (short)f2bf(a0.z); af[3] = (short)f2bf(a0.w);
    af[4] = (short)f2bf(a1.x); af[5] = (short)f2bf(a1.y);
    af[6] = (short)f2bf(a1.z); af[7] = (short)f2bf(a1.w);
    return af;
}

// ---------------- fused preamble A: init (cnt, sc[0],sc[3..7]) + consts (sc[1],sc[2]) ----------------
// disjoint sc addresses -> no cross-block race.

__global__ __launch_bounds__(256) void k_pre_a(int* cnt, float* sc,
                                               const float* We1, const float* ae1,
                                               const float* We2, const float* ae2) {
    if (blockIdx.x < NBLK) {
        int i = blockIdx.x * 256 + threadIdx.x;
        if (i < NN) cnt[i] = 0;
        if (i == 0) { sc[0] = 0.f; sc[3] = 0.f; sc[4] = 0.f; sc[5] = 0.f; sc[6] = 0.f; sc[7] = 0.f; }
    } else if (threadIdx.x < 64) {
        int l = threadIdx.x;
        float v = We1[l] * ae1[l] + We1[l + 64] * ae1[l + 64];
        v = wave_reduce_sum(v);
        if (l == 0) { sc[1] = v; sc[2] = We2[0] * ae2[0]; }
    }
}

// ---------------- fused preamble B: k_wt || sum_attr || hist (all need only pre_a) ----------------

__global__ __launch_bounds__(256) void k_pre_b(const float* __restrict__ W, ushort* __restrict__ Wp,
                                               const float* __restrict__ eattr, float* sc,
                                               const int* __restrict__ ei, int* cnt) {
    int b = blockIdx.x;
    if (b < WT_BLKS) {
        int i = b * 256 + threadIdx.x;
        if (i >= WP_ELEMS) return;
        int s = i >> 12;
        int r = i & 4095;
        int cg = r >> 9;
        int q = r & 511;
        int lane = q >> 3, j = q & 7;
        int k = s * 32 + (lane >> 4) * 8 + j;
        int c = cg * 16 + (lane & 15);
        float v = (k < FI) ? W[(size_t)k * HD + c] : 0.f;
        Wp[i] = f2bf(v);
    } else if (b < WT_BLKS + 256) {
        __shared__ float wsum[4];
        int b2 = b - WT_BLKS;
        float v = 0.f;
        for (int i = b2 * 256 + threadIdx.x; i < NE; i += 256 * 256)
            v += eattr[i];
        v = wave_reduce_sum(v);
        int wid = threadIdx.x >> 6, l = threadIdx.x & 63;
        if (l == 0) wsum[wid] = v;
        __syncthreads();
        if (threadIdx.x == 0)
            atomicAdd(&sc[0], wsum[0] + wsum[1] + wsum[2] + wsum[3]);
    } else {
        int e = (b - WT_BLKS - 256) * 256 + threadIdx.x;
        if (e >= NEP) return;
        int d = (e < NE) ? ei[NE + e] : e - NE;
        atomicAdd(&cnt[d], 1);
    }
}

// ---------------- GEMM1: h1 = x @ W1 (bf16 MFMA, 3-buffer depth-2) + fused rowdot epilogue ----------------

__global__ __launch_bounds__(256) void k_gemm1_mfma(const float* __restrict__ x,
                                                    const ushort* __restrict__ Wp,
                                                    ushort* __restrict__ h1,
                                                    const float* __restrict__ asrc,
                                                    const float* __restrict__ adst,
                                                    float* __restrict__ as1,
                                                    float* __restrict__ ad1) {
    __shared__ float  As[3][64][32];    // 24 KB
    __shared__ ushort Bs[3][4096];      // 24 KB
    const int t = threadIdx.x;
    const int wid = t >> 6, l = t & 63;
    const int lr = l & 15, lg = l >> 4;
    const int wrow0 = blockIdx.x * 64 + wid * 16;

    const int srow = l >> 3;
    const int schunk = (l & 7) ^ srow;
    int g0 = wrow0 + srow;      if (g0 > NN - 1) g0 = NN - 1;
    int g1 = wrow0 + 8 + srow;  if (g1 > NN - 1) g1 = NN - 1;
    const float* sp0 = x + (size_t)g0 * FI + schunk * 4;
    const float* sp1 = x + (size_t)g1 * FI + schunk * 4;

    const ushort* bq0 = Wp + (wid * 2    ) * 512 + l * 8;
    const ushort* bq1 = Wp + (wid * 2 + 1) * 512 + l * 8;

    const int rs0 = (lg * 2)     ^ (lr & 7);
    const int rs1 = (lg * 2 + 1) ^ (lr & 7);

    f32x4 acc[8];
    #pragma unroll
    for (int c = 0; c < 8; ++c) acc[c] = (f32x4){0.f, 0.f, 0.f, 0.f};

#define STAGE(B, IT) do { \
    __builtin_amdgcn_global_load_lds( \
        (const __attribute__((address_space(1))) unsigned int*)(sp0 + (size_t)(IT) * 32), \
        (__attribute__((address_space(3))) unsigned int*)&As[B][wid * 16][0], 16, 0, 0); \
    __builtin_amdgcn_global_load_lds( \
        (const __attribute__((address_space(1))) unsigned int*)(sp1 + (size_t)(IT) * 32), \
        (__attribute__((address_space(3))) unsigned int*)&As[B][wid * 16 + 8][0], 16, 0, 0); \
    __builtin_amdgcn_global_load_lds( \
        (const __attribute__((address_space(1))) unsigned int*)(bq0 + (size_t)(IT) * 4096), \
        (__attribute__((address_space(3))) unsigned int*)&Bs[B][(wid * 2) * 512], 16, 0, 0); \
    __builtin_amdgcn_global_load_lds( \
        (const __attribute__((address_space(1))) unsigned int*)(bq1 + (size_t)(IT) * 4096), \
        (__attribute__((address_space(3))) unsigned int*)&Bs[B][(wid * 2 + 1) * 512], 16, 0, 0); \
} while (0)

    STAGE(0, 0);
    STAGE(1, 1);
    STAGE(2, 2);
    asm volatile("s_waitcnt vmcnt(8)" ::: "memory");
    __builtin_amdgcn_s_barrier();

    int bsel = 0;
    for (int it = 0; it < 40; ++it) {
        bfrag bfr[8];
        #pragma unroll
        for (int cg = 0; cg < 8; ++cg)
            bfr[cg] = *(const bfrag*)&Bs[bsel][cg * 512 + l * 8];

        float4 a0 = *(const float4*)&As[bsel][wid * 16 + lr][rs0 * 4];
        float4 a1 = *(const float4*)&As[bsel][wid * 16 + lr][rs1 * 4];
        bfrag af = cvt_frag(a0, a1);
        #pragma unroll
        for (int cg = 0; cg < 8; ++cg)
            acc[cg] = __builtin_amdgcn_mfma_f32_16x16x32_bf16(af, bfr[cg], acc[cg], 0, 0, 0);

        __builtin_amdgcn_s_barrier();
        if (it + 3 < 40) {
            STAGE(bsel, it + 3);
            asm volatile("s_waitcnt vmcnt(8)" ::: "memory");
        } else if (it == 37) {
            asm volatile("s_waitcnt vmcnt(4)" ::: "memory");
        } else if (it == 38) {
            asm volatile("s_waitcnt vmcnt(0)" ::: "memory");
        }
        __builtin_amdgcn_s_barrier();
        bsel = (bsel == 2) ? 0 : bsel + 1;
    }
#undef STAGE

    {   // K tail: step 40 (k0=1280, valid k<1284 in lg==0 low half); Wp zero-padded
        int rowc = wrow0 + lr; if (rowc > NN - 1) rowc = NN - 1;
        float4 a0t = make_float4(0.f, 0.f, 0.f, 0.f);
        if (lg == 0) a0t = *(const float4*)(x + (size_t)rowc * FI + 1280);
        bfrag af;
        af[0] = (short)f2bf(a0t.x); af[1] = (short)f2bf(a0t.y);
        af[2] = (short)f2bf(a0t.z); af[3] = (short)f2bf(a0t.w);
        af[4] = 0; af[5] = 0; af[6] = 0; af[7] = 0;
        const ushort* wqs = Wp + (size_t)40 * 4096 + l * 8;
        #pragma unroll
        for (int cg = 0; cg < 8; ++cg) {
            bfrag bf = *(const bfrag*)(wqs + cg * 512);
            acc[cg] = __builtin_amdgcn_mfma_f32_16x16x32_bf16(af, bf, acc[cg], 0, 0, 0);
        }
    }

    // h1 store (bf16)
    #pragma unroll
    for (int cg = 0; cg < 8; ++cg) {
        #pragma unroll
        for (int r = 0; r < 4; ++r) {
            int gr = wrow0 + lg * 4 + r;
            if (gr < NN) h1[(size_t)gr * HD + cg * 16 + lr] = f2bf(acc[cg][r]);
        }
    }

    // fused rowdot epilogue: as1/ad1[row] from fp32 acc.
    // row = wrow0 + lg*4 + r lives across the 16 lanes sharing lg (lr = 0..15),
    // lane holding cols cg*16+lr. Reduce via shfl_xor within the 16-lane group.
    float av[8], dv[8];
    #pragma unroll
    for (int cg = 0; cg < 8; ++cg) {
        av[cg] = asrc[cg * 16 + lr];
        dv[cg] = adst[cg * 16 + lr];
    }
    #pragma unroll
    for (int r = 0; r < 4; ++r) {
        float s = 0.f, d = 0.f;
        #pragma unroll
        for (int cg = 0; cg < 8; ++cg) {
            s += acc[cg][r] * av[cg];
            d += acc[cg][r] * dv[cg];
        }
        #pragma unroll
        for (int off = 1; off < 16; off <<= 1) {
            s += __shfl_xor(s, off);
            d += __shfl_xor(d, off);
        }
        int gr = wrow0 + lg * 4 + r;
        if (lr == 0 && gr < NN) { as1[gr] = s; ad1[gr] = d; }
    }
}

// ---------------- scan (3 small kernels) ----------------

__global__ void k_scan_blk(const int* __restrict__ cnt, int* incl, int* bsum) {
    __shared__ int sh[SCAN_B];
    int i = blockIdx.x * SCAN_B + threadIdx.x;
    sh[threadIdx.x] = (i < NN) ? cnt[i] : 0;
    __syncthreads();
    for (int off = 1; off < SCAN_B; off <<= 1) {
        int t = (threadIdx.x >= off) ? sh[threadIdx.x - off] : 0;
        __syncthreads();
        sh[threadIdx.x] += t;
        __syncthreads();
    }
    if (i < NN) incl[i] = sh[threadIdx.x];
    if (threadIdx.x == SCAN_B - 1) bsum[blockIdx.x] = sh[threadIdx.x];
}

__global__ void k_scan_top(int* bsum) {
    __shared__ int sh[SCAN_B];
    sh[threadIdx.x] = (threadIdx.x < NBLK) ? bsum[threadIdx.x] : 0;
    __syncthreads();
    for (int off = 1; off < SCAN_B; off <<= 1) {
        int t = (threadIdx.x >= off) ? sh[threadIdx.x - off] : 0;
        __syncthreads();
        sh[threadIdx.x] += t;
        __syncthreads();
    }
    if (threadIdx.x < NBLK) bsum[threadIdx.x] = sh[threadIdx.x];
}

__global__ void k_scan_fix(int* incl_start, const int* __restrict__ cnt,
                           const int* __restrict__ bsum, int* cursor) {
    int i = blockIdx.x * SCAN_B + threadIdx.x;
    if (i >= NN) return;
    int off = (blockIdx.x > 0) ? bsum[blockIdx.x - 1] : 0;
    int st = incl_start[i] - cnt[i] + off;
    incl_start[i] = st;
    cursor[i] = st;
}

// ---------------- place: dst-grouped CSR, packed 8B record {src, al_h<<16 | attr_h} ----------------

__global__ void k_place(const int* __restrict__ ei, const float* __restrict__ eattr,
                        const float* __restrict__ sc,
                        const float* __restrict__ as1, const float* __restrict__ ad1,
                        int* cursor, int2* __restrict__ csr) {
    int e = blockIdx.x * blockDim.x + threadIdx.x;
    if (e >= NEP) return;
    int s, d; float av;
    if (e < NE) { s = ei[e]; d = ei[NE + e]; av = eattr[e]; }
    else        { s = d = e - NE; av = sc[0] * (1.0f / NE); }
    float a = as1[s] + ad1[d] + sc[1] * av;
    a = (a > 0.f) ? a : 0.2f * a;
    int pos = atomicAdd(&cursor[d], 1);
    csr[pos] = make_int2(s, ((int)f2h(a) << 16) | (int)f2h(av));
}

// ---------------- layer 1 (fused): streamed-alpha softmax + PV + ELU + W2-dot ----------------

__global__ __launch_bounds__(256) void k_layer1(const int2* __restrict__ csr,
                                                const int* __restrict__ start,
                                                const int* __restrict__ cnt,
                                                const ushort* __restrict__ h1,
                                                const float* __restrict__ b1,
                                                const float* __restrict__ W2,
                                                float* __restrict__ h2) {
    int wid = threadIdx.x >> 6, l = threadIdx.x & 63;
    int d = blockIdx.x * 4 + wid;
    if (d >= NN) return;
    int s0 = start[d], n = cnt[d];

    float m = -INFINITY;
    for (int i = 0; i < n; ++i)
        m = fmaxf(m, h2f((ushort)(csr[s0 + i].y >> 16)));

    float den = 0.f, ax = 0.f, ay = 0.f;
    int i = 0;
    for (; i + 4 <= n; i += 4) {
        int2 e0 = csr[s0 + i],     e1 = csr[s0 + i + 1];
        int2 e2 = csr[s0 + i + 2], e3 = csr[s0 + i + 3];
        float w0 = expf(h2f((ushort)(e0.y >> 16)) - m);
        float w1 = expf(h2f((ushort)(e1.y >> 16)) - m);
        float w2 = expf(h2f((ushort)(e2.y >> 16)) - m);
        float w3 = expf(h2f((ushort)(e3.y >> 16)) - m);
        ushort2 hv0 = *(const ushort2*)&h1[(size_t)e0.x * HD + 2 * l];
        ushort2 hv1 = *(const ushort2*)&h1[(size_t)e1.x * HD + 2 * l];
        ushort2 hv2 = *(const ushort2*)&h1[(size_t)e2.x * HD + 2 * l];
        ushort2 hv3 = *(const ushort2*)&h1[(size_t)e3.x * HD + 2 * l];
        den += w0 + w1 + w2 + w3;
        ax += w0 * bf2f(hv0.x) + w1 * bf2f(hv1.x) + w2 * bf2f(hv2.x) + w3 * bf2f(hv3.x);
        ay += w0 * bf2f(hv0.y) + w1 * bf2f(hv1.y) + w2 * bf2f(hv2.y) + w3 * bf2f(hv3.y);
    }
    for (; i < n; ++i) {
        int2 e0 = csr[s0 + i];
        float w0 = expf(h2f((ushort)(e0.y >> 16)) - m);
        ushort2 hv0 = *(const ushort2*)&h1[(size_t)e0.x * HD + 2 * l];
        den += w0;
        ax += w0 * bf2f(hv0.x);
        ay += w0 * bf2f(hv0.y);
    }
    float inv = 1.f / (den + 1e-16f);
    ax *= inv; ay *= inv;
    float2 bb = *(const float2*)&b1[2 * l];
    float2 w  = *(const float2*)&W2[2 * l];
    float a = ax + bb.x; a = (a > 0.f) ? a : (expf(a) - 1.f);
    float b = ay + bb.y; b = (b > 0.f) ? b : (expf(b) - 1.f);
    float p = a * w.x + b * w.y;
    p = wave_reduce_sum(p);
    if (l == 0) h2[d] = p;
}

// ---------------- layer 2 (fused, scalar) ----------------

__global__ __launch_bounds__(256) void k_layer2(const int2* __restrict__ csr,
                                                const int* __restrict__ start,
                                                const int* __restrict__ cnt,
                                                const float* __restrict__ h2,
                                                const float* __restrict__ as2,
                                                const float* __restrict__ ad2,
                                                const float* __restrict__ sc,
                                                const float* __restrict__ b2,
                                                float* __restrict__ out) {
    int d = blockIdx.x * blockDim.x + threadIdx.x;
    if (d >= NN) return;
    int s0 = start[d], n = cnt[d];
    float A = as2[0], D = ad2[0], c2 = sc[2];
    float hd = D * h2[d];

    float m = -INFINITY;
    for (int i = 0; i < n; ++i) {
        int2 sa = csr[s0 + i];
        float a = A * h2[sa.x] + hd + c2 * h2f((ushort)(sa.y & 0xFFFF));
        a = (a > 0.f) ? a : 0.2f * a;
        m = fmaxf(m, a);
    }
    float den = 0.f, num = 0.f;
    for (int i = 0; i < n; ++i) {
        int2 sa = csr[s0 + i];
        float hs = h2[sa.x];
        float a = A * hs + hd + c2 * h2f((ushort)(sa.y & 0xFFFF));
        a = (a > 0.f) ? a : 0.2f * a;
        float wgt = expf(a - m);
        den += wgt;
        num += wgt * hs;
    }
    float v = num / (den + 1e-16f) + b2[0];
    out[d] = (v >= 0.f) ? v : 0.01f * v;
}

// ---------------- launch ----------------

extern "C" void kernel_launch(void* const* d_in, const int* in_sizes, int n_in,
                              void* d_out, int out_size, void* d_ws, size_t ws_size,
                              hipStream_t stream) {
    const float* x     = (const float*)d_in[0];
    const int*   ei    = (const int*)d_in[1];
    const float* eattr = (const float*)d_in[2];
    const float* W1    = (const float*)d_in[3];
    const float* asrc1 = (const float*)d_in[4];
    const float* adst1 = (const float*)d_in[5];
    const float* We1   = (const float*)d_in[6];
    const float* ae1   = (const float*)d_in[7];
    const float* b1    = (const float*)d_in[8];
    const float* W2    = (const float*)d_in[9];
    const float* as2   = (const float*)d_in[10];
    const float* ad2   = (const float*)d_in[11];
    const float* We2   = (const float*)d_in[12];
    const float* ae2   = (const float*)d_in[13];
    const float* b2    = (const float*)d_in[14];
    float* out = (float*)d_out;

    // workspace layout (~21.4 MB)
    ushort* h1  = (ushort*)d_ws;              // NH ushorts (12.8 MB)
    float* as1  = (float*)(h1 + (size_t)NH);  // NN
    float* ad1  = as1 + NN;
    float* h2   = ad1 + NN;
    float* sc   = h2 + NN;                    // 8 scalars
    int*   cnt    = (int*)(sc + 8);           // NN
    int*   start  = cnt + NN;                 // NN
    int*   cursor = start + NN;               // NN
    int*   bsum   = cursor + NN;              // 256
    int2*  csr    = (int2*)(bsum + 256);      // NEP int2 (6.8 MB)
    ushort* Wp  = (ushort*)(csr + NEP);       // WP_ELEMS bf16 (packed)

    k_pre_a<<<NBLK + 1, 256, 0, stream>>>(cnt, sc, We1, ae1, We2, ae2);
    k_pre_b<<<WT_BLKS + 256 + HIST_BLKS, 256, 0, stream>>>(W1, Wp, eattr, sc, ei, cnt);

    k_gemm1_mfma<<<NROWB, 256, 0, stream>>>(x, Wp, h1, asrc1, adst1, as1, ad1);

    k_scan_blk<<<NBLK, SCAN_B, 0, stream>>>(cnt, start, bsum);
    k_scan_top<<<1, SCAN_B, 0, stream>>>(bsum);
    k_scan_fix<<<NBLK, SCAN_B, 0, stream>>>(start, cnt, bsum, cursor);
    k_place<<<(NEP + 255) / 256, 256, 0, stream>>>(ei, eattr, sc, as1, ad1, cursor, csr);

    k_layer1<<<(NN + 3) / 4, 256, 0, stream>>>(csr, start, cnt, h1, b1, W2, h2);
    k_layer2<<<(NN + 255) / 256, 256, 0, stream>>>(csr, start, cnt, h2, as2, ad2, sc, b2, out);
}

// Round 14
// 248.301 us; speedup vs baseline: 3.1757x; 1.1308x over previous
//
#include <hip/hip_runtime.h>
#include <math.h>

#define NN 50000
#define NE 800000
#define NEP 850000          // NE + NN self loops
#define FI 1284
#define HD 128
#define KP 1312             // FI padded to 41*32 for MFMA K-loop
#define NSTEP 41            // KP/32
#define NH (NN * HD)        // 6,400,000
#define PAD 64              // per-dst CSR bucket (Poisson(17): P(deg>64) ~ 1e-20)
#define NBLK ((NN + 255) / 256)             // 196
#define NROWB ((NN + 63) / 64)              // 782 row-blocks of 64
#define WP_ELEMS (NSTEP * 4096)             // packed B: 41 steps * 8cg * 64lane * 8
#define WT_BLKS ((WP_ELEMS + 255) / 256)    // 657

typedef float f32x4 __attribute__((ext_vector_type(4)));
typedef short bfrag __attribute__((ext_vector_type(8)));   // 8 bf16 in 4 VGPRs

// ---------------- helpers ----------------

__device__ __forceinline__ float wave_reduce_sum(float v) {
    #pragma unroll
    for (int off = 32; off; off >>= 1) v += __shfl_down(v, off);
    return v;
}

__device__ __forceinline__ ushort f2bf(float f) {   // RNE fp32->bf16 bits
    unsigned u = __float_as_uint(f);
    u += 0x7FFFu + ((u >> 16) & 1u);
    return (ushort)(u >> 16);
}

__device__ __forceinline__ float bf2f(ushort u) {
    return __uint_as_float(((unsigned)u) << 16);
}

__device__ __forceinline__ ushort f2h(float f) {    // fp32 -> fp16 bits (RNE)
    _Float16 h = (_Float16)f;
    return *(ushort*)&h;
}

__device__ __forceinline__ float h2f(ushort u) {
    _Float16 h = *(_Float16*)&u;
    return (float)h;
}

__device__ __forceinline__ bfrag cvt_frag(float4 a0, float4 a1) {
    bfrag af;
    af[0] = (short)f2bf(a0.x); af[1] = (short)f2bf(a0.y);
    af[2] = (short)f2bf(a0.z); af[3] = (short)f2bf(a0.w);
    af[4] = (short)f2bf(a1.x); af[5] = (short)f2bf(a1.y);
    af[6] = (short)f2bf(a1.z); af[7] = (short)f2bf(a1.w);
    return af;
}

// ---------------- preamble A: init cursor (=d*PAD) + sc + consts ----------------

__global__ __launch_bounds__(256) void k_pre_a(int* cursor, float* sc,
                                               const float* We1, const float* ae1,
                                               const float* We2, const float* ae2) {
    if (blockIdx.x < NBLK) {
        int i = blockIdx.x * 256 + threadIdx.x;
        if (i < NN) cursor[i] = i * PAD;
        if (i == 0) { sc[0] = 0.f; sc[3] = 0.f; sc[4] = 0.f; sc[5] = 0.f; sc[6] = 0.f; sc[7] = 0.f; }
    } else if (threadIdx.x < 64) {
        int l = threadIdx.x;
        float v = We1[l] * ae1[l] + We1[l + 64] * ae1[l + 64];
        v = wave_reduce_sum(v);
        if (l == 0) { sc[1] = v; sc[2] = We2[0] * ae2[0]; }
    }
}

// ---------------- preamble B: k_wt || sum_attr ----------------

__global__ __launch_bounds__(256) void k_pre_b(const float* __restrict__ W, ushort* __restrict__ Wp,
                                               const float* __restrict__ eattr, float* sc) {
    int b = blockIdx.x;
    if (b < WT_BLKS) {
        int i = b * 256 + threadIdx.x;
        if (i >= WP_ELEMS) return;
        int s = i >> 12;
        int r = i & 4095;
        int cg = r >> 9;
        int q = r & 511;
        int lane = q >> 3, j = q & 7;
        int k = s * 32 + (lane >> 4) * 8 + j;
        int c = cg * 16 + (lane & 15);
        float v = (k < FI) ? W[(size_t)k * HD + c] : 0.f;
        Wp[i] = f2bf(v);
    } else {
        __shared__ float wsum[4];
        int b2 = b - WT_BLKS;
        float v = 0.f;
        for (int i = b2 * 256 + threadIdx.x; i < NE; i += 256 * 256)
            v += eattr[i];
        v = wave_reduce_sum(v);
        int wid = threadIdx.x >> 6, l = threadIdx.x & 63;
        if (l == 0) wsum[wid] = v;
        __syncthreads();
        if (threadIdx.x == 0)
            atomicAdd(&sc[0], wsum[0] + wsum[1] + wsum[2] + wsum[3]);
    }
}

// ---------------- GEMM1: h1 = x @ W1 (bf16 MFMA, 3-buffer depth-2) + fused rowdot epilogue ----------------

__global__ __launch_bounds__(256) void k_gemm1_mfma(const float* __restrict__ x,
                                                    const ushort* __restrict__ Wp,
                                                    ushort* __restrict__ h1,
                                                    const float* __restrict__ asrc,
                                                    const float* __restrict__ adst,
                                                    float* __restrict__ as1,
                                                    float* __restrict__ ad1) {
    __shared__ float  As[3][64][32];    // 24 KB
    __shared__ ushort Bs[3][4096];      // 24 KB
    const int t = threadIdx.x;
    const int wid = t >> 6, l = t & 63;
    const int lr = l & 15, lg = l >> 4;
    const int wrow0 = blockIdx.x * 64 + wid * 16;

    const int srow = l >> 3;
    const int schunk = (l & 7) ^ srow;
    int g0 = wrow0 + srow;      if (g0 > NN - 1) g0 = NN - 1;
    int g1 = wrow0 + 8 + srow;  if (g1 > NN - 1) g1 = NN - 1;
    const float* sp0 = x + (size_t)g0 * FI + schunk * 4;
    const float* sp1 = x + (size_t)g1 * FI + schunk * 4;

    const ushort* bq0 = Wp + (wid * 2    ) * 512 + l * 8;
    const ushort* bq1 = Wp + (wid * 2 + 1) * 512 + l * 8;

    const int rs0 = (lg * 2)     ^ (lr & 7);
    const int rs1 = (lg * 2 + 1) ^ (lr & 7);

    f32x4 acc[8];
    #pragma unroll
    for (int c = 0; c < 8; ++c) acc[c] = (f32x4){0.f, 0.f, 0.f, 0.f};

#define STAGE(B, IT) do { \
    __builtin_amdgcn_global_load_lds( \
        (const __attribute__((address_space(1))) unsigned int*)(sp0 + (size_t)(IT) * 32), \
        (__attribute__((address_space(3))) unsigned int*)&As[B][wid * 16][0], 16, 0, 0); \
    __builtin_amdgcn_global_load_lds( \
        (const __attribute__((address_space(1))) unsigned int*)(sp1 + (size_t)(IT) * 32), \
        (__attribute__((address_space(3))) unsigned int*)&As[B][wid * 16 + 8][0], 16, 0, 0); \
    __builtin_amdgcn_global_load_lds( \
        (const __attribute__((address_space(1))) unsigned int*)(bq0 + (size_t)(IT) * 4096), \
        (__attribute__((address_space(3))) unsigned int*)&Bs[B][(wid * 2) * 512], 16, 0, 0); \
    __builtin_amdgcn_global_load_lds( \
        (const __attribute__((address_space(1))) unsigned int*)(bq1 + (size_t)(IT) * 4096), \
        (__attribute__((address_space(3))) unsigned int*)&Bs[B][(wid * 2 + 1) * 512], 16, 0, 0); \
} while (0)

    STAGE(0, 0);
    STAGE(1, 1);
    STAGE(2, 2);
    asm volatile("s_waitcnt vmcnt(8)" ::: "memory");
    __builtin_amdgcn_s_barrier();

    int bsel = 0;
    for (int it = 0; it < 40; ++it) {
        bfrag bfr[8];
        #pragma unroll
        for (int cg = 0; cg < 8; ++cg)
            bfr[cg] = *(const bfrag*)&Bs[bsel][cg * 512 + l * 8];

        float4 a0 = *(const float4*)&As[bsel][wid * 16 + lr][rs0 * 4];
        float4 a1 = *(const float4*)&As[bsel][wid * 16 + lr][rs1 * 4];
        bfrag af = cvt_frag(a0, a1);
        #pragma unroll
        for (int cg = 0; cg < 8; ++cg)
            acc[cg] = __builtin_amdgcn_mfma_f32_16x16x32_bf16(af, bfr[cg], acc[cg], 0, 0, 0);

        __builtin_amdgcn_s_barrier();
        if (it + 3 < 40) {
            STAGE(bsel, it + 3);
            asm volatile("s_waitcnt vmcnt(8)" ::: "memory");
        } else if (it == 37) {
            asm volatile("s_waitcnt vmcnt(4)" ::: "memory");
        } else if (it == 38) {
            asm volatile("s_waitcnt vmcnt(0)" ::: "memory");
        }
        __builtin_amdgcn_s_barrier();
        bsel = (bsel == 2) ? 0 : bsel + 1;
    }
#undef STAGE

    {   // K tail: step 40 (k0=1280, valid k<1284 in lg==0 low half); Wp zero-padded
        int rowc = wrow0 + lr; if (rowc > NN - 1) rowc = NN - 1;
        float4 a0t = make_float4(0.f, 0.f, 0.f, 0.f);
        if (lg == 0) a0t = *(const float4*)(x + (size_t)rowc * FI + 1280);
        bfrag af;
        af[0] = (short)f2bf(a0t.x); af[1] = (short)f2bf(a0t.y);
        af[2] = (short)f2bf(a0t.z); af[3] = (short)f2bf(a0t.w);
        af[4] = 0; af[5] = 0; af[6] = 0; af[7] = 0;
        const ushort* wqs = Wp + (size_t)40 * 4096 + l * 8;
        #pragma unroll
        for (int cg = 0; cg < 8; ++cg) {
            bfrag bf = *(const bfrag*)(wqs + cg * 512);
            acc[cg] = __builtin_amdgcn_mfma_f32_16x16x32_bf16(af, bf, acc[cg], 0, 0, 0);
        }
    }

    // h1 store (bf16)
    #pragma unroll
    for (int cg = 0; cg < 8; ++cg) {
        #pragma unroll
        for (int r = 0; r < 4; ++r) {
            int gr = wrow0 + lg * 4 + r;
            if (gr < NN) h1[(size_t)gr * HD + cg * 16 + lr] = f2bf(acc[cg][r]);
        }
    }

    // fused rowdot epilogue: as1/ad1[row] from fp32 acc (shfl_xor over 16-lane lr group)
    float av[8], dv[8];
    #pragma unroll
    for (int cg = 0; cg < 8; ++cg) {
        av[cg] = asrc[cg * 16 + lr];
        dv[cg] = adst[cg * 16 + lr];
    }
    #pragma unroll
    for (int r = 0; r < 4; ++r) {
        float s = 0.f, d = 0.f;
        #pragma unroll
        for (int cg = 0; cg < 8; ++cg) {
            s += acc[cg][r] * av[cg];
            d += acc[cg][r] * dv[cg];
        }
        #pragma unroll
        for (int off = 1; off < 16; off <<= 1) {
            s += __shfl_xor(s, off);
            d += __shfl_xor(d, off);
        }
        int gr = wrow0 + lg * 4 + r;
        if (lr == 0 && gr < NN) { as1[gr] = s; ad1[gr] = d; }
    }
}

// ---------------- place: fixed-bucket CSR (d*PAD), packed 8B record {src, al_h<<16 | attr_h} ----------------

__global__ void k_place(const int* __restrict__ ei, const float* __restrict__ eattr,
                        const float* __restrict__ sc,
                        const float* __restrict__ as1, const float* __restrict__ ad1,
                        int* cursor, int2* __restrict__ csr) {
    int e = blockIdx.x * blockDim.x + threadIdx.x;
    if (e >= NEP) return;
    int s, d; float av;
    if (e < NE) { s = ei[e]; d = ei[NE + e]; av = eattr[e]; }
    else        { s = d = e - NE; av = sc[0] * (1.0f / NE); }
    float a = as1[s] + ad1[d] + sc[1] * av;
    a = (a > 0.f) ? a : 0.2f * a;
    int pos = atomicAdd(&cursor[d], 1);
    if (pos - d * PAD < PAD)   // never taken for this input; memory-safety guard
        csr[pos] = make_int2(s, ((int)f2h(a) << 16) | (int)f2h(av));
}

// ---------------- layer 1 (fused): streamed-alpha softmax + PV + ELU + W2-dot ----------------

__global__ __launch_bounds__(256) void k_layer1(const int2* __restrict__ csr,
                                                const int* __restrict__ cursor,
                                                const ushort* __restrict__ h1,
                                                const float* __restrict__ b1,
                                                const float* __restrict__ W2,
                                                float* __restrict__ h2) {
    int wid = threadIdx.x >> 6, l = threadIdx.x & 63;
    int d = blockIdx.x * 4 + wid;
    if (d >= NN) return;
    int s0 = d * PAD;
    int n = cursor[d] - s0; if (n > PAD) n = PAD;

    float m = -INFINITY;
    for (int i = 0; i < n; ++i)
        m = fmaxf(m, h2f((ushort)(csr[s0 + i].y >> 16)));

    float den = 0.f, ax = 0.f, ay = 0.f;
    int i = 0;
    for (; i + 4 <= n; i += 4) {
        int2 e0 = csr[s0 + i],     e1 = csr[s0 + i + 1];
        int2 e2 = csr[s0 + i + 2], e3 = csr[s0 + i + 3];
        float w0 = expf(h2f((ushort)(e0.y >> 16)) - m);
        float w1 = expf(h2f((ushort)(e1.y >> 16)) - m);
        float w2 = expf(h2f((ushort)(e2.y >> 16)) - m);
        float w3 = expf(h2f((ushort)(e3.y >> 16)) - m);
        ushort2 hv0 = *(const ushort2*)&h1[(size_t)e0.x * HD + 2 * l];
        ushort2 hv1 = *(const ushort2*)&h1[(size_t)e1.x * HD + 2 * l];
        ushort2 hv2 = *(const ushort2*)&h1[(size_t)e2.x * HD + 2 * l];
        ushort2 hv3 = *(const ushort2*)&h1[(size_t)e3.x * HD + 2 * l];
        den += w0 + w1 + w2 + w3;
        ax += w0 * bf2f(hv0.x) + w1 * bf2f(hv1.x) + w2 * bf2f(hv2.x) + w3 * bf2f(hv3.x);
        ay += w0 * bf2f(hv0.y) + w1 * bf2f(hv1.y) + w2 * bf2f(hv2.y) + w3 * bf2f(hv3.y);
    }
    for (; i < n; ++i) {
        int2 e0 = csr[s0 + i];
        float w0 = expf(h2f((ushort)(e0.y >> 16)) - m);
        ushort2 hv0 = *(const ushort2*)&h1[(size_t)e0.x * HD + 2 * l];
        den += w0;
        ax += w0 * bf2f(hv0.x);
        ay += w0 * bf2f(hv0.y);
    }
    float inv = 1.f / (den + 1e-16f);
    ax *= inv; ay *= inv;
    float2 bb = *(const float2*)&b1[2 * l];
    float2 w  = *(const float2*)&W2[2 * l];
    float a = ax + bb.x; a = (a > 0.f) ? a : (expf(a) - 1.f);
    float b = ay + bb.y; b = (b > 0.f) ? b : (expf(b) - 1.f);
    float p = a * w.x + b * w.y;
    p = wave_reduce_sum(p);
    if (l == 0) h2[d] = p;
}

// ---------------- layer 2 (fused, scalar) ----------------

__global__ __launch_bounds__(256) void k_layer2(const int2* __restrict__ csr,
                                                const int* __restrict__ cursor,
                                                const float* __restrict__ h2,
                                                const float* __restrict__ as2,
                                                const float* __restrict__ ad2,
                                                const float* __restrict__ sc,
                                                const float* __restrict__ b2,
                                                float* __restrict__ out) {
    int d = blockIdx.x * blockDim.x + threadIdx.x;
    if (d >= NN) return;
    int s0 = d * PAD;
    int n = cursor[d] - s0; if (n > PAD) n = PAD;
    float A = as2[0], D = ad2[0], c2 = sc[2];
    float hd = D * h2[d];

    float m = -INFINITY;
    for (int i = 0; i < n; ++i) {
        int2 sa = csr[s0 + i];
        float a = A * h2[sa.x] + hd + c2 * h2f((ushort)(sa.y & 0xFFFF));
        a = (a > 0.f) ? a : 0.2f * a;
        m = fmaxf(m, a);
    }
    float den = 0.f, num = 0.f;
    for (int i = 0; i < n; ++i) {
        int2 sa = csr[s0 + i];
        float hs = h2[sa.x];
        float a = A * hs + hd + c2 * h2f((ushort)(sa.y & 0xFFFF));
        a = (a > 0.f) ? a : 0.2f * a;
        float wgt = expf(a - m);
        den += wgt;
        num += wgt * hs;
    }
    float v = num / (den + 1e-16f) + b2[0];
    out[d] = (v >= 0.f) ? v : 0.01f * v;
}

// ---------------- launch ----------------

extern "C" void kernel_launch(void* const* d_in, const int* in_sizes, int n_in,
                              void* d_out, int out_size, void* d_ws, size_t ws_size,
                              hipStream_t stream) {
    const float* x     = (const float*)d_in[0];
    const int*   ei    = (const int*)d_in[1];
    const float* eattr = (const float*)d_in[2];
    const float* W1    = (const float*)d_in[3];
    const float* asrc1 = (const float*)d_in[4];
    const float* adst1 = (const float*)d_in[5];
    const float* We1   = (const float*)d_in[6];
    const float* ae1   = (const float*)d_in[7];
    const float* b1    = (const float*)d_in[8];
    const float* W2    = (const float*)d_in[9];
    const float* as2   = (const float*)d_in[10];
    const float* ad2   = (const float*)d_in[11];
    const float* We2   = (const float*)d_in[12];
    const float* ae2   = (const float*)d_in[13];
    const float* b2    = (const float*)d_in[14];
    float* out = (float*)d_out;

    // workspace layout (~40 MB)
    ushort* h1  = (ushort*)d_ws;              // NH ushorts (12.8 MB)
    float* as1  = (float*)(h1 + (size_t)NH);  // NN
    float* ad1  = as1 + NN;
    float* h2   = ad1 + NN;
    float* sc   = h2 + NN;                    // 8 scalars
    int*   cursor = (int*)(sc + 8);           // NN
    int2*  csr    = (int2*)(cursor + NN);     // NN*PAD int2 (25.6 MB)
    ushort* Wp  = (ushort*)(csr + (size_t)NN * PAD);  // WP_ELEMS bf16 (packed)

    k_pre_a<<<NBLK + 1, 256, 0, stream>>>(cursor, sc, We1, ae1, We2, ae2);
    k_pre_b<<<WT_BLKS + 256, 256, 0, stream>>>(W1, Wp, eattr, sc);

    k_gemm1_mfma<<<NROWB, 256, 0, stream>>>(x, Wp, h1, asrc1, adst1, as1, ad1);

    k_place<<<(NEP + 255) / 256, 256, 0, stream>>>(ei, eattr, sc, as1, ad1, cursor, csr);

    k_layer1<<<(NN + 3) / 4, 256, 0, stream>>>(csr, cursor, h1, b1, W2, h2);
    k_layer2<<<(NN + 255) / 256, 256, 0, stream>>>(csr, cursor, h2, as2, ad2, sc, b2, out);
}

// Round 15
// 223.471 us; speedup vs baseline: 3.5286x; 1.1111x over previous
//
#include <hip/hip_runtime.h>
#include <math.h>

#define NN 50000
#define NE 800000
#define NEP 850000          // NE + NN self loops
#define FI 1284
#define HD 128
#define KP 1312             // FI padded to 41*32 for MFMA K-loop
#define NSTEP 41            // KP/32
#define NH (NN * HD)        // 6,400,000
#define PAD 64              // per-dst CSR bucket (Poisson(17): P(deg>64) ~ 1e-20)
#define NBLK ((NN + 255) / 256)             // 196
#define NROWB ((NN + 127) / 128)            // 391 row-blocks of 128
#define WP_ELEMS (NSTEP * 4096)             // packed B: 41 steps * 8cg * 64lane * 8
#define WT_BLKS ((WP_ELEMS + 255) / 256)    // 657

typedef float f32x4 __attribute__((ext_vector_type(4)));
typedef short bfrag __attribute__((ext_vector_type(8)));   // 8 bf16 in 4 VGPRs

// ---------------- helpers ----------------

__device__ __forceinline__ float wave_reduce_sum(float v) {
    #pragma unroll
    for (int off = 32; off; off >>= 1) v += __shfl_down(v, off);
    return v;
}

__device__ __forceinline__ ushort f2bf(float f) {   // RNE fp32->bf16 bits
    unsigned u = __float_as_uint(f);
    u += 0x7FFFu + ((u >> 16) & 1u);
    return (ushort)(u >> 16);
}

__device__ __forceinline__ float bf2f(ushort u) {
    return __uint_as_float(((unsigned)u) << 16);
}

__device__ __forceinline__ ushort f2h(float f) {    // fp32 -> fp16 bits (RNE)
    _Float16 h = (_Float16)f;
    return *(ushort*)&h;
}

__device__ __forceinline__ float h2f(ushort u) {
    _Float16 h = *(_Float16*)&u;
    return (float)h;
}

// packed RNE convert: 4x v_cvt_pk_bf16_f32 (dst.lo=src0, dst.hi=src1)
__device__ __forceinline__ bfrag cvt_frag(float4 a0, float4 a1) {
    union { int i[4]; bfrag f; } u;
    asm("v_cvt_pk_bf16_f32 %0, %1, %2" : "=v"(u.i[0]) : "v"(a0.x), "v"(a0.y));
    asm("v_cvt_pk_bf16_f32 %0, %1, %2" : "=v"(u.i[1]) : "v"(a0.z), "v"(a0.w));
    asm("v_cvt_pk_bf16_f32 %0, %1, %2" : "=v"(u.i[2]) : "v"(a1.x), "v"(a1.y));
    asm("v_cvt_pk_bf16_f32 %0, %1, %2" : "=v"(u.i[3]) : "v"(a1.z), "v"(a1.w));
    return u.f;
}

// ---------------- preamble A: init cursor (=d*PAD) + sc + consts ----------------

__global__ __launch_bounds__(256) void k_pre_a(int* cursor, float* sc,
                                               const float* We1, const float* ae1,
                                               const float* We2, const float* ae2) {
    if (blockIdx.x < NBLK) {
        int i = blockIdx.x * 256 + threadIdx.x;
        if (i < NN) cursor[i] = i * PAD;
        if (i == 0) { sc[0] = 0.f; sc[3] = 0.f; sc[4] = 0.f; sc[5] = 0.f; sc[6] = 0.f; sc[7] = 0.f; }
    } else if (threadIdx.x < 64) {
        int l = threadIdx.x;
        float v = We1[l] * ae1[l] + We1[l + 64] * ae1[l + 64];
        v = wave_reduce_sum(v);
        if (l == 0) { sc[1] = v; sc[2] = We2[0] * ae2[0]; }
    }
}

// ---------------- preamble B: k_wt || sum_attr ----------------

__global__ __launch_bounds__(256) void k_pre_b(const float* __restrict__ W, ushort* __restrict__ Wp,
                                               const float* __restrict__ eattr, float* sc) {
    int b = blockIdx.x;
    if (b < WT_BLKS) {
        int i = b * 256 + threadIdx.x;
        if (i >= WP_ELEMS) return;
        int s = i >> 12;
        int r = i & 4095;
        int cg = r >> 9;
        int q = r & 511;
        int lane = q >> 3, j = q & 7;
        int k = s * 32 + (lane >> 4) * 8 + j;
        int c = cg * 16 + (lane & 15);
        float v = (k < FI) ? W[(size_t)k * HD + c] : 0.f;
        Wp[i] = f2bf(v);
    } else {
        __shared__ float wsum[4];
        int b2 = b - WT_BLKS;
        float v = 0.f;
        for (int i = b2 * 256 + threadIdx.x; i < NE; i += 256 * 256)
            v += eattr[i];
        v = wave_reduce_sum(v);
        int wid = threadIdx.x >> 6, l = threadIdx.x & 63;
        if (l == 0) wsum[wid] = v;
        __syncthreads();
        if (threadIdx.x == 0)
            atomicAdd(&sc[0], wsum[0] + wsum[1] + wsum[2] + wsum[3]);
    }
}

// ---------------- GEMM1: h1 = x @ W1 (bf16 MFMA, BM=128, 8 waves, 3-buffer depth-2) ----------------
// 512 threads; wave w owns rows [blk*128 + w*16, +16) x 128 cols. LDS 72KB -> 2 blocks/CU
// (16 waves/CU = 4/SIMD). Staging per wave per step: 2 A insts + 1 B inst = 3.
// vmcnt: steady 6 (2 stages x 3), tail 3 -> 0. Fused rowdot epilogue.

__global__ __launch_bounds__(512) void k_gemm1_mfma(const float* __restrict__ x,
                                                    const ushort* __restrict__ Wp,
                                                    ushort* __restrict__ h1,
                                                    const float* __restrict__ asrc,
                                                    const float* __restrict__ adst,
                                                    float* __restrict__ as1,
                                                    float* __restrict__ ad1) {
    __shared__ float  As[3][128][32];   // 48 KB
    __shared__ ushort Bs[3][4096];      // 24 KB
    const int t = threadIdx.x;
    const int wid = t >> 6, l = t & 63;
    const int lr = l & 15, lg = l >> 4;
    const int wrow0 = blockIdx.x * 128 + wid * 16;

    // A staging: inst i of wave covers rows wid*16 + i*8 .. +8; lane l -> row +l/8, slot l%8
    // slot p of row r holds global chunk p^(r&7); r&7 == l/8.
    const int srow = l >> 3;
    const int schunk = (l & 7) ^ srow;
    int g0 = wrow0 + srow;      if (g0 > NN - 1) g0 = NN - 1;
    int g1 = wrow0 + 8 + srow;  if (g1 > NN - 1) g1 = NN - 1;
    const float* sp0 = x + (size_t)g0 * FI + schunk * 4;
    const float* sp1 = x + (size_t)g1 * FI + schunk * 4;

    // B staging: wave wid stages chunk wid (512 ushorts = 1KB), linear
    const ushort* bq0 = Wp + wid * 512 + l * 8;

    // swizzled A read slots (chunk c of row lr lives at slot c^(lr&7))
    const int rs0 = (lg * 2)     ^ (lr & 7);
    const int rs1 = (lg * 2 + 1) ^ (lr & 7);

    f32x4 acc[8];
    #pragma unroll
    for (int c = 0; c < 8; ++c) acc[c] = (f32x4){0.f, 0.f, 0.f, 0.f};

#define STAGE(B, IT) do { \
    __builtin_amdgcn_global_load_lds( \
        (const __attribute__((address_space(1))) unsigned int*)(sp0 + (size_t)(IT) * 32), \
        (__attribute__((address_space(3))) unsigned int*)&As[B][wid * 16][0], 16, 0, 0); \
    __builtin_amdgcn_global_load_lds( \
        (const __attribute__((address_space(1))) unsigned int*)(sp1 + (size_t)(IT) * 32), \
        (__attribute__((address_space(3))) unsigned int*)&As[B][wid * 16 + 8][0], 16, 0, 0); \
    __builtin_amdgcn_global_load_lds( \
        (const __attribute__((address_space(1))) unsigned int*)(bq0 + (size_t)(IT) * 4096), \
        (__attribute__((address_space(3))) unsigned int*)&Bs[B][wid * 512], 16, 0, 0); \
} while (0)

    STAGE(0, 0);
    STAGE(1, 1);
    STAGE(2, 2);
    asm volatile("s_waitcnt vmcnt(6)" ::: "memory");    // stage 0's 3 insts landed
    __builtin_amdgcn_s_barrier();

    int bsel = 0;
    for (int it = 0; it < 40; ++it) {
        bfrag bfr[8];
        #pragma unroll
        for (int cg = 0; cg < 8; ++cg)
            bfr[cg] = *(const bfrag*)&Bs[bsel][cg * 512 + l * 8];

        float4 a0 = *(const float4*)&As[bsel][wid * 16 + lr][rs0 * 4];
        float4 a1 = *(const float4*)&As[bsel][wid * 16 + lr][rs1 * 4];
        bfrag af = cvt_frag(a0, a1);
        #pragma unroll
        for (int cg = 0; cg < 8; ++cg)
            acc[cg] = __builtin_amdgcn_mfma_f32_16x16x32_bf16(af, bfr[cg], acc[cg], 0, 0, 0);

        __builtin_amdgcn_s_barrier();                   // all waves done READING buf[bsel]
        if (it + 3 < 40) {
            STAGE(bsel, it + 3);
            asm volatile("s_waitcnt vmcnt(6)" ::: "memory");  // stage(it+1) landed
        } else if (it == 37) {
            asm volatile("s_waitcnt vmcnt(3)" ::: "memory");  // stage(38) landed
        } else if (it == 38) {
            asm volatile("s_waitcnt vmcnt(0)" ::: "memory");  // stage(39) landed
        }
        __builtin_amdgcn_s_barrier();                   // staged writes visible to all waves
        bsel = (bsel == 2) ? 0 : bsel + 1;
    }
#undef STAGE

    {   // K tail: step 40 (k0=1280, valid k<1284 in lg==0 low half); Wp zero-padded
        int rowc = wrow0 + lr; if (rowc > NN - 1) rowc = NN - 1;
        float4 a0t = make_float4(0.f, 0.f, 0.f, 0.f);
        if (lg == 0) a0t = *(const float4*)(x + (size_t)rowc * FI + 1280);
        bfrag af;
        af[0] = (short)f2bf(a0t.x); af[1] = (short)f2bf(a0t.y);
        af[2] = (short)f2bf(a0t.z); af[3] = (short)f2bf(a0t.w);
        af[4] = 0; af[5] = 0; af[6] = 0; af[7] = 0;
        const ushort* wqs = Wp + (size_t)40 * 4096 + l * 8;
        #pragma unroll
        for (int cg = 0; cg < 8; ++cg) {
            bfrag bf = *(const bfrag*)(wqs + cg * 512);
            acc[cg] = __builtin_amdgcn_mfma_f32_16x16x32_bf16(af, bf, acc[cg], 0, 0, 0);
        }
    }

    // h1 store (bf16)
    #pragma unroll
    for (int cg = 0; cg < 8; ++cg) {
        #pragma unroll
        for (int r = 0; r < 4; ++r) {
            int gr = wrow0 + lg * 4 + r;
            if (gr < NN) h1[(size_t)gr * HD + cg * 16 + lr] = f2bf(acc[cg][r]);
        }
    }

    // fused rowdot epilogue: as1/ad1[row] from fp32 acc (shfl_xor over 16-lane lr group)
    float av[8], dv[8];
    #pragma unroll
    for (int cg = 0; cg < 8; ++cg) {
        av[cg] = asrc[cg * 16 + lr];
        dv[cg] = adst[cg * 16 + lr];
    }
    #pragma unroll
    for (int r = 0; r < 4; ++r) {
        float s = 0.f, d = 0.f;
        #pragma unroll
        for (int cg = 0; cg < 8; ++cg) {
            s += acc[cg][r] * av[cg];
            d += acc[cg][r] * dv[cg];
        }
        #pragma unroll
        for (int off = 1; off < 16; off <<= 1) {
            s += __shfl_xor(s, off);
            d += __shfl_xor(d, off);
        }
        int gr = wrow0 + lg * 4 + r;
        if (lr == 0 && gr < NN) { as1[gr] = s; ad1[gr] = d; }
    }
}

// ---------------- place: fixed-bucket CSR (d*PAD), packed 8B record {src, al_h<<16 | attr_h} ----------------

__global__ void k_place(const int* __restrict__ ei, const float* __restrict__ eattr,
                        const float* __restrict__ sc,
                        const float* __restrict__ as1, const float* __restrict__ ad1,
                        int* cursor, int2* __restrict__ csr) {
    int e = blockIdx.x * blockDim.x + threadIdx.x;
    if (e >= NEP) return;
    int s, d; float av;
    if (e < NE) { s = ei[e]; d = ei[NE + e]; av = eattr[e]; }
    else        { s = d = e - NE; av = sc[0] * (1.0f / NE); }
    float a = as1[s] + ad1[d] + sc[1] * av;
    a = (a > 0.f) ? a : 0.2f * a;
    int pos = atomicAdd(&cursor[d], 1);
    if (pos - d * PAD < PAD)   // never taken for this input; memory-safety guard
        csr[pos] = make_int2(s, ((int)f2h(a) << 16) | (int)f2h(av));
}

// ---------------- layer 1 (fused): streamed-alpha softmax + PV + ELU + W2-dot ----------------

__global__ __launch_bounds__(256) void k_layer1(const int2* __restrict__ csr,
                                                const int* __restrict__ cursor,
                                                const ushort* __restrict__ h1,
                                                const float* __restrict__ b1,
                                                const float* __restrict__ W2,
                                                float* __restrict__ h2) {
    int wid = threadIdx.x >> 6, l = threadIdx.x & 63;
    int d = blockIdx.x * 4 + wid;
    if (d >= NN) return;
    int s0 = d * PAD;
    int n = cursor[d] - s0; if (n > PAD) n = PAD;

    float m = -INFINITY;
    for (int i = 0; i < n; ++i)
        m = fmaxf(m, h2f((ushort)(csr[s0 + i].y >> 16)));

    float den = 0.f, ax = 0.f, ay = 0.f;
    int i = 0;
    for (; i + 4 <= n; i += 4) {
        int2 e0 = csr[s0 + i],     e1 = csr[s0 + i + 1];
        int2 e2 = csr[s0 + i + 2], e3 = csr[s0 + i + 3];
        float w0 = expf(h2f((ushort)(e0.y >> 16)) - m);
        float w1 = expf(h2f((ushort)(e1.y >> 16)) - m);
        float w2 = expf(h2f((ushort)(e2.y >> 16)) - m);
        float w3 = expf(h2f((ushort)(e3.y >> 16)) - m);
        ushort2 hv0 = *(const ushort2*)&h1[(size_t)e0.x * HD + 2 * l];
        ushort2 hv1 = *(const ushort2*)&h1[(size_t)e1.x * HD + 2 * l];
        ushort2 hv2 = *(const ushort2*)&h1[(size_t)e2.x * HD + 2 * l];
        ushort2 hv3 = *(const ushort2*)&h1[(size_t)e3.x * HD + 2 * l];
        den += w0 + w1 + w2 + w3;
        ax += w0 * bf2f(hv0.x) + w1 * bf2f(hv1.x) + w2 * bf2f(hv2.x) + w3 * bf2f(hv3.x);
        ay += w0 * bf2f(hv0.y) + w1 * bf2f(hv1.y) + w2 * bf2f(hv2.y) + w3 * bf2f(hv3.y);
    }
    for (; i < n; ++i) {
        int2 e0 = csr[s0 + i];
        float w0 = expf(h2f((ushort)(e0.y >> 16)) - m);
        ushort2 hv0 = *(const ushort2*)&h1[(size_t)e0.x * HD + 2 * l];
        den += w0;
        ax += w0 * bf2f(hv0.x);
        ay += w0 * bf2f(hv0.y);
    }
    float inv = 1.f / (den + 1e-16f);
    ax *= inv; ay *= inv;
    float2 bb = *(const float2*)&b1[2 * l];
    float2 w  = *(const float2*)&W2[2 * l];
    float a = ax + bb.x; a = (a > 0.f) ? a : (expf(a) - 1.f);
    float b = ay + bb.y; b = (b > 0.f) ? b : (expf(b) - 1.f);
    float p = a * w.x + b * w.y;
    p = wave_reduce_sum(p);
    if (l == 0) h2[d] = p;
}

// ---------------- layer 2 (fused, scalar) ----------------

__global__ __launch_bounds__(256) void k_layer2(const int2* __restrict__ csr,
                                                const int* __restrict__ cursor,
                                                const float* __restrict__ h2,
                                                const float* __restrict__ as2,
                                                const float* __restrict__ ad2,
                                                const float* __restrict__ sc,
                                                const float* __restrict__ b2,
                                                float* __restrict__ out) {
    int d = blockIdx.x * blockDim.x + threadIdx.x;
    if (d >= NN) return;
    int s0 = d * PAD;
    int n = cursor[d] - s0; if (n > PAD) n = PAD;
    float A = as2[0], D = ad2[0], c2 = sc[2];
    float hd = D * h2[d];

    float m = -INFINITY;
    for (int i = 0; i < n; ++i) {
        int2 sa = csr[s0 + i];
        float a = A * h2[sa.x] + hd + c2 * h2f((ushort)(sa.y & 0xFFFF));
        a = (a > 0.f) ? a : 0.2f * a;
        m = fmaxf(m, a);
    }
    float den = 0.f, num = 0.f;
    for (int i = 0; i < n; ++i) {
        int2 sa = csr[s0 + i];
        float hs = h2[sa.x];
        float a = A * hs + hd + c2 * h2f((ushort)(sa.y & 0xFFFF));
        a = (a > 0.f) ? a : 0.2f * a;
        float wgt = expf(a - m);
        den += wgt;
        num += wgt * hs;
    }
    float v = num / (den + 1e-16f) + b2[0];
    out[d] = (v >= 0.f) ? v : 0.01f * v;
}

// ---------------- launch ----------------

extern "C" void kernel_launch(void* const* d_in, const int* in_sizes, int n_in,
                              void* d_out, int out_size, void* d_ws, size_t ws_size,
                              hipStream_t stream) {
    const float* x     = (const float*)d_in[0];
    const int*   ei    = (const int*)d_in[1];
    const float* eattr = (const float*)d_in[2];
    const float* W1    = (const float*)d_in[3];
    const float* asrc1 = (const float*)d_in[4];
    const float* adst1 = (const float*)d_in[5];
    const float* We1   = (const float*)d_in[6];
    const float* ae1   = (const float*)d_in[7];
    const float* b1    = (const float*)d_in[8];
    const float* W2    = (const float*)d_in[9];
    const float* as2   = (const float*)d_in[10];
    const float* ad2   = (const float*)d_in[11];
    const float* We2   = (const float*)d_in[12];
    const float* ae2   = (const float*)d_in[13];
    const float* b2    = (const float*)d_in[14];
    float* out = (float*)d_out;

    // workspace layout (~40 MB)
    ushort* h1  = (ushort*)d_ws;              // NH ushorts (12.8 MB)
    float* as1  = (float*)(h1 + (size_t)NH);  // NN
    float* ad1  = as1 + NN;
    float* h2   = ad1 + NN;
    float* sc   = h2 + NN;                    // 8 scalars
    int*   cursor = (int*)(sc + 8);           // NN
    int2*  csr    = (int2*)(cursor + NN);     // NN*PAD int2 (25.6 MB)
    ushort* Wp  = (ushort*)(csr + (size_t)NN * PAD);  // WP_ELEMS bf16 (packed)

    k_pre_a<<<NBLK + 1, 256, 0, stream>>>(cursor, sc, We1, ae1, We2, ae2);
    k_pre_b<<<WT_BLKS + 256, 256, 0, stream>>>(W1, Wp, eattr, sc);

    k_gemm1_mfma<<<NROWB, 512, 0, stream>>>(x, Wp, h1, asrc1, adst1, as1, ad1);

    k_place<<<(NEP + 255) / 256, 256, 0, stream>>>(ei, eattr, sc, as1, ad1, cursor, csr);

    k_layer1<<<(NN + 3) / 4, 256, 0, stream>>>(csr, cursor, h1, b1, W2, h2);
    k_layer2<<<(NN + 255) / 256, 256, 0, stream>>>(csr, cursor, h2, as2, ad2, sc, b2, out);
}

// Round 16
// 182.475 us; speedup vs baseline: 4.3213x; 1.2247x over previous
//
#include <hip/hip_runtime.h>
#include <math.h>

#define NN 50000
#define NE 800000
#define NEP 850000          // NE + NN self loops
#define FI 1284
#define HD 128
#define KP 1312             // FI padded to 41*32 for MFMA K-loop
#define NSTEP 41            // KP/32
#define NH (NN * HD)        // 6,400,000
#define PAD 64              // per-dst CSR bucket (Poisson(17): P(deg>64) ~ 1e-20)
#define NBLK ((NN + 255) / 256)             // 196
#define NROWB ((NN + 127) / 128)            // 391 row-blocks of 128
#define WP_ELEMS (NSTEP * 4096)             // packed B: 41 steps * 8cg * 64lane * 8
#define WT_BLKS ((WP_ELEMS + 255) / 256)    // 657

typedef float f32x4 __attribute__((ext_vector_type(4)));
typedef short bfrag __attribute__((ext_vector_type(8)));   // 8 bf16 in 4 VGPRs

// ---------------- helpers ----------------

__device__ __forceinline__ float wave_reduce_sum(float v) {
    #pragma unroll
    for (int off = 32; off; off >>= 1) v += __shfl_down(v, off);
    return v;
}

__device__ __forceinline__ ushort f2bf(float f) {   // RNE fp32->bf16 bits
    unsigned u = __float_as_uint(f);
    u += 0x7FFFu + ((u >> 16) & 1u);
    return (ushort)(u >> 16);
}

__device__ __forceinline__ float bf2f(ushort u) {
    return __uint_as_float(((unsigned)u) << 16);
}

__device__ __forceinline__ ushort f2h(float f) {    // fp32 -> fp16 bits (RNE)
    _Float16 h = (_Float16)f;
    return *(ushort*)&h;
}

__device__ __forceinline__ float h2f(ushort u) {
    _Float16 h = *(_Float16*)&u;
    return (float)h;
}

// packed RNE convert: 4x v_cvt_pk_bf16_f32 (dst.lo=src0, dst.hi=src1)
__device__ __forceinline__ bfrag cvt_frag(float4 a0, float4 a1) {
    union { int i[4]; bfrag f; } u;
    asm("v_cvt_pk_bf16_f32 %0, %1, %2" : "=v"(u.i[0]) : "v"(a0.x), "v"(a0.y));
    asm("v_cvt_pk_bf16_f32 %0, %1, %2" : "=v"(u.i[1]) : "v"(a0.z), "v"(a0.w));
    asm("v_cvt_pk_bf16_f32 %0, %1, %2" : "=v"(u.i[2]) : "v"(a1.x), "v"(a1.y));
    asm("v_cvt_pk_bf16_f32 %0, %1, %2" : "=v"(u.i[3]) : "v"(a1.z), "v"(a1.w));
    return u.f;
}

// ---------------- fused preamble: cursor init | consts | Wp pack | sum_attr partials ----------------
// no cross-block ordering needed: sum_attr writes per-block partials (bsum), finalized in gemm blk 0.

__global__ __launch_bounds__(256) void k_pre(int* cursor, float* sc,
                                             const float* We1, const float* ae1,
                                             const float* We2, const float* ae2,
                                             const float* __restrict__ W, ushort* __restrict__ Wp,
                                             const float* __restrict__ eattr, float* bsum) {
    int b = blockIdx.x;
    if (b < NBLK) {
        int i = b * 256 + threadIdx.x;
        if (i < NN) cursor[i] = i * PAD;
    } else if (b == NBLK) {
        if (threadIdx.x < 64) {
            int l = threadIdx.x;
            float v = We1[l] * ae1[l] + We1[l + 64] * ae1[l + 64];
            v = wave_reduce_sum(v);
            if (l == 0) { sc[1] = v; sc[2] = We2[0] * ae2[0]; }
        }
    } else if (b < NBLK + 1 + WT_BLKS) {
        int i = (b - NBLK - 1) * 256 + threadIdx.x;
        if (i >= WP_ELEMS) return;
        int s = i >> 12;
        int r = i & 4095;
        int cg = r >> 9;
        int q = r & 511;
        int lane = q >> 3, j = q & 7;
        int k = s * 32 + (lane >> 4) * 8 + j;
        int c = cg * 16 + (lane & 15);
        float v = (k < FI) ? W[(size_t)k * HD + c] : 0.f;
        Wp[i] = f2bf(v);
    } else {
        __shared__ float wsum[4];
        int b2 = b - NBLK - 1 - WT_BLKS;   // 0..255
        float v = 0.f;
        for (int i = b2 * 256 + threadIdx.x; i < NE; i += 256 * 256)
            v += eattr[i];
        v = wave_reduce_sum(v);
        int wid = threadIdx.x >> 6, l = threadIdx.x & 63;
        if (l == 0) wsum[wid] = v;
        __syncthreads();
        if (threadIdx.x == 0)
            bsum[b2] = wsum[0] + wsum[1] + wsum[2] + wsum[3];
    }
}

// ---------------- GEMM1: h1 = x @ W1 (bf16 MFMA, BM=128, 8 waves, 3-buffer depth-2) ----------------
// block 0 wave 0 also finalizes sc[0] = sum(bsum) (needed only by k_place, next kernel).

__global__ __launch_bounds__(512) void k_gemm1_mfma(const float* __restrict__ x,
                                                    const ushort* __restrict__ Wp,
                                                    ushort* __restrict__ h1,
                                                    const float* __restrict__ asrc,
                                                    const float* __restrict__ adst,
                                                    float* __restrict__ as1,
                                                    float* __restrict__ ad1,
                                                    const float* __restrict__ bsum,
                                                    float* sc) {
    __shared__ float  As[3][128][32];   // 48 KB
    __shared__ ushort Bs[3][4096];      // 24 KB
    const int t = threadIdx.x;
    const int wid = t >> 6, l = t & 63;
    const int lr = l & 15, lg = l >> 4;
    const int wrow0 = blockIdx.x * 128 + wid * 16;

    if (blockIdx.x == 0 && wid == 0) {   // finalize sum_attr (fixed order, deterministic)
        float v = bsum[l] + bsum[l + 64] + bsum[l + 128] + bsum[l + 192];
        v = wave_reduce_sum(v);
        if (l == 0) sc[0] = v;
    }

    const int srow = l >> 3;
    const int schunk = (l & 7) ^ srow;
    int g0 = wrow0 + srow;      if (g0 > NN - 1) g0 = NN - 1;
    int g1 = wrow0 + 8 + srow;  if (g1 > NN - 1) g1 = NN - 1;
    const float* sp0 = x + (size_t)g0 * FI + schunk * 4;
    const float* sp1 = x + (size_t)g1 * FI + schunk * 4;

    const ushort* bq0 = Wp + wid * 512 + l * 8;

    const int rs0 = (lg * 2)     ^ (lr & 7);
    const int rs1 = (lg * 2 + 1) ^ (lr & 7);

    f32x4 acc[8];
    #pragma unroll
    for (int c = 0; c < 8; ++c) acc[c] = (f32x4){0.f, 0.f, 0.f, 0.f};

#define STAGE(B, IT) do { \
    __builtin_amdgcn_global_load_lds( \
        (const __attribute__((address_space(1))) unsigned int*)(sp0 + (size_t)(IT) * 32), \
        (__attribute__((address_space(3))) unsigned int*)&As[B][wid * 16][0], 16, 0, 0); \
    __builtin_amdgcn_global_load_lds( \
        (const __attribute__((address_space(1))) unsigned int*)(sp1 + (size_t)(IT) * 32), \
        (__attribute__((address_space(3))) unsigned int*)&As[B][wid * 16 + 8][0], 16, 0, 0); \
    __builtin_amdgcn_global_load_lds( \
        (const __attribute__((address_space(1))) unsigned int*)(bq0 + (size_t)(IT) * 4096), \
        (__attribute__((address_space(3))) unsigned int*)&Bs[B][wid * 512], 16, 0, 0); \
} while (0)

    STAGE(0, 0);
    STAGE(1, 1);
    STAGE(2, 2);
    asm volatile("s_waitcnt vmcnt(6)" ::: "memory");    // stage 0's 3 insts landed
    __builtin_amdgcn_s_barrier();

    int bsel = 0;
    for (int it = 0; it < 40; ++it) {
        bfrag bfr[8];
        #pragma unroll
        for (int cg = 0; cg < 8; ++cg)
            bfr[cg] = *(const bfrag*)&Bs[bsel][cg * 512 + l * 8];

        float4 a0 = *(const float4*)&As[bsel][wid * 16 + lr][rs0 * 4];
        float4 a1 = *(const float4*)&As[bsel][wid * 16 + lr][rs1 * 4];
        bfrag af = cvt_frag(a0, a1);
        #pragma unroll
        for (int cg = 0; cg < 8; ++cg)
            acc[cg] = __builtin_amdgcn_mfma_f32_16x16x32_bf16(af, bfr[cg], acc[cg], 0, 0, 0);

        __builtin_amdgcn_s_barrier();                   // all waves done READING buf[bsel]
        if (it + 3 < 40) {
            STAGE(bsel, it + 3);
            asm volatile("s_waitcnt vmcnt(6)" ::: "memory");  // stage(it+1) landed
        } else if (it == 37) {
            asm volatile("s_waitcnt vmcnt(3)" ::: "memory");  // stage(38) landed
        } else if (it == 38) {
            asm volatile("s_waitcnt vmcnt(0)" ::: "memory");  // stage(39) landed
        }
        __builtin_amdgcn_s_barrier();                   // staged writes visible to all waves
        bsel = (bsel == 2) ? 0 : bsel + 1;
    }
#undef STAGE

    {   // K tail: step 40 (k0=1280, valid k<1284 in lg==0 low half); Wp zero-padded
        int rowc = wrow0 + lr; if (rowc > NN - 1) rowc = NN - 1;
        float4 a0t = make_float4(0.f, 0.f, 0.f, 0.f);
        if (lg == 0) a0t = *(const float4*)(x + (size_t)rowc * FI + 1280);
        bfrag af;
        af[0] = (short)f2bf(a0t.x); af[1] = (short)f2bf(a0t.y);
        af[2] = (short)f2bf(a0t.z); af[3] = (short)f2bf(a0t.w);
        af[4] = 0; af[5] = 0; af[6] = 0; af[7] = 0;
        const ushort* wqs = Wp + (size_t)40 * 4096 + l * 8;
        #pragma unroll
        for (int cg = 0; cg < 8; ++cg) {
            bfrag bf = *(const bfrag*)(wqs + cg * 512);
            acc[cg] = __builtin_amdgcn_mfma_f32_16x16x32_bf16(af, bf, acc[cg], 0, 0, 0);
        }
    }

    // h1 store (bf16)
    #pragma unroll
    for (int cg = 0; cg < 8; ++cg) {
        #pragma unroll
        for (int r = 0; r < 4; ++r) {
            int gr = wrow0 + lg * 4 + r;
            if (gr < NN) h1[(size_t)gr * HD + cg * 16 + lr] = f2bf(acc[cg][r]);
        }
    }

    // fused rowdot epilogue: as1/ad1[row] from fp32 acc (shfl_xor over 16-lane lr group)
    float av[8], dv[8];
    #pragma unroll
    for (int cg = 0; cg < 8; ++cg) {
        av[cg] = asrc[cg * 16 + lr];
        dv[cg] = adst[cg * 16 + lr];
    }
    #pragma unroll
    for (int r = 0; r < 4; ++r) {
        float s = 0.f, d = 0.f;
        #pragma unroll
        for (int cg = 0; cg < 8; ++cg) {
            s += acc[cg][r] * av[cg];
            d += acc[cg][r] * dv[cg];
        }
        #pragma unroll
        for (int off = 1; off < 16; off <<= 1) {
            s += __shfl_xor(s, off);
            d += __shfl_xor(d, off);
        }
        int gr = wrow0 + lg * 4 + r;
        if (lr == 0 && gr < NN) { as1[gr] = s; ad1[gr] = d; }
    }
}

// ---------------- place: fixed-bucket CSR (d*PAD), packed 8B record {src, al_h<<16 | attr_h} ----------------

__global__ void k_place(const int* __restrict__ ei, const float* __restrict__ eattr,
                        const float* __restrict__ sc,
                        const float* __restrict__ as1, const float* __restrict__ ad1,
                        int* cursor, int2* __restrict__ csr) {
    int e = blockIdx.x * blockDim.x + threadIdx.x;
    if (e >= NEP) return;
    int s, d; float av;
    if (e < NE) { s = ei[e]; d = ei[NE + e]; av = eattr[e]; }
    else        { s = d = e - NE; av = sc[0] * (1.0f / NE); }
    float a = as1[s] + ad1[d] + sc[1] * av;
    a = (a > 0.f) ? a : 0.2f * a;
    int pos = atomicAdd(&cursor[d], 1);
    if (pos - d * PAD < PAD)   // never taken for this input; memory-safety guard
        csr[pos] = make_int2(s, ((int)f2h(a) << 16) | (int)f2h(av));
}

// ---------------- layer 1 (fused): single-pass ONLINE softmax + PV + ELU + W2-dot ----------------
// one wave per dst; 4-edge tiles: one wave-uniform rescale per tile; csr read once.

__global__ __launch_bounds__(256) void k_layer1(const int2* __restrict__ csr,
                                                const int* __restrict__ cursor,
                                                const ushort* __restrict__ h1,
                                                const float* __restrict__ b1,
                                                const float* __restrict__ W2,
                                                float* __restrict__ h2) {
    int wid = threadIdx.x >> 6, l = threadIdx.x & 63;
    int d = blockIdx.x * 4 + wid;
    if (d >= NN) return;
    int s0 = d * PAD;
    int n = cursor[d] - s0; if (n > PAD) n = PAD;

    float m = -INFINITY, den = 0.f, ax = 0.f, ay = 0.f;
    int i = 0;
    for (; i + 4 <= n; i += 4) {
        int2 e0 = csr[s0 + i],     e1 = csr[s0 + i + 1];
        int2 e2 = csr[s0 + i + 2], e3 = csr[s0 + i + 3];
        float a0 = h2f((ushort)(e0.y >> 16));
        float a1 = h2f((ushort)(e1.y >> 16));
        float a2 = h2f((ushort)(e2.y >> 16));
        float a3 = h2f((ushort)(e3.y >> 16));
        ushort2 hv0 = *(const ushort2*)&h1[(size_t)e0.x * HD + 2 * l];
        ushort2 hv1 = *(const ushort2*)&h1[(size_t)e1.x * HD + 2 * l];
        ushort2 hv2 = *(const ushort2*)&h1[(size_t)e2.x * HD + 2 * l];
        ushort2 hv3 = *(const ushort2*)&h1[(size_t)e3.x * HD + 2 * l];
        float mt = fmaxf(fmaxf(a0, a1), fmaxf(a2, a3));
        if (mt > m) {                      // wave-uniform branch
            float r = expf(m - mt);        // first tile: exp(-inf) = 0
            den *= r; ax *= r; ay *= r; m = mt;
        }
        float w0 = expf(a0 - m), w1 = expf(a1 - m);
        float w2 = expf(a2 - m), w3 = expf(a3 - m);
        den += w0 + w1 + w2 + w3;
        ax += w0 * bf2f(hv0.x) + w1 * bf2f(hv1.x) + w2 * bf2f(hv2.x) + w3 * bf2f(hv3.x);
        ay += w0 * bf2f(hv0.y) + w1 * bf2f(hv1.y) + w2 * bf2f(hv2.y) + w3 * bf2f(hv3.y);
    }
    for (; i < n; ++i) {
        int2 e0 = csr[s0 + i];
        float a0 = h2f((ushort)(e0.y >> 16));
        ushort2 hv0 = *(const ushort2*)&h1[(size_t)e0.x * HD + 2 * l];
        if (a0 > m) {
            float r = expf(m - a0);
            den *= r; ax *= r; ay *= r; m = a0;
        }
        float w0 = expf(a0 - m);
        den += w0;
        ax += w0 * bf2f(hv0.x);
        ay += w0 * bf2f(hv0.y);
    }
    float inv = 1.f / (den + 1e-16f);
    ax *= inv; ay *= inv;
    float2 bb = *(const float2*)&b1[2 * l];
    float2 w  = *(const float2*)&W2[2 * l];
    float a = ax + bb.x; a = (a > 0.f) ? a : (expf(a) - 1.f);
    float b = ay + bb.y; b = (b > 0.f) ? b : (expf(b) - 1.f);
    float p = a * w.x + b * w.y;
    p = wave_reduce_sum(p);
    if (l == 0) h2[d] = p;
}

// ---------------- layer 2 (fused, scalar): single-pass online softmax ----------------

__global__ __launch_bounds__(256) void k_layer2(const int2* __restrict__ csr,
                                                const int* __restrict__ cursor,
                                                const float* __restrict__ h2,
                                                const float* __restrict__ as2,
                                                const float* __restrict__ ad2,
                                                const float* __restrict__ sc,
                                                const float* __restrict__ b2,
                                                float* __restrict__ out) {
    int d = blockIdx.x * blockDim.x + threadIdx.x;
    if (d >= NN) return;
    int s0 = d * PAD;
    int n = cursor[d] - s0; if (n > PAD) n = PAD;
    float A = as2[0], D = ad2[0], c2 = sc[2];
    float hd = D * h2[d];

    float m = -INFINITY, den = 0.f, num = 0.f;
    int i = 0;
    for (; i + 4 <= n; i += 4) {
        int2 s_0 = csr[s0 + i],     s_1 = csr[s0 + i + 1];
        int2 s_2 = csr[s0 + i + 2], s_3 = csr[s0 + i + 3];
        float h0 = h2[s_0.x], h1v = h2[s_1.x], h2v = h2[s_2.x], h3 = h2[s_3.x];
        float a0 = A * h0 + hd + c2 * h2f((ushort)(s_0.y & 0xFFFF));
        float a1 = A * h1v + hd + c2 * h2f((ushort)(s_1.y & 0xFFFF));
        float a2 = A * h2v + hd + c2 * h2f((ushort)(s_2.y & 0xFFFF));
        float a3 = A * h3 + hd + c2 * h2f((ushort)(s_3.y & 0xFFFF));
        a0 = (a0 > 0.f) ? a0 : 0.2f * a0;
        a1 = (a1 > 0.f) ? a1 : 0.2f * a1;
        a2 = (a2 > 0.f) ? a2 : 0.2f * a2;
        a3 = (a3 > 0.f) ? a3 : 0.2f * a3;
        float mt = fmaxf(fmaxf(a0, a1), fmaxf(a2, a3));
        if (mt > m) {
            float r = expf(m - mt);
            den *= r; num *= r; m = mt;
        }
        float w0 = expf(a0 - m), w1 = expf(a1 - m);
        float w2 = expf(a2 - m), w3 = expf(a3 - m);
        den += w0 + w1 + w2 + w3;
        num += w0 * h0 + w1 * h1v + w2 * h2v + w3 * h3;
    }
    for (; i < n; ++i) {
        int2 sa = csr[s0 + i];
        float hs = h2[sa.x];
        float a = A * hs + hd + c2 * h2f((ushort)(sa.y & 0xFFFF));
        a = (a > 0.f) ? a : 0.2f * a;
        if (a > m) {
            float r = expf(m - a);
            den *= r; num *= r; m = a;
        }
        float wgt = expf(a - m);
        den += wgt;
        num += wgt * hs;
    }
    float v = num / (den + 1e-16f) + b2[0];
    out[d] = (v >= 0.f) ? v : 0.01f * v;
}

// ---------------- launch ----------------

extern "C" void kernel_launch(void* const* d_in, const int* in_sizes, int n_in,
                              void* d_out, int out_size, void* d_ws, size_t ws_size,
                              hipStream_t stream) {
    const float* x     = (const float*)d_in[0];
    const int*   ei    = (const int*)d_in[1];
    const float* eattr = (const float*)d_in[2];
    const float* W1    = (const float*)d_in[3];
    const float* asrc1 = (const float*)d_in[4];
    const float* adst1 = (const float*)d_in[5];
    const float* We1   = (const float*)d_in[6];
    const float* ae1   = (const float*)d_in[7];
    const float* b1    = (const float*)d_in[8];
    const float* W2    = (const float*)d_in[9];
    const float* as2   = (const float*)d_in[10];
    const float* ad2   = (const float*)d_in[11];
    const float* We2   = (const float*)d_in[12];
    const float* ae2   = (const float*)d_in[13];
    const float* b2    = (const float*)d_in[14];
    float* out = (float*)d_out;

    // workspace layout (~40 MB)
    ushort* h1  = (ushort*)d_ws;              // NH ushorts (12.8 MB)
    float* as1  = (float*)(h1 + (size_t)NH);  // NN
    float* ad1  = as1 + NN;
    float* h2   = ad1 + NN;
    float* sc   = h2 + NN;                    // 8 scalars
    float* bsum = sc + 8;                     // 256 partials
    int*   cursor = (int*)(bsum + 256);       // NN
    int2*  csr    = (int2*)(cursor + NN);     // NN*PAD int2 (25.6 MB)
    ushort* Wp  = (ushort*)(csr + (size_t)NN * PAD);  // WP_ELEMS bf16 (packed)

    k_pre<<<NBLK + 1 + WT_BLKS + 256, 256, 0, stream>>>(cursor, sc, We1, ae1, We2, ae2,
                                                        W1, Wp, eattr, bsum);

    k_gemm1_mfma<<<NROWB, 512, 0, stream>>>(x, Wp, h1, asrc1, adst1, as1, ad1, bsum, sc);

    k_place<<<(NEP + 255) / 256, 256, 0, stream>>>(ei, eattr, sc, as1, ad1, cursor, csr);

    k_layer1<<<(NN + 3) / 4, 256, 0, stream>>>(csr, cursor, h1, b1, W2, h2);
    k_layer2<<<(NN + 255) / 256, 256, 0, stream>>>(csr, cursor, h2, as2, ad2, sc, b2, out);
}